// Round 2
// baseline (37723.666 us; speedup 1.0000x reference)
//
#include <hip/hip_runtime.h>
#include <hip/hip_cooperative_groups.h>
#include <math.h>

#define BB   128
#define TT   256
#define IN0  300
#define HID  512
#define G3   1536
#define EPSV 1e-5f

namespace cg = cooperative_groups;

__device__ __forceinline__ float sigm(float x) { return 1.0f / (1.0f + expf(-x)); }

// C[m, n] = A_rows @ B[N,K]^T + bias[N], chunk-local rows.
// Chunk-local row gr maps to source row (gr/Tc)*TT + c + gr%Tc of A (K-contig).
// C is (B*Tc, 1536) chunk-local contiguous.
__global__ __launch_bounds__(256) void gemm_nt_bias(
    const float* __restrict__ A, const float* __restrict__ Bm,
    const float* __restrict__ bias, float* __restrict__ C,
    int K, int c, int Tc)
{
    __shared__ float As[8][128];
    __shared__ float Bs[8][128];
    const int n0 = blockIdx.x * 128;
    const int m0 = blockIdx.y * 128;
    const int tid = threadIdx.x;
    const int tx = tid & 15;   // N dir
    const int ty = tid >> 4;   // M dir

    float acc[8][8];
#pragma unroll
    for (int i = 0; i < 8; ++i)
#pragma unroll
        for (int j = 0; j < 8; ++j) acc[i][j] = 0.f;

    const int lm = tid >> 1;         // 0..127 row within tile
    const int lk = (tid & 1) * 4;    // 0 or 4

    const int gr   = m0 + lm;                 // chunk-local row
    const int brow = gr / Tc;
    const int tl   = gr - brow * Tc;
    const float* Arow = A + ((size_t)brow * TT + (size_t)(c + tl)) * K;
    const float* Brow = Bm + (size_t)(n0 + lm) * K;

    for (int k0 = 0; k0 < K; k0 += 8) {
        const int gk = k0 + lk;
        float4 av = make_float4(0.f, 0.f, 0.f, 0.f);
        float4 bv = make_float4(0.f, 0.f, 0.f, 0.f);
        if (gk < K) {
            av = *(const float4*)(Arow + gk);
            bv = *(const float4*)(Brow + gk);
        }
        As[lk + 0][lm] = av.x; As[lk + 1][lm] = av.y; As[lk + 2][lm] = av.z; As[lk + 3][lm] = av.w;
        Bs[lk + 0][lm] = bv.x; Bs[lk + 1][lm] = bv.y; Bs[lk + 2][lm] = bv.z; Bs[lk + 3][lm] = bv.w;
        __syncthreads();
#pragma unroll
        for (int kk = 0; kk < 8; ++kk) {
            float4 a0 = *(const float4*)&As[kk][ty * 8];
            float4 a1 = *(const float4*)&As[kk][ty * 8 + 4];
            float4 b0 = *(const float4*)&Bs[kk][tx * 8];
            float4 b1 = *(const float4*)&Bs[kk][tx * 8 + 4];
            float ar[8] = {a0.x, a0.y, a0.z, a0.w, a1.x, a1.y, a1.z, a1.w};
            float br[8] = {b0.x, b0.y, b0.z, b0.w, b1.x, b1.y, b1.z, b1.w};
#pragma unroll
            for (int i = 0; i < 8; ++i)
#pragma unroll
                for (int j = 0; j < 8; ++j)
                    acc[i][j] = fmaf(ar[i], br[j], acc[i][j]);
        }
        __syncthreads();
    }

#pragma unroll
    for (int i = 0; i < 8; ++i) {
        const size_t row = (size_t)(m0 + ty * 8 + i);
        float o0[4], o1[4];
#pragma unroll
        for (int j = 0; j < 4; ++j) o0[j] = acc[i][j] + bias[n0 + tx * 8 + j];
#pragma unroll
        for (int j = 0; j < 4; ++j) o1[j] = acc[i][4 + j] + bias[n0 + tx * 8 + 4 + j];
        *(float4*)(C + row * G3 + n0 + tx * 8)     = *(float4*)o0;
        *(float4*)(C + row * G3 + n0 + tx * 8 + 4) = *(float4*)o1;
    }
}

// Cooperative GRU recurrence for timesteps [t0, t0+Tc).
// xg: chunk-local (B, Tc, 1536) x-gates (+b_ih already folded by GEMM bias).
// w_hh: (1536,512). y: (B,T,512) or nullptr. hbuf: 2*B*512 ping-pong keyed on
// global-t parity; after t=255 the final h is in hbuf[0 .. B*512).
__global__ __launch_bounds__(256) void gru_rec(
    const float* __restrict__ xg, const float* __restrict__ w_hh,
    const float* __restrict__ b_hh, float* __restrict__ y,
    float* __restrict__ hbuf, int t0, int Tc)
{
    cg::grid_group grid = cg::this_grid();
    __shared__ float hs[16][516];   // stride 516: kills stride-512 bank conflicts

    const int wg  = blockIdx.x;     // 256 wg
    const int bt  = wg >> 5;        // 8 batch tiles of 16
    const int jt  = wg & 31;        // 32 hidden tiles of 16
    const int b0  = bt * 16;
    const int j0  = jt * 16;
    const int tid = threadIdx.x;
    const int ji  = tid & 15;       // lanes contiguous over hidden
    const int bi  = tid >> 4;
    const int j   = j0 + ji;

    float* h0 = hbuf;
    float* h1 = hbuf + BB * HID;

    if (t0 == 0) {
        // zero initial hidden state (all jt tiles of a bt write the same zeros: benign)
        for (int i = tid; i < 16 * HID; i += 256)
            h0[(size_t)(b0 + (i >> 9)) * HID + (i & 511)] = 0.f;
        grid.sync();
    }

    const float bhr = b_hh[j];
    const float bhz = b_hh[HID + j];
    const float bhn = b_hh[2 * HID + j];
    const float4* wr = (const float4*)(w_hh + (size_t)j * HID);
    const float4* wz = (const float4*)(w_hh + (size_t)(HID + j) * HID);
    const float4* wn = (const float4*)(w_hh + (size_t)(2 * HID + j) * HID);

    for (int t = t0; t < t0 + Tc; ++t) {
        const float* hp = (t & 1) ? h1 : h0;
        float*       hn = (t & 1) ? h0 : h1;

        // stage h[b0..b0+16, :] into LDS (2048 float4, 8 per thread)
        for (int cc = tid; cc < 16 * (HID / 4); cc += 256) {
            const int bb = cc >> 7;
            const int kc = (cc & 127) * 4;
            float4 v = *(const float4*)(hp + (size_t)(b0 + bb) * HID + kc);
            *(float4*)&hs[bb][kc] = v;
        }
        __syncthreads();

        float ar = bhr, az = bhz, an = bhn;
#pragma unroll 4
        for (int kq = 0; kq < HID / 4; ++kq) {
            float4 h4  = *(const float4*)&hs[bi][kq * 4];
            float4 w4r = wr[kq];
            float4 w4z = wz[kq];
            float4 w4n = wn[kq];
            ar = fmaf(h4.x, w4r.x, ar); ar = fmaf(h4.y, w4r.y, ar);
            ar = fmaf(h4.z, w4r.z, ar); ar = fmaf(h4.w, w4r.w, ar);
            az = fmaf(h4.x, w4z.x, az); az = fmaf(h4.y, w4z.y, az);
            az = fmaf(h4.z, w4z.z, az); az = fmaf(h4.w, w4z.w, az);
            an = fmaf(h4.x, w4n.x, an); an = fmaf(h4.y, w4n.y, an);
            an = fmaf(h4.z, w4n.z, an); an = fmaf(h4.w, w4n.w, an);
        }

        const float* xrow = xg + ((size_t)(b0 + bi) * Tc + (t - t0)) * G3;
        const float r = sigm(xrow[j] + ar);
        const float z = sigm(xrow[HID + j] + az);
        const float n = tanhf(xrow[2 * HID + j] + r * an);
        const float hprev = hs[bi][j];
        const float hnew  = (1.f - z) * n + z * hprev;

        hn[(size_t)(b0 + bi) * HID + j] = hnew;
        if (y) y[((size_t)(b0 + bi) * TT + t) * HID + j] = hnew;
        grid.sync();
    }
}

// pooled -> BN -> fc1 -> relu -> LN -> fc2 ; one workgroup per batch row
__global__ __launch_bounds__(256) void tail_kernel(
    const float* __restrict__ hfin,
    const float* __restrict__ bn_w, const float* __restrict__ bn_b,
    const float* __restrict__ bn_mean, const float* __restrict__ bn_var,
    const float* __restrict__ fc1_w, const float* __restrict__ fc1_b,
    const float* __restrict__ ln_w, const float* __restrict__ ln_b,
    const float* __restrict__ fc2_w, const float* __restrict__ fc2_b,
    float* __restrict__ out)
{
    const int b = blockIdx.x;
    const int tid = threadIdx.x;
    __shared__ float pn[512];
    __shared__ float o1[256];
    __shared__ float red[2][4];

    for (int jj = tid; jj < 512; jj += 256) {
        float v = hfin[(size_t)b * 512 + jj];
        v = (v - bn_mean[jj]) * rsqrtf(bn_var[jj] + EPSV) * bn_w[jj] + bn_b[jj];
        pn[jj] = v;
    }
    __syncthreads();

    const float4* w1 = (const float4*)(fc1_w + (size_t)tid * 512);
    float acc = fc1_b[tid];
#pragma unroll 4
    for (int kq = 0; kq < 128; ++kq) {
        float4 w4 = w1[kq];
        float4 h4 = *(const float4*)&pn[kq * 4];
        acc = fmaf(w4.x, h4.x, acc); acc = fmaf(w4.y, h4.y, acc);
        acc = fmaf(w4.z, h4.z, acc); acc = fmaf(w4.w, h4.w, acc);
    }
    const float val = fmaxf(acc, 0.f);

    float s = val, sq = val * val;
#pragma unroll
    for (int off = 32; off >= 1; off >>= 1) {
        s  += __shfl_xor(s, off);
        sq += __shfl_xor(sq, off);
    }
    const int wv = tid >> 6, ln = tid & 63;
    if (ln == 0) { red[0][wv] = s; red[1][wv] = sq; }
    __syncthreads();
    const float S  = red[0][0] + red[0][1] + red[0][2] + red[0][3];
    const float SQ = red[1][0] + red[1][1] + red[1][2] + red[1][3];
    const float mu  = S * (1.f / 256.f);
    const float var = SQ * (1.f / 256.f) - mu * mu;
    const float nv = (val - mu) * rsqrtf(var + EPSV) * ln_w[tid] + ln_b[tid];
    o1[tid] = nv;
    __syncthreads();

    if (wv < 3) {
        const float* w2 = fc2_w + wv * 256;
        float p = w2[ln] * o1[ln] + w2[ln + 64] * o1[ln + 64]
                + w2[ln + 128] * o1[ln + 128] + w2[ln + 192] * o1[ln + 192];
#pragma unroll
        for (int off = 32; off >= 1; off >>= 1) p += __shfl_xor(p, off);
        if (ln == 0) out[b * 3 + wv] = p + fc2_b[wv];
    }
}

extern "C" void kernel_launch(void* const* d_in, const int* in_sizes, int n_in,
                              void* d_out, int out_size, void* d_ws, size_t ws_size,
                              hipStream_t stream) {
    const float* x       = (const float*)d_in[0];
    const float* w_ih0   = (const float*)d_in[1];
    const float* w_hh0   = (const float*)d_in[2];
    const float* b_ih0   = (const float*)d_in[3];
    const float* b_hh0   = (const float*)d_in[4];
    const float* w_ih1   = (const float*)d_in[5];
    const float* w_hh1   = (const float*)d_in[6];
    const float* b_ih1   = (const float*)d_in[7];
    const float* b_hh1   = (const float*)d_in[8];
    const float* bn_w    = (const float*)d_in[9];
    const float* bn_b    = (const float*)d_in[10];
    const float* bn_mean = (const float*)d_in[11];
    const float* bn_var  = (const float*)d_in[12];
    const float* fc1_w   = (const float*)d_in[13];
    const float* fc1_b   = (const float*)d_in[14];
    const float* ln_w    = (const float*)d_in[15];
    const float* ln_b    = (const float*)d_in[16];
    const float* fc2_w   = (const float*)d_in[17];
    const float* fc2_b   = (const float*)d_in[18];
    float* out = (float*)d_out;

    // workspace layout: fixed buffers first, chunk-sized xg after
    float* ws = (float*)d_ws;
    const size_t y0F = (size_t)BB * TT * HID;   // 16,777,216 floats
    const size_t hbF = 2 * (size_t)BB * HID;    //    131,072 floats
    float* y0  = ws;
    float* hb  = y0 + y0F;
    float* xgc = hb + hbF;

    // choose largest chunk Tc (timesteps of precomputed x-gates) that fits ws
    const size_t availF = ws_size / sizeof(float);
    int Tc = TT;
    while (Tc > 8 && y0F + hbF + (size_t)BB * (size_t)Tc * G3 > availF) Tc >>= 1;

    for (int layer = 0; layer < 2; ++layer) {
        const float* Ain = layer ? y0 : x;
        const int    K   = layer ? HID : IN0;
        const float* wih = layer ? w_ih1 : w_ih0;
        const float* bih = layer ? b_ih1 : b_ih0;
        const float* whh = layer ? w_hh1 : w_hh0;
        const float* bhh = layer ? b_hh1 : b_hh0;
        float*       yout = layer ? nullptr : y0;

        for (int c = 0; c < TT; c += Tc) {
            gemm_nt_bias<<<dim3(12, (BB * Tc) / 128), dim3(256), 0, stream>>>(
                Ain, wih, bih, xgc, K, c, Tc);
            int t0 = c, tc = Tc;
            void* args[] = { (void*)&xgc, (void*)&whh, (void*)&bhh,
                             (void*)&yout, (void*)&hb, (void*)&t0, (void*)&tc };
            hipLaunchCooperativeKernel((void*)gru_rec, dim3(256), dim3(256),
                                       args, 0, stream);
        }
    }

    tail_kernel<<<dim3(128), dim3(256), 0, stream>>>(
        hb, bn_w, bn_b, bn_mean, bn_var,
        fc1_w, fc1_b, ln_w, ln_b, fc2_w, fc2_b, out);
}

// Round 3
// 16613.744 us; speedup vs baseline: 2.2706x; 2.2706x over previous
//
#include <hip/hip_runtime.h>
#include <math.h>

#define BB   128
#define TT   256
#define IN0  300
#define HID  512
#define G3   1536
#define EPSV 1e-5f
#define NWG  256          // recurrence workgroups: 8 batch-groups x 32 j-groups
#define WPAD 520          // bf16 elems per LDS row (512 + 8 pad -> 2-way conflicts max)

typedef __attribute__((ext_vector_type(8))) short bf16x8;
typedef __attribute__((ext_vector_type(4))) float f32x4;

__device__ __forceinline__ float sigm(float x) { return 1.0f / (1.0f + expf(-x)); }

__device__ __forceinline__ unsigned short f2bf(float f) {
    union { float f; unsigned u; } v; v.f = f;
    unsigned r = v.u + 0x7fffu + ((v.u >> 16) & 1u);   // RNE
    return (unsigned short)(r >> 16);
}

// monotonic barrier over the 32 wgs of one batch-group
__device__ __forceinline__ void gbar(unsigned int* bar, unsigned int* phase) {
    __syncthreads();
    if (threadIdx.x == 0) {
        __threadfence();   // release my wg's global writes
        __hip_atomic_fetch_add(bar, 1u, __ATOMIC_ACQ_REL, __HIP_MEMORY_SCOPE_AGENT);
        const unsigned tgt = (*phase) * 32u;
        while (__hip_atomic_load(bar, __ATOMIC_ACQUIRE, __HIP_MEMORY_SCOPE_AGENT) < tgt)
            __builtin_amdgcn_s_sleep(2);
    }
    __syncthreads();
    __threadfence();       // acquire: invalidate L1 so peers' h writes are visible
    ++(*phase);
}

// ---------------- xg GEMM (unchanged from round 2) ----------------
// C[m,n] = A_rows @ B[N,K]^T + bias, chunk-local rows; C is (B*Tc, 1536).
__global__ __launch_bounds__(256) void gemm_nt_bias(
    const float* __restrict__ A, const float* __restrict__ Bm,
    const float* __restrict__ bias, float* __restrict__ C,
    int K, int c, int Tc)
{
    __shared__ float As[8][128];
    __shared__ float Bs[8][128];
    const int n0 = blockIdx.x * 128;
    const int m0 = blockIdx.y * 128;
    const int tid = threadIdx.x;
    const int tx = tid & 15;
    const int ty = tid >> 4;

    float acc[8][8];
#pragma unroll
    for (int i = 0; i < 8; ++i)
#pragma unroll
        for (int j = 0; j < 8; ++j) acc[i][j] = 0.f;

    const int lm = tid >> 1;
    const int lk = (tid & 1) * 4;

    const int gr   = m0 + lm;
    const int brow = gr / Tc;
    const int tl   = gr - brow * Tc;
    const float* Arow = A + ((size_t)brow * TT + (size_t)(c + tl)) * K;
    const float* Brow = Bm + (size_t)(n0 + lm) * K;

    for (int k0 = 0; k0 < K; k0 += 8) {
        const int gk = k0 + lk;
        float4 av = make_float4(0.f, 0.f, 0.f, 0.f);
        float4 bv = make_float4(0.f, 0.f, 0.f, 0.f);
        if (gk < K) {
            av = *(const float4*)(Arow + gk);
            bv = *(const float4*)(Brow + gk);
        }
        As[lk + 0][lm] = av.x; As[lk + 1][lm] = av.y; As[lk + 2][lm] = av.z; As[lk + 3][lm] = av.w;
        Bs[lk + 0][lm] = bv.x; Bs[lk + 1][lm] = bv.y; Bs[lk + 2][lm] = bv.z; Bs[lk + 3][lm] = bv.w;
        __syncthreads();
#pragma unroll
        for (int kk = 0; kk < 8; ++kk) {
            float4 a0 = *(const float4*)&As[kk][ty * 8];
            float4 a1 = *(const float4*)&As[kk][ty * 8 + 4];
            float4 b0 = *(const float4*)&Bs[kk][tx * 8];
            float4 b1 = *(const float4*)&Bs[kk][tx * 8 + 4];
            float ar[8] = {a0.x, a0.y, a0.z, a0.w, a1.x, a1.y, a1.z, a1.w};
            float br[8] = {b0.x, b0.y, b0.z, b0.w, b1.x, b1.y, b1.z, b1.w};
#pragma unroll
            for (int i = 0; i < 8; ++i)
#pragma unroll
                for (int j = 0; j < 8; ++j)
                    acc[i][j] = fmaf(ar[i], br[j], acc[i][j]);
        }
        __syncthreads();
    }

#pragma unroll
    for (int i = 0; i < 8; ++i) {
        const size_t row = (size_t)(m0 + ty * 8 + i);
        float o0[4], o1[4];
#pragma unroll
        for (int j = 0; j < 4; ++j) o0[j] = acc[i][j] + bias[n0 + tx * 8 + j];
#pragma unroll
        for (int j = 0; j < 4; ++j) o1[j] = acc[i][4 + j] + bias[n0 + tx * 8 + 4 + j];
        *(float4*)(C + row * G3 + n0 + tx * 8)     = *(float4*)o0;
        *(float4*)(C + row * G3 + n0 + tx * 8 + 4) = *(float4*)o1;
    }
}

// ---------------- persistent MFMA recurrence ----------------
// 256 wgs = 8 batch-groups (16 rows) x 32 j-groups (16 hidden units).
// w_hh slice (48 rows x 512) resident in LDS as bf16 for the whole launch.
// Per step: stage own 16 h rows (bf16, global ping-pong) -> 3 waves compute the
// three gates via 16 MFMA each -> gate math in fp32 with per-thread fp32 h.
// Sync: per-batch-group monotonic barrier over 32 wgs.
__global__ __launch_bounds__(256) void gru_pers(
    const float* __restrict__ xg,     // (B, Tc, 1536) chunk-local, b_ih folded
    const float* __restrict__ w_hh,   // (1536, 512) fp32
    const float* __restrict__ b_hh,   // (1536)
    float* __restrict__ y,            // (B,T,512) fp32 or nullptr
    float* __restrict__ h32,          // (B,512) fp32 master (chunk carry + tail)
    unsigned short* __restrict__ hbf, // 2 * B*512 bf16 ping-pong
    unsigned int* __restrict__ bar,   // 8 counters, 16 u32 apart
    int t0, int Tc)
{
    __shared__ unsigned short wlds[48 * WPAD];   // 49,920 B
    __shared__ unsigned short hlds[16 * WPAD];   // 16,640 B
    __shared__ float gpatch[3][16][17];          //  3,264 B

    const int wg = blockIdx.x;
    const int bg = wg >> 5;           // 0..7
    const int jg = wg & 31;           // 0..31
    const int b0 = bg * 16;
    const int j0 = jg * 16;
    const int tid = threadIdx.x;
    const int wv  = tid >> 6;
    const int ln  = tid & 63;
    const int r   = tid >> 4;         // patch row  (batch)
    const int c   = tid & 15;         // patch col  (hidden)

    unsigned int* mybar = bar + bg * 16;
    unsigned int  phase = 1;

    // ---- load + convert my w_hh slice to LDS bf16 (once) ----
    for (int i = tid; i < 48 * 512; i += 256) {
        const int row = i >> 9, col = i & 511;
        const int grow = (row >> 4) * HID + j0 + (row & 15);   // gate*512 + j
        wlds[row * WPAD + col] = f2bf(w_hh[(size_t)grow * HID + col]);
    }

    const float bhr = b_hh[j0 + c];
    const float bhz = b_hh[HID + j0 + c];
    const float bhn = b_hh[2 * HID + j0 + c];

    unsigned short* hbf0 = hbf;
    unsigned short* hbf1 = hbf + BB * HID;

    float hreg;
    if (t0 == 0) {
        hreg = 0.f;
        hbf0[(size_t)(b0 + r) * HID + j0 + c] = 0;   // zero my patch in ping buf
        gbar(mybar, &phase);                          // zeros visible group-wide
    } else {
        hreg = h32[(size_t)(b0 + r) * HID + j0 + c];
    }

    for (int t = t0; t < t0 + Tc; ++t) {
        const unsigned short* hprev = (t & 1) ? hbf1 : hbf0;
        unsigned short*       hnext = (t & 1) ? hbf0 : hbf1;

        // stage my 16 h rows (bf16) into LDS, 16B vector copies
        for (int i = tid; i < 16 * (HID / 8); i += 256) {
            const int row = i >> 6, k8 = (i & 63) * 8;
            *(bf16x8*)&hlds[row * WPAD + k8] =
                *(const bf16x8*)&hprev[(size_t)(b0 + row) * HID + k8];
        }
        __syncthreads();

        // waves 0..2: gate wv as 16 chained MFMAs over K=512
        if (wv < 3) {
            f32x4 acc = {0.f, 0.f, 0.f, 0.f};
            const int frow = ln & 15;
            const int koff = (ln >> 4) * 8;
            const unsigned short* wrow = &wlds[(wv * 16 + frow) * WPAD + koff];
            const unsigned short* hrow = &hlds[frow * WPAD + koff];
#pragma unroll
            for (int ks = 0; ks < 16; ++ks) {
                bf16x8 a = *(const bf16x8*)(hrow + ks * 32);
                bf16x8 b = *(const bf16x8*)(wrow + ks * 32);
                acc = __builtin_amdgcn_mfma_f32_16x16x32_bf16(a, b, acc, 0, 0, 0);
            }
#pragma unroll
            for (int i = 0; i < 4; ++i)                   // D: col=lane&15, row=(lane>>4)*4+i
                gpatch[wv][(ln >> 4) * 4 + i][ln & 15] = acc[i];
        }
        __syncthreads();

        // gate math, fp32
        const float* xrow = xg + ((size_t)(b0 + r) * Tc + (t - t0)) * G3 + j0 + c;
        const float rr = sigm(xrow[0]   + gpatch[0][r][c] + bhr);
        const float zz = sigm(xrow[HID] + gpatch[1][r][c] + bhz);
        const float nn = tanhf(xrow[2 * HID] + rr * (gpatch[2][r][c] + bhn));
        hreg = (1.f - zz) * nn + zz * hreg;

        hnext[(size_t)(b0 + r) * HID + j0 + c] = f2bf(hreg);
        if (y) y[((size_t)(b0 + r) * TT + t) * HID + j0 + c] = hreg;

        gbar(mybar, &phase);   // h_new visible to my batch-group
    }

    h32[(size_t)(b0 + r) * HID + j0 + c] = hreg;   // carry to next chunk / tail
}

// ---------------- tail (unchanged) ----------------
__global__ __launch_bounds__(256) void tail_kernel(
    const float* __restrict__ hfin,
    const float* __restrict__ bn_w, const float* __restrict__ bn_b,
    const float* __restrict__ bn_mean, const float* __restrict__ bn_var,
    const float* __restrict__ fc1_w, const float* __restrict__ fc1_b,
    const float* __restrict__ ln_w, const float* __restrict__ ln_b,
    const float* __restrict__ fc2_w, const float* __restrict__ fc2_b,
    float* __restrict__ out)
{
    const int b = blockIdx.x;
    const int tid = threadIdx.x;
    __shared__ float pn[512];
    __shared__ float o1[256];
    __shared__ float red[2][4];

    for (int jj = tid; jj < 512; jj += 256) {
        float v = hfin[(size_t)b * 512 + jj];
        v = (v - bn_mean[jj]) * rsqrtf(bn_var[jj] + EPSV) * bn_w[jj] + bn_b[jj];
        pn[jj] = v;
    }
    __syncthreads();

    const float4* w1 = (const float4*)(fc1_w + (size_t)tid * 512);
    float acc = fc1_b[tid];
#pragma unroll 4
    for (int kq = 0; kq < 128; ++kq) {
        float4 w4 = w1[kq];
        float4 h4 = *(const float4*)&pn[kq * 4];
        acc = fmaf(w4.x, h4.x, acc); acc = fmaf(w4.y, h4.y, acc);
        acc = fmaf(w4.z, h4.z, acc); acc = fmaf(w4.w, h4.w, acc);
    }
    const float val = fmaxf(acc, 0.f);

    float s = val, sq = val * val;
#pragma unroll
    for (int off = 32; off >= 1; off >>= 1) {
        s  += __shfl_xor(s, off);
        sq += __shfl_xor(sq, off);
    }
    const int wv = tid >> 6, ln = tid & 63;
    if (ln == 0) { red[0][wv] = s; red[1][wv] = sq; }
    __syncthreads();
    const float S  = red[0][0] + red[0][1] + red[0][2] + red[0][3];
    const float SQ = red[1][0] + red[1][1] + red[1][2] + red[1][3];
    const float mu  = S * (1.f / 256.f);
    const float var = SQ * (1.f / 256.f) - mu * mu;
    const float nv = (val - mu) * rsqrtf(var + EPSV) * ln_w[tid] + ln_b[tid];
    o1[tid] = nv;
    __syncthreads();

    if (wv < 3) {
        const float* w2 = fc2_w + wv * 256;
        float p = w2[ln] * o1[ln] + w2[ln + 64] * o1[ln + 64]
                + w2[ln + 128] * o1[ln + 128] + w2[ln + 192] * o1[ln + 192];
#pragma unroll
        for (int off = 32; off >= 1; off >>= 1) p += __shfl_xor(p, off);
        if (ln == 0) out[b * 3 + wv] = p + fc2_b[wv];
    }
}

extern "C" void kernel_launch(void* const* d_in, const int* in_sizes, int n_in,
                              void* d_out, int out_size, void* d_ws, size_t ws_size,
                              hipStream_t stream) {
    const float* x       = (const float*)d_in[0];
    const float* w_ih0   = (const float*)d_in[1];
    const float* w_hh0   = (const float*)d_in[2];
    const float* b_ih0   = (const float*)d_in[3];
    const float* b_hh0   = (const float*)d_in[4];
    const float* w_ih1   = (const float*)d_in[5];
    const float* w_hh1   = (const float*)d_in[6];
    const float* b_ih1   = (const float*)d_in[7];
    const float* b_hh1   = (const float*)d_in[8];
    const float* bn_w    = (const float*)d_in[9];
    const float* bn_b    = (const float*)d_in[10];
    const float* bn_mean = (const float*)d_in[11];
    const float* bn_var  = (const float*)d_in[12];
    const float* fc1_w   = (const float*)d_in[13];
    const float* fc1_b   = (const float*)d_in[14];
    const float* ln_w    = (const float*)d_in[15];
    const float* ln_b    = (const float*)d_in[16];
    const float* fc2_w   = (const float*)d_in[17];
    const float* fc2_b   = (const float*)d_in[18];
    float* out = (float*)d_out;

    // ws layout (float slots): y0 | h32 | hbf(ushort x2) | bar | xg chunk
    float* ws = (float*)d_ws;
    const size_t y0F  = (size_t)BB * TT * HID;        // 16,777,216
    const size_t h32F = (size_t)BB * HID;             //     65,536
    const size_t hbfF = (size_t)BB * HID;             // 2*B*H ushort = 65,536 float slots
    const size_t barF = 128;                          // 8 counters, padded
    float*          y0  = ws;
    float*          h32 = y0 + y0F;
    unsigned short* hbf = (unsigned short*)(h32 + h32F);
    unsigned int*   bar = (unsigned int*)(h32 + h32F + hbfF);
    float*          xgc = h32 + h32F + hbfF + barF;

    const size_t fixedF = y0F + h32F + hbfF + barF;
    const size_t availF = ws_size / sizeof(float);
    int Tc = TT;
    while (Tc > 8 && fixedF + (size_t)BB * (size_t)Tc * G3 > availF) Tc >>= 1;

    for (int layer = 0; layer < 2; ++layer) {
        const float* Ain  = layer ? y0 : x;
        const int    K    = layer ? HID : IN0;
        const float* wih  = layer ? w_ih1 : w_ih0;
        const float* bih  = layer ? b_ih1 : b_ih0;
        const float* whh  = layer ? w_hh1 : w_hh0;
        const float* bhh  = layer ? b_hh1 : b_hh0;
        float*       yout = layer ? nullptr : y0;

        for (int c = 0; c < TT; c += Tc) {
            gemm_nt_bias<<<dim3(12, (BB * Tc) / 128), dim3(256), 0, stream>>>(
                Ain, wih, bih, xgc, K, c, Tc);
            hipMemsetAsync(bar, 0, barF * sizeof(float), stream);
            int t0 = c, tc = Tc;
            void* args[] = { (void*)&xgc, (void*)&whh, (void*)&bhh, (void*)&yout,
                             (void*)&h32, (void*)&hbf, (void*)&bar,
                             (void*)&t0, (void*)&tc };
            hipLaunchCooperativeKernel((void*)gru_pers, dim3(NWG), dim3(256),
                                       args, 0, stream);
        }
    }

    tail_kernel<<<dim3(128), dim3(256), 0, stream>>>(
        h32, bn_w, bn_b, bn_mean, bn_var,
        fc1_w, fc1_b, ln_w, ln_b, fc2_w, fc2_b, out);
}

// Round 4
// 4241.436 us; speedup vs baseline: 8.8941x; 3.9170x over previous
//
#include <hip/hip_runtime.h>
#include <math.h>

#define BB   128
#define TT   256
#define IN0  300
#define HID  512
#define G3   1536
#define EPSV 1e-5f
#define NWG  256          // recurrence workgroups: 8 batch-groups x 32 j-groups
#define WPAD 520          // bf16 elems per LDS row (512 + 8 pad)

typedef __attribute__((ext_vector_type(8))) short bf16x8;
typedef __attribute__((ext_vector_type(4))) float f32x4;

__device__ __forceinline__ float sigm(float x) { return 1.0f / (1.0f + expf(-x)); }

__device__ __forceinline__ unsigned short f2bf(float f) {
    union { float f; unsigned u; } v; v.f = f;
    unsigned r = v.u + 0x7fffu + ((v.u >> 16) & 1u);   // RNE
    return (unsigned short)(r >> 16);
}

// fence-free barrier over the 32 wgs of one batch-group.
// Data coherence is carried by SYSTEM-scope data accesses, not by this barrier.
// __syncthreads() before the add drains all threads' stores (vmcnt(0) before s_barrier).
__device__ __forceinline__ void gbar(unsigned int* bar, unsigned int* phase) {
    __syncthreads();
    if (threadIdx.x == 0) {
        __hip_atomic_fetch_add(bar, 1u, __ATOMIC_RELAXED, __HIP_MEMORY_SCOPE_AGENT);
        const unsigned tgt = (*phase) * 32u;
        while (__hip_atomic_load(bar, __ATOMIC_RELAXED, __HIP_MEMORY_SCOPE_AGENT) < tgt)
            __builtin_amdgcn_s_sleep(1);
    }
    __syncthreads();
    ++(*phase);
}

// ---------------- xg GEMM (unchanged) ----------------
__global__ __launch_bounds__(256) void gemm_nt_bias(
    const float* __restrict__ A, const float* __restrict__ Bm,
    const float* __restrict__ bias, float* __restrict__ C,
    int K, int c, int Tc)
{
    __shared__ float As[8][128];
    __shared__ float Bs[8][128];
    const int n0 = blockIdx.x * 128;
    const int m0 = blockIdx.y * 128;
    const int tid = threadIdx.x;
    const int tx = tid & 15;
    const int ty = tid >> 4;

    float acc[8][8];
#pragma unroll
    for (int i = 0; i < 8; ++i)
#pragma unroll
        for (int j = 0; j < 8; ++j) acc[i][j] = 0.f;

    const int lm = tid >> 1;
    const int lk = (tid & 1) * 4;

    const int gr   = m0 + lm;
    const int brow = gr / Tc;
    const int tl   = gr - brow * Tc;
    const float* Arow = A + ((size_t)brow * TT + (size_t)(c + tl)) * K;
    const float* Brow = Bm + (size_t)(n0 + lm) * K;

    for (int k0 = 0; k0 < K; k0 += 8) {
        const int gk = k0 + lk;
        float4 av = make_float4(0.f, 0.f, 0.f, 0.f);
        float4 bv = make_float4(0.f, 0.f, 0.f, 0.f);
        if (gk < K) {
            av = *(const float4*)(Arow + gk);
            bv = *(const float4*)(Brow + gk);
        }
        As[lk + 0][lm] = av.x; As[lk + 1][lm] = av.y; As[lk + 2][lm] = av.z; As[lk + 3][lm] = av.w;
        Bs[lk + 0][lm] = bv.x; Bs[lk + 1][lm] = bv.y; Bs[lk + 2][lm] = bv.z; Bs[lk + 3][lm] = bv.w;
        __syncthreads();
#pragma unroll
        for (int kk = 0; kk < 8; ++kk) {
            float4 a0 = *(const float4*)&As[kk][ty * 8];
            float4 a1 = *(const float4*)&As[kk][ty * 8 + 4];
            float4 b0 = *(const float4*)&Bs[kk][tx * 8];
            float4 b1 = *(const float4*)&Bs[kk][tx * 8 + 4];
            float ar[8] = {a0.x, a0.y, a0.z, a0.w, a1.x, a1.y, a1.z, a1.w};
            float br[8] = {b0.x, b0.y, b0.z, b0.w, b1.x, b1.y, b1.z, b1.w};
#pragma unroll
            for (int i = 0; i < 8; ++i)
#pragma unroll
                for (int j = 0; j < 8; ++j)
                    acc[i][j] = fmaf(ar[i], br[j], acc[i][j]);
        }
        __syncthreads();
    }

#pragma unroll
    for (int i = 0; i < 8; ++i) {
        const size_t row = (size_t)(m0 + ty * 8 + i);
        float o0[4], o1[4];
#pragma unroll
        for (int j = 0; j < 4; ++j) o0[j] = acc[i][j] + bias[n0 + tx * 8 + j];
#pragma unroll
        for (int j = 0; j < 4; ++j) o1[j] = acc[i][4 + j] + bias[n0 + tx * 8 + 4 + j];
        *(float4*)(C + row * G3 + n0 + tx * 8)     = *(float4*)o0;
        *(float4*)(C + row * G3 + n0 + tx * 8 + 4) = *(float4*)o1;
    }
}

// ---------------- persistent MFMA recurrence, coherent h-exchange ----------------
// 256 wgs = 8 batch-groups (16 rows) x 32 j-groups (16 hidden units).
// h ping-pong in fp32; exchanged with SYSTEM-scope relaxed atomics (LLC-coherent,
// bypasses the non-coherent per-XCD L2) -> NO cache-nuking fences anywhere.
__global__ __launch_bounds__(256) void gru_pers(
    const float* __restrict__ xg,     // (B, Tc, 1536) chunk-local, b_ih folded
    const float* __restrict__ w_hh,   // (1536, 512) fp32
    const float* __restrict__ b_hh,   // (1536)
    float* __restrict__ y,            // (B,T,512) fp32 or nullptr
    float* __restrict__ h32,          // (B,512) fp32 master (chunk carry + tail)
    float* __restrict__ hex,          // 2 * B*512 fp32 ping-pong (system-scope)
    unsigned int* __restrict__ bar,   // 8 counters, 16 u32 apart
    int t0, int Tc)
{
    __shared__ unsigned short wlds[48 * WPAD];   // 49,920 B
    __shared__ unsigned short hlds[16 * WPAD];   // 16,640 B
    __shared__ float gpatch[3][16][17];          //  3,264 B

    const int wg = blockIdx.x;
    const int bg = wg >> 5;
    const int jg = wg & 31;
    const int b0 = bg * 16;
    const int j0 = jg * 16;
    const int tid = threadIdx.x;
    const int wv  = tid >> 6;
    const int ln  = tid & 63;
    const int r   = tid >> 4;         // patch row (batch)
    const int c   = tid & 15;         // patch col (hidden)

    unsigned int* mybar = bar + bg * 16;
    unsigned int  phase = 1;

    // load + convert my w_hh slice to LDS bf16 (once per launch)
    for (int i = tid; i < 48 * 512; i += 256) {
        const int row = i >> 9, col = i & 511;
        const int grow = (row >> 4) * HID + j0 + (row & 15);   // gate*512 + j
        wlds[row * WPAD + col] = f2bf(w_hh[(size_t)grow * HID + col]);
    }

    const float bhr = b_hh[j0 + c];
    const float bhz = b_hh[HID + j0 + c];
    const float bhn = b_hh[2 * HID + j0 + c];

    float* hex0 = hex;
    float* hex1 = hex + BB * HID;

    float hreg;
    if (t0 == 0) {
        hreg = 0.f;
        // zero my patch in ping buffer, system-scope so peers see it
        __hip_atomic_store(&hex0[(size_t)(b0 + r) * HID + j0 + c], 0.f,
                           __ATOMIC_RELAXED, __HIP_MEMORY_SCOPE_SYSTEM);
        gbar(mybar, &phase);
    } else {
        hreg = h32[(size_t)(b0 + r) * HID + j0 + c];
    }

    for (int t = t0; t < t0 + Tc; ++t) {
        const float* hprev = (t & 1) ? hex1 : hex0;
        float*       hnext = (t & 1) ? hex0 : hex1;

        // prefetch my 3 xg values early (normal cached loads; overlap with staging)
        const float* xrow = xg + ((size_t)(b0 + r) * Tc + (t - t0)) * G3 + j0 + c;
        const float xr_ = xrow[0];
        const float xz_ = xrow[HID];
        const float xn_ = xrow[2 * HID];

        // stage my 16 h rows into LDS as bf16: 16 x 8B system-scope loads/thread
        {
            unsigned int* hl32 = (unsigned int*)hlds;
#pragma unroll
            for (int ii = 0; ii < 16; ++ii) {
                const unsigned long long* src = (const unsigned long long*)
                    (hprev + (size_t)(b0 + ii) * HID) + tid;   // pair index = tid (0..255)
                unsigned long long v = __hip_atomic_load(src, __ATOMIC_RELAXED,
                                                         __HIP_MEMORY_SCOPE_SYSTEM);
                const float f0 = __uint_as_float((unsigned)v);
                const float f1 = __uint_as_float((unsigned)(v >> 32));
                hl32[ii * (WPAD / 2) + tid] =
                    (unsigned)f2bf(f0) | ((unsigned)f2bf(f1) << 16);
            }
        }
        __syncthreads();

        // waves 0..2: gate wv = 16 chained MFMAs over K=512
        if (wv < 3) {
            f32x4 acc = {0.f, 0.f, 0.f, 0.f};
            const int frow = ln & 15;
            const int koff = (ln >> 4) * 8;
            const unsigned short* wrow = &wlds[(wv * 16 + frow) * WPAD + koff];
            const unsigned short* hrow = &hlds[frow * WPAD + koff];
#pragma unroll
            for (int ks = 0; ks < 16; ++ks) {
                bf16x8 a = *(const bf16x8*)(hrow + ks * 32);
                bf16x8 b = *(const bf16x8*)(wrow + ks * 32);
                acc = __builtin_amdgcn_mfma_f32_16x16x32_bf16(a, b, acc, 0, 0, 0);
            }
#pragma unroll
            for (int i = 0; i < 4; ++i)                 // D: col=lane&15, row=(lane>>4)*4+i
                gpatch[wv][(ln >> 4) * 4 + i][ln & 15] = acc[i];
        }
        __syncthreads();

        // gate math in fp32
        const float rr = sigm(xr_ + gpatch[0][r][c] + bhr);
        const float zz = sigm(xz_ + gpatch[1][r][c] + bhz);
        const float nn = tanhf(xn_ + rr * (gpatch[2][r][c] + bhn));
        hreg = (1.f - zz) * nn + zz * hreg;

        __hip_atomic_store(&hnext[(size_t)(b0 + r) * HID + j0 + c], hreg,
                           __ATOMIC_RELAXED, __HIP_MEMORY_SCOPE_SYSTEM);
        if (y) y[((size_t)(b0 + r) * TT + t) * HID + j0 + c] = hreg;

        gbar(mybar, &phase);
    }

    h32[(size_t)(b0 + r) * HID + j0 + c] = hreg;   // carry to next chunk / tail
}

// ---------------- tail (unchanged) ----------------
__global__ __launch_bounds__(256) void tail_kernel(
    const float* __restrict__ hfin,
    const float* __restrict__ bn_w, const float* __restrict__ bn_b,
    const float* __restrict__ bn_mean, const float* __restrict__ bn_var,
    const float* __restrict__ fc1_w, const float* __restrict__ fc1_b,
    const float* __restrict__ ln_w, const float* __restrict__ ln_b,
    const float* __restrict__ fc2_w, const float* __restrict__ fc2_b,
    float* __restrict__ out)
{
    const int b = blockIdx.x;
    const int tid = threadIdx.x;
    __shared__ float pn[512];
    __shared__ float o1[256];
    __shared__ float red[2][4];

    for (int jj = tid; jj < 512; jj += 256) {
        float v = hfin[(size_t)b * 512 + jj];
        v = (v - bn_mean[jj]) * rsqrtf(bn_var[jj] + EPSV) * bn_w[jj] + bn_b[jj];
        pn[jj] = v;
    }
    __syncthreads();

    const float4* w1 = (const float4*)(fc1_w + (size_t)tid * 512);
    float acc = fc1_b[tid];
#pragma unroll 4
    for (int kq = 0; kq < 128; ++kq) {
        float4 w4 = w1[kq];
        float4 h4 = *(const float4*)&pn[kq * 4];
        acc = fmaf(w4.x, h4.x, acc); acc = fmaf(w4.y, h4.y, acc);
        acc = fmaf(w4.z, h4.z, acc); acc = fmaf(w4.w, h4.w, acc);
    }
    const float val = fmaxf(acc, 0.f);

    float s = val, sq = val * val;
#pragma unroll
    for (int off = 32; off >= 1; off >>= 1) {
        s  += __shfl_xor(s, off);
        sq += __shfl_xor(sq, off);
    }
    const int wv = tid >> 6, ln = tid & 63;
    if (ln == 0) { red[0][wv] = s; red[1][wv] = sq; }
    __syncthreads();
    const float S  = red[0][0] + red[0][1] + red[0][2] + red[0][3];
    const float SQ = red[1][0] + red[1][1] + red[1][2] + red[1][3];
    const float mu  = S * (1.f / 256.f);
    const float var = SQ * (1.f / 256.f) - mu * mu;
    const float nv = (val - mu) * rsqrtf(var + EPSV) * ln_w[tid] + ln_b[tid];
    o1[tid] = nv;
    __syncthreads();

    if (wv < 3) {
        const float* w2 = fc2_w + wv * 256;
        float p = w2[ln] * o1[ln] + w2[ln + 64] * o1[ln + 64]
                + w2[ln + 128] * o1[ln + 128] + w2[ln + 192] * o1[ln + 192];
#pragma unroll
        for (int off = 32; off >= 1; off >>= 1) p += __shfl_xor(p, off);
        if (ln == 0) out[b * 3 + wv] = p + fc2_b[wv];
    }
}

extern "C" void kernel_launch(void* const* d_in, const int* in_sizes, int n_in,
                              void* d_out, int out_size, void* d_ws, size_t ws_size,
                              hipStream_t stream) {
    const float* x       = (const float*)d_in[0];
    const float* w_ih0   = (const float*)d_in[1];
    const float* w_hh0   = (const float*)d_in[2];
    const float* b_ih0   = (const float*)d_in[3];
    const float* b_hh0   = (const float*)d_in[4];
    const float* w_ih1   = (const float*)d_in[5];
    const float* w_hh1   = (const float*)d_in[6];
    const float* b_ih1   = (const float*)d_in[7];
    const float* b_hh1   = (const float*)d_in[8];
    const float* bn_w    = (const float*)d_in[9];
    const float* bn_b    = (const float*)d_in[10];
    const float* bn_mean = (const float*)d_in[11];
    const float* bn_var  = (const float*)d_in[12];
    const float* fc1_w   = (const float*)d_in[13];
    const float* fc1_b   = (const float*)d_in[14];
    const float* ln_w    = (const float*)d_in[15];
    const float* ln_b    = (const float*)d_in[16];
    const float* fc2_w   = (const float*)d_in[17];
    const float* fc2_b   = (const float*)d_in[18];
    float* out = (float*)d_out;

    // ws layout (float slots): y0 | h32 | hex(2x B*H f32) | bar | xg chunk
    float* ws = (float*)d_ws;
    const size_t y0F  = (size_t)BB * TT * HID;        // 16,777,216
    const size_t h32F = (size_t)BB * HID;             //     65,536
    const size_t hexF = 2 * (size_t)BB * HID;         //    131,072
    const size_t barF = 128;
    float*        y0  = ws;
    float*        h32 = y0 + y0F;
    float*        hex = h32 + h32F;
    unsigned int* bar = (unsigned int*)(hex + hexF);
    float*        xgc = hex + hexF + barF;

    const size_t fixedF = y0F + h32F + hexF + barF;
    const size_t availF = ws_size / sizeof(float);
    int Tc = TT;
    while (Tc > 8 && fixedF + (size_t)BB * (size_t)Tc * G3 > availF) Tc >>= 1;

    for (int layer = 0; layer < 2; ++layer) {
        const float* Ain  = layer ? y0 : x;
        const int    K    = layer ? HID : IN0;
        const float* wih  = layer ? w_ih1 : w_ih0;
        const float* bih  = layer ? b_ih1 : b_ih0;
        const float* whh  = layer ? w_hh1 : w_hh0;
        const float* bhh  = layer ? b_hh1 : b_hh0;
        float*       yout = layer ? nullptr : y0;

        for (int c = 0; c < TT; c += Tc) {
            gemm_nt_bias<<<dim3(12, (BB * Tc) / 128), dim3(256), 0, stream>>>(
                Ain, wih, bih, xgc, K, c, Tc);
            hipMemsetAsync(bar, 0, barF * sizeof(float), stream);
            int t0 = c, tc = Tc;
            void* args[] = { (void*)&xgc, (void*)&whh, (void*)&bhh, (void*)&yout,
                             (void*)&h32, (void*)&hex, (void*)&bar,
                             (void*)&t0, (void*)&tc };
            hipLaunchCooperativeKernel((void*)gru_pers, dim3(NWG), dim3(256),
                                       args, 0, stream);
        }
    }

    tail_kernel<<<dim3(128), dim3(256), 0, stream>>>(
        h32, bn_w, bn_b, bn_mean, bn_var,
        fc1_w, fc1_b, ln_w, ln_b, fc2_w, fc2_b, out);
}

// Round 5
// 4119.521 us; speedup vs baseline: 9.1573x; 1.0296x over previous
//
#include <hip/hip_runtime.h>
#include <math.h>

#define BB   128
#define TT   256
#define IN0  300
#define HID  512
#define G3   1536
#define EPSV 1e-5f
#define NWG  128          // recurrence wgs: 4 bg-pairs x 32 j-groups
#define WPAD 520          // bf16 elems per LDS row (512 + 8 pad)

typedef __attribute__((ext_vector_type(8))) short bf16x8;
typedef __attribute__((ext_vector_type(4))) float f32x4;

__device__ __forceinline__ float sigm(float x) { return 1.0f / (1.0f + expf(-x)); }

__device__ __forceinline__ unsigned short f2bf(float f) {
    union { float f; unsigned u; } v; v.f = f;
    unsigned r = v.u + 0x7fffu + ((v.u >> 16) & 1u);   // RNE
    return (unsigned short)(r >> 16);
}

// dual barrier: two independent 32-wg barriers, spun by two leader threads.
// Data coherence is carried by SYSTEM-scope data accesses; __syncthreads()
// drains stores (vmcnt 0) before the arrive-add.
__device__ __forceinline__ void gbar2(unsigned int* barA, unsigned int* barB,
                                      unsigned int* phase) {
    __syncthreads();
    const unsigned tgt = (*phase) * 32u;
    if (threadIdx.x == 0) {
        __hip_atomic_fetch_add(barA, 1u, __ATOMIC_RELAXED, __HIP_MEMORY_SCOPE_AGENT);
        while (__hip_atomic_load(barA, __ATOMIC_RELAXED, __HIP_MEMORY_SCOPE_AGENT) < tgt)
            __builtin_amdgcn_s_sleep(1);
    } else if (threadIdx.x == 64) {
        __hip_atomic_fetch_add(barB, 1u, __ATOMIC_RELAXED, __HIP_MEMORY_SCOPE_AGENT);
        while (__hip_atomic_load(barB, __ATOMIC_RELAXED, __HIP_MEMORY_SCOPE_AGENT) < tgt)
            __builtin_amdgcn_s_sleep(1);
    }
    __syncthreads();
    ++(*phase);
}

// ---------------- xg GEMM (unchanged) ----------------
__global__ __launch_bounds__(256) void gemm_nt_bias(
    const float* __restrict__ A, const float* __restrict__ Bm,
    const float* __restrict__ bias, float* __restrict__ C,
    int K, int c, int Tc)
{
    __shared__ float As[8][128];
    __shared__ float Bs[8][128];
    const int n0 = blockIdx.x * 128;
    const int m0 = blockIdx.y * 128;
    const int tid = threadIdx.x;
    const int tx = tid & 15;
    const int ty = tid >> 4;

    float acc[8][8];
#pragma unroll
    for (int i = 0; i < 8; ++i)
#pragma unroll
        for (int j = 0; j < 8; ++j) acc[i][j] = 0.f;

    const int lm = tid >> 1;
    const int lk = (tid & 1) * 4;

    const int gr   = m0 + lm;
    const int brow = gr / Tc;
    const int tl   = gr - brow * Tc;
    const float* Arow = A + ((size_t)brow * TT + (size_t)(c + tl)) * K;
    const float* Brow = Bm + (size_t)(n0 + lm) * K;

    for (int k0 = 0; k0 < K; k0 += 8) {
        const int gk = k0 + lk;
        float4 av = make_float4(0.f, 0.f, 0.f, 0.f);
        float4 bv = make_float4(0.f, 0.f, 0.f, 0.f);
        if (gk < K) {
            av = *(const float4*)(Arow + gk);
            bv = *(const float4*)(Brow + gk);
        }
        As[lk + 0][lm] = av.x; As[lk + 1][lm] = av.y; As[lk + 2][lm] = av.z; As[lk + 3][lm] = av.w;
        Bs[lk + 0][lm] = bv.x; Bs[lk + 1][lm] = bv.y; Bs[lk + 2][lm] = bv.z; Bs[lk + 3][lm] = bv.w;
        __syncthreads();
#pragma unroll
        for (int kk = 0; kk < 8; ++kk) {
            float4 a0 = *(const float4*)&As[kk][ty * 8];
            float4 a1 = *(const float4*)&As[kk][ty * 8 + 4];
            float4 b0 = *(const float4*)&Bs[kk][tx * 8];
            float4 b1 = *(const float4*)&Bs[kk][tx * 8 + 4];
            float ar[8] = {a0.x, a0.y, a0.z, a0.w, a1.x, a1.y, a1.z, a1.w};
            float br[8] = {b0.x, b0.y, b0.z, b0.w, b1.x, b1.y, b1.z, b1.w};
#pragma unroll
            for (int i = 0; i < 8; ++i)
#pragma unroll
                for (int j = 0; j < 8; ++j)
                    acc[i][j] = fmaf(ar[i], br[j], acc[i][j]);
        }
        __syncthreads();
    }

#pragma unroll
    for (int i = 0; i < 8; ++i) {
        const size_t row = (size_t)(m0 + ty * 8 + i);
        float o0[4], o1[4];
#pragma unroll
        for (int j = 0; j < 4; ++j) o0[j] = acc[i][j] + bias[n0 + tx * 8 + j];
#pragma unroll
        for (int j = 0; j < 4; ++j) o1[j] = acc[i][4 + j] + bias[n0 + tx * 8 + 4 + j];
        *(float4*)(C + row * G3 + n0 + tx * 8)     = *(float4*)o0;
        *(float4*)(C + row * G3 + n0 + tx * 8 + 4) = *(float4*)o1;
    }
}

// ---------------- persistent MFMA recurrence: 2 batch-groups per wg ----------------
// 128 wgs = 4 bg-pairs (bgA=pr, bgB=pr+4) x 32 j-groups. w slice shared by both.
// h exchanged as packed bf16 via SYSTEM-scope u32/u64 (LLC-coherent, no fences).
// Two streams interleave so barrier/LLC latency of one hides under the other.
__global__ __launch_bounds__(256) void gru_pers(
    const float* __restrict__ xg,     // (B, Tc, 1536) chunk-local, b_ih folded
    const float* __restrict__ w_hh,   // (1536, 512) fp32
    const float* __restrict__ b_hh,   // (1536)
    float* __restrict__ y,            // (B,T,512) fp32 or nullptr
    float* __restrict__ h32,          // (B,512) fp32 master (chunk carry + tail)
    unsigned short* __restrict__ hbf, // 2 * B*512 bf16 ping-pong (system-scope)
    unsigned int* __restrict__ bar,   // 8 counters, 16 u32 apart
    int t0, int Tc)
{
    __shared__ unsigned short wlds[48 * WPAD];    // 49,920 B
    __shared__ unsigned short hldsA[16 * WPAD];   // 16,640 B
    __shared__ unsigned short hldsB[16 * WPAD];   // 16,640 B
    __shared__ float gpatch[2][3][16][17];        //  6,528 B

    const int wg  = blockIdx.x;       // 0..127
    const int pr  = wg >> 5;          // 0..3
    const int jg  = wg & 31;
    const int b0A = pr * 16;
    const int b0B = (pr + 4) * 16;
    const int j0  = jg * 16;
    const int tid = threadIdx.x;
    const int wv  = tid >> 6;
    const int ln  = tid & 63;
    const int r   = tid >> 4;         // patch row (batch)
    const int c   = tid & 15;         // patch col (hidden)

    unsigned int* barA = bar + pr * 16;
    unsigned int* barB = bar + (pr + 4) * 16;
    unsigned int  phase = 1;

    // load + convert my w_hh slice to LDS bf16 (once per launch)
    for (int i = tid; i < 48 * 512; i += 256) {
        const int row = i >> 9, col = i & 511;
        const int grow = (row >> 4) * HID + j0 + (row & 15);   // gate*512 + j
        wlds[row * WPAD + col] = f2bf(w_hh[(size_t)grow * HID + col]);
    }

    const float bh0 = b_hh[j0 + c];
    const float bh1 = b_hh[HID + j0 + c];
    const float bh2 = b_hh[2 * HID + j0 + c];

    unsigned short* hx0 = hbf;
    unsigned short* hx1 = hbf + BB * HID;

    float hA, hB;
    if (t0 == 0) {
        hA = hB = 0.f;
        if (!(tid & 1)) {   // zero my patches in ping buffer (u32 = 2 bf16)
            __hip_atomic_store((unsigned*)&hx0[(size_t)(b0A + r) * HID + j0 + c], 0u,
                               __ATOMIC_RELAXED, __HIP_MEMORY_SCOPE_SYSTEM);
            __hip_atomic_store((unsigned*)&hx0[(size_t)(b0B + r) * HID + j0 + c], 0u,
                               __ATOMIC_RELAXED, __HIP_MEMORY_SCOPE_SYSTEM);
        }
        gbar2(barA, barB, &phase);
    } else {
        hA = h32[(size_t)(b0A + r) * HID + j0 + c];
        hB = h32[(size_t)(b0B + r) * HID + j0 + c];
    }

    for (int t = t0; t < t0 + Tc; ++t) {
        const unsigned short* hprev = (t & 1) ? hx1 : hx0;
        unsigned short*       hnext = (t & 1) ? hx0 : hx1;

        // xg prefetch for both streams (6 scalar loads; overlap with staging)
        const float* xrA = xg + ((size_t)(b0A + r) * Tc + (t - t0)) * G3 + j0 + c;
        const float* xrB = xg + ((size_t)(b0B + r) * Tc + (t - t0)) * G3 + j0 + c;
        const float xA0 = xrA[0], xA1 = xrA[HID], xA2 = xrA[2 * HID];
        const float xB0 = xrB[0], xB1 = xrB[HID], xB2 = xrB[2 * HID];

        // stage both h blocks (bf16, 8 B per load; 16 loads in flight per thread)
        {
            const unsigned long long* srcA =
                (const unsigned long long*)(hprev + (size_t)b0A * HID);
            const unsigned long long* srcB =
                (const unsigned long long*)(hprev + (size_t)b0B * HID);
#pragma unroll
            for (int k = 0; k < 8; ++k) {
                const int i = k * 256 + tid;       // 0..2047
                const int row = i >> 7;            // 0..15
                const int q   = i & 127;           // u64 index in row (4 bf16)
                unsigned long long vA = __hip_atomic_load(srcA + row * 128 + q,
                        __ATOMIC_RELAXED, __HIP_MEMORY_SCOPE_SYSTEM);
                unsigned long long vB = __hip_atomic_load(srcB + row * 128 + q,
                        __ATOMIC_RELAXED, __HIP_MEMORY_SCOPE_SYSTEM);
                *(unsigned long long*)&hldsA[row * WPAD + q * 4] = vA;
                *(unsigned long long*)&hldsB[row * WPAD + q * 4] = vB;
            }
        }
        __syncthreads();

        // 6 gate-chains (2 streams x r/z/n) on 4 waves: w -> chain w; w<2 -> 4+w
        {
            const int frow = ln & 15;
            const int koff = (ln >> 4) * 8;
            auto chain = [&](int cid) {
                const int half = (cid >= 3) ? 1 : 0;
                const int g    = cid - half * 3;
                const unsigned short* hrow =
                    (half ? hldsB : hldsA) + frow * WPAD + koff;
                const unsigned short* wrow = wlds + (g * 16 + frow) * WPAD + koff;
                f32x4 acc = {0.f, 0.f, 0.f, 0.f};
#pragma unroll
                for (int ks = 0; ks < 16; ++ks)
                    acc = __builtin_amdgcn_mfma_f32_16x16x32_bf16(
                        *(const bf16x8*)(hrow + ks * 32),
                        *(const bf16x8*)(wrow + ks * 32), acc, 0, 0, 0);
#pragma unroll
                for (int i = 0; i < 4; ++i)   // D: col=lane&15, row=(lane>>4)*4+i
                    gpatch[half][g][(ln >> 4) * 4 + i][ln & 15] = acc[i];
            };
            chain(wv);
            if (wv < 2) chain(4 + wv);
        }
        __syncthreads();

        // gate math in fp32, both streams
        {
            const float rr = sigm(xA0 + gpatch[0][0][r][c] + bh0);
            const float zz = sigm(xA1 + gpatch[0][1][r][c] + bh1);
            const float nn = tanhf(xA2 + rr * (gpatch[0][2][r][c] + bh2));
            hA = (1.f - zz) * nn + zz * hA;
        }
        {
            const float rr = sigm(xB0 + gpatch[1][0][r][c] + bh0);
            const float zz = sigm(xB1 + gpatch[1][1][r][c] + bh1);
            const float nn = tanhf(xB2 + rr * (gpatch[1][2][r][c] + bh2));
            hB = (1.f - zz) * nn + zz * hB;
        }

        // pack bf16 pairs via shfl, even lanes store u32 system-scope
        const float oA = __shfl_xor(hA, 1);
        const float oB = __shfl_xor(hB, 1);
        if (!(tid & 1)) {
            const unsigned pA = (unsigned)f2bf(hA) | ((unsigned)f2bf(oA) << 16);
            const unsigned pB = (unsigned)f2bf(hB) | ((unsigned)f2bf(oB) << 16);
            __hip_atomic_store((unsigned*)&hnext[(size_t)(b0A + r) * HID + j0 + c], pA,
                               __ATOMIC_RELAXED, __HIP_MEMORY_SCOPE_SYSTEM);
            __hip_atomic_store((unsigned*)&hnext[(size_t)(b0B + r) * HID + j0 + c], pB,
                               __ATOMIC_RELAXED, __HIP_MEMORY_SCOPE_SYSTEM);
        }
        if (y) {
            y[((size_t)(b0A + r) * TT + t) * HID + j0 + c] = hA;
            y[((size_t)(b0B + r) * TT + t) * HID + j0 + c] = hB;
        }

        gbar2(barA, barB, &phase);
    }

    h32[(size_t)(b0A + r) * HID + j0 + c] = hA;   // carry to next chunk / tail
    h32[(size_t)(b0B + r) * HID + j0 + c] = hB;
}

// ---------------- tail (unchanged) ----------------
__global__ __launch_bounds__(256) void tail_kernel(
    const float* __restrict__ hfin,
    const float* __restrict__ bn_w, const float* __restrict__ bn_b,
    const float* __restrict__ bn_mean, const float* __restrict__ bn_var,
    const float* __restrict__ fc1_w, const float* __restrict__ fc1_b,
    const float* __restrict__ ln_w, const float* __restrict__ ln_b,
    const float* __restrict__ fc2_w, const float* __restrict__ fc2_b,
    float* __restrict__ out)
{
    const int b = blockIdx.x;
    const int tid = threadIdx.x;
    __shared__ float pn[512];
    __shared__ float o1[256];
    __shared__ float red[2][4];

    for (int jj = tid; jj < 512; jj += 256) {
        float v = hfin[(size_t)b * 512 + jj];
        v = (v - bn_mean[jj]) * rsqrtf(bn_var[jj] + EPSV) * bn_w[jj] + bn_b[jj];
        pn[jj] = v;
    }
    __syncthreads();

    const float4* w1 = (const float4*)(fc1_w + (size_t)tid * 512);
    float acc = fc1_b[tid];
#pragma unroll 4
    for (int kq = 0; kq < 128; ++kq) {
        float4 w4 = w1[kq];
        float4 h4 = *(const float4*)&pn[kq * 4];
        acc = fmaf(w4.x, h4.x, acc); acc = fmaf(w4.y, h4.y, acc);
        acc = fmaf(w4.z, h4.z, acc); acc = fmaf(w4.w, h4.w, acc);
    }
    const float val = fmaxf(acc, 0.f);

    float s = val, sq = val * val;
#pragma unroll
    for (int off = 32; off >= 1; off >>= 1) {
        s  += __shfl_xor(s, off);
        sq += __shfl_xor(sq, off);
    }
    const int wv = tid >> 6, ln = tid & 63;
    if (ln == 0) { red[0][wv] = s; red[1][wv] = sq; }
    __syncthreads();
    const float S  = red[0][0] + red[0][1] + red[0][2] + red[0][3];
    const float SQ = red[1][0] + red[1][1] + red[1][2] + red[1][3];
    const float mu  = S * (1.f / 256.f);
    const float var = SQ * (1.f / 256.f) - mu * mu;
    const float nv = (val - mu) * rsqrtf(var + EPSV) * ln_w[tid] + ln_b[tid];
    o1[tid] = nv;
    __syncthreads();

    if (wv < 3) {
        const float* w2 = fc2_w + wv * 256;
        float p = w2[ln] * o1[ln] + w2[ln + 64] * o1[ln + 64]
                + w2[ln + 128] * o1[ln + 128] + w2[ln + 192] * o1[ln + 192];
#pragma unroll
        for (int off = 32; off >= 1; off >>= 1) p += __shfl_xor(p, off);
        if (ln == 0) out[b * 3 + wv] = p + fc2_b[wv];
    }
}

extern "C" void kernel_launch(void* const* d_in, const int* in_sizes, int n_in,
                              void* d_out, int out_size, void* d_ws, size_t ws_size,
                              hipStream_t stream) {
    const float* x       = (const float*)d_in[0];
    const float* w_ih0   = (const float*)d_in[1];
    const float* w_hh0   = (const float*)d_in[2];
    const float* b_ih0   = (const float*)d_in[3];
    const float* b_hh0   = (const float*)d_in[4];
    const float* w_ih1   = (const float*)d_in[5];
    const float* w_hh1   = (const float*)d_in[6];
    const float* b_ih1   = (const float*)d_in[7];
    const float* b_hh1   = (const float*)d_in[8];
    const float* bn_w    = (const float*)d_in[9];
    const float* bn_b    = (const float*)d_in[10];
    const float* bn_mean = (const float*)d_in[11];
    const float* bn_var  = (const float*)d_in[12];
    const float* fc1_w   = (const float*)d_in[13];
    const float* fc1_b   = (const float*)d_in[14];
    const float* ln_w    = (const float*)d_in[15];
    const float* ln_b    = (const float*)d_in[16];
    const float* fc2_w   = (const float*)d_in[17];
    const float* fc2_b   = (const float*)d_in[18];
    float* out = (float*)d_out;

    // ws layout (float slots): y0 | h32 | hbf(2x B*H bf16) | bar | xg chunk
    float* ws = (float*)d_ws;
    const size_t y0F  = (size_t)BB * TT * HID;        // 16,777,216
    const size_t h32F = (size_t)BB * HID;             //     65,536
    const size_t hbfF = (size_t)BB * HID;             // 2*B*H ushort = 65,536 slots
    const size_t barF = 128;
    float*          y0  = ws;
    float*          h32 = y0 + y0F;
    unsigned short* hbf = (unsigned short*)(h32 + h32F);
    unsigned int*   bar = (unsigned int*)(h32 + h32F + hbfF);
    float*          xgc = h32 + h32F + hbfF + barF;

    const size_t fixedF = y0F + h32F + hbfF + barF;
    const size_t availF = ws_size / sizeof(float);
    int Tc = TT;
    while (Tc > 8 && fixedF + (size_t)BB * (size_t)Tc * G3 > availF) Tc >>= 1;

    for (int layer = 0; layer < 2; ++layer) {
        const float* Ain  = layer ? y0 : x;
        const int    K    = layer ? HID : IN0;
        const float* wih  = layer ? w_ih1 : w_ih0;
        const float* bih  = layer ? b_ih1 : b_ih0;
        const float* whh  = layer ? w_hh1 : w_hh0;
        const float* bhh  = layer ? b_hh1 : b_hh0;
        float*       yout = layer ? nullptr : y0;

        for (int c = 0; c < TT; c += Tc) {
            gemm_nt_bias<<<dim3(12, (BB * Tc) / 128), dim3(256), 0, stream>>>(
                Ain, wih, bih, xgc, K, c, Tc);
            hipMemsetAsync(bar, 0, barF * sizeof(float), stream);
            int t0 = c, tc = Tc;
            void* args[] = { (void*)&xgc, (void*)&whh, (void*)&bhh, (void*)&yout,
                             (void*)&h32, (void*)&hbf, (void*)&bar,
                             (void*)&t0, (void*)&tc };
            hipLaunchCooperativeKernel((void*)gru_pers, dim3(NWG), dim3(256),
                                       args, 0, stream);
        }
    }

    tail_kernel<<<dim3(128), dim3(256), 0, stream>>>(
        h32, bn_w, bn_b, bn_mean, bn_var,
        fc1_w, fc1_b, ln_w, ln_b, fc2_w, fc2_b, out);
}

// Round 6
// 3570.810 us; speedup vs baseline: 10.5645x; 1.1537x over previous
//
#include <hip/hip_runtime.h>
#include <math.h>

#define BB   128
#define TT   256
#define IN0  300
#define HID  512
#define G3   1536
#define EPSV 1e-5f
#define NWG  128          // recurrence wgs: 4 bg-pairs x 32 j-groups
#define WPAD 520          // bf16 elems per LDS row (512 + 8 pad)

typedef __attribute__((ext_vector_type(8))) short bf16x8;
typedef __attribute__((ext_vector_type(4))) float f32x4;

__device__ __forceinline__ float sigm(float x) { return 1.0f / (1.0f + expf(-x)); }

__device__ __forceinline__ unsigned short f2bf(float f) {
    union { float f; unsigned u; } v; v.f = f;
    unsigned r = v.u + 0x7fffu + ((v.u >> 16) & 1u);   // RNE
    return (unsigned short)(r >> 16);
}

// ---------------- xg GEMM (unchanged) ----------------
__global__ __launch_bounds__(256) void gemm_nt_bias(
    const float* __restrict__ A, const float* __restrict__ Bm,
    const float* __restrict__ bias, float* __restrict__ C,
    int K, int c, int Tc)
{
    __shared__ float As[8][128];
    __shared__ float Bs[8][128];
    const int n0 = blockIdx.x * 128;
    const int m0 = blockIdx.y * 128;
    const int tid = threadIdx.x;
    const int tx = tid & 15;
    const int ty = tid >> 4;

    float acc[8][8];
#pragma unroll
    for (int i = 0; i < 8; ++i)
#pragma unroll
        for (int j = 0; j < 8; ++j) acc[i][j] = 0.f;

    const int lm = tid >> 1;
    const int lk = (tid & 1) * 4;

    const int gr   = m0 + lm;
    const int brow = gr / Tc;
    const int tl   = gr - brow * Tc;
    const float* Arow = A + ((size_t)brow * TT + (size_t)(c + tl)) * K;
    const float* Brow = Bm + (size_t)(n0 + lm) * K;

    for (int k0 = 0; k0 < K; k0 += 8) {
        const int gk = k0 + lk;
        float4 av = make_float4(0.f, 0.f, 0.f, 0.f);
        float4 bv = make_float4(0.f, 0.f, 0.f, 0.f);
        if (gk < K) {
            av = *(const float4*)(Arow + gk);
            bv = *(const float4*)(Brow + gk);
        }
        As[lk + 0][lm] = av.x; As[lk + 1][lm] = av.y; As[lk + 2][lm] = av.z; As[lk + 3][lm] = av.w;
        Bs[lk + 0][lm] = bv.x; Bs[lk + 1][lm] = bv.y; Bs[lk + 2][lm] = bv.z; Bs[lk + 3][lm] = bv.w;
        __syncthreads();
#pragma unroll
        for (int kk = 0; kk < 8; ++kk) {
            float4 a0 = *(const float4*)&As[kk][ty * 8];
            float4 a1 = *(const float4*)&As[kk][ty * 8 + 4];
            float4 b0 = *(const float4*)&Bs[kk][tx * 8];
            float4 b1 = *(const float4*)&Bs[kk][tx * 8 + 4];
            float ar[8] = {a0.x, a0.y, a0.z, a0.w, a1.x, a1.y, a1.z, a1.w};
            float br[8] = {b0.x, b0.y, b0.z, b0.w, b1.x, b1.y, b1.z, b1.w};
#pragma unroll
            for (int i = 0; i < 8; ++i)
#pragma unroll
                for (int j = 0; j < 8; ++j)
                    acc[i][j] = fmaf(ar[i], br[j], acc[i][j]);
        }
        __syncthreads();
    }

#pragma unroll
    for (int i = 0; i < 8; ++i) {
        const size_t row = (size_t)(m0 + ty * 8 + i);
        float o0[4], o1[4];
#pragma unroll
        for (int j = 0; j < 4; ++j) o0[j] = acc[i][j] + bias[n0 + tx * 8 + j];
#pragma unroll
        for (int j = 0; j < 4; ++j) o1[j] = acc[i][4 + j] + bias[n0 + tx * 8 + 4 + j];
        *(float4*)(C + row * G3 + n0 + tx * 8)     = *(float4*)o0;
        *(float4*)(C + row * G3 + n0 + tx * 8 + 4) = *(float4*)o1;
    }
}

// ---------------- persistent MFMA recurrence: flag-array barrier ----------------
// 128 wgs = 4 bg-pairs (bgA=pr, bgB=pr+4) x 32 j-groups. w slice shared by both.
// h exchanged as packed bf16 via SYSTEM-scope stores/loads (LLC-coherent).
// Barrier = per-wg flag STORE (no RMW!) + wave-0 vector poll of all 64 flags.
__global__ __launch_bounds__(256) void gru_pers(
    const float* __restrict__ xg,     // (B, Tc, 1536) chunk-local, b_ih folded
    const float* __restrict__ w_hh,   // (1536, 512) fp32
    const float* __restrict__ b_hh,   // (1536)
    float* __restrict__ y,            // (B,T,512) fp32 or nullptr
    float* __restrict__ h32,          // (B,512) fp32 master (chunk carry + tail)
    unsigned short* __restrict__ hbf, // 2 * B*512 bf16 ping-pong (system-scope)
    unsigned int* __restrict__ flags, // 8 bgs x 32 jg flags (zeroed per launch)
    int t0, int Tc)
{
    __shared__ unsigned short wlds[48 * WPAD];    // 49,920 B
    __shared__ unsigned short hldsA[16 * WPAD];   // 16,640 B
    __shared__ unsigned short hldsB[16 * WPAD];   // 16,640 B
    __shared__ float gpatch[2][3][16][17];        //  6,528 B

    const int wg  = blockIdx.x;       // 0..127
    const int pr  = wg >> 5;          // 0..3
    const int jg  = wg & 31;
    const int b0A = pr * 16;
    const int b0B = (pr + 4) * 16;
    const int j0  = jg * 16;
    const int tid = threadIdx.x;
    const int wv  = tid >> 6;
    const int ln  = tid & 63;
    const int r   = tid >> 4;         // patch row (batch)
    const int c   = tid & 15;         // patch col (hidden)

    unsigned int phase = 0;

    // my flag slots + the flag I poll (wave 0: lanes 0..31 -> bgA, 32..63 -> bgB)
    unsigned int* flagA = &flags[pr * 32 + jg];
    unsigned int* flagB = &flags[(pr + 4) * 32 + jg];
    unsigned int* pollp = (tid < 32) ? &flags[pr * 32 + tid]
                                     : &flags[(pr + 4) * 32 + (tid - 32)];

    // arrive (store own flags) + wait (wave-0 vector poll), no RMW anywhere
    auto barrier = [&]() {
        __syncthreads();               // drains all threads' stores (vmcnt 0)
        ++phase;
        if (tid == 0)
            __hip_atomic_store(flagA, phase, __ATOMIC_RELAXED, __HIP_MEMORY_SCOPE_SYSTEM);
        else if (tid == 64)
            __hip_atomic_store(flagB, phase, __ATOMIC_RELAXED, __HIP_MEMORY_SCOPE_SYSTEM);
        __syncthreads();               // flag stores ordered before poll-exit reuse
        if (tid < 64) {
            while (true) {
                unsigned v = __hip_atomic_load(pollp, __ATOMIC_RELAXED,
                                               __HIP_MEMORY_SCOPE_SYSTEM);
                if (__all(v >= phase)) break;
                __builtin_amdgcn_s_sleep(1);
            }
        }
        __syncthreads();
    };

    // load + convert my w_hh slice to LDS bf16 (once per launch)
    for (int i = tid; i < 48 * 512; i += 256) {
        const int row = i >> 9, col = i & 511;
        const int grow = (row >> 4) * HID + j0 + (row & 15);   // gate*512 + j
        wlds[row * WPAD + col] = f2bf(w_hh[(size_t)grow * HID + col]);
    }

    const float bh0 = b_hh[j0 + c];
    const float bh1 = b_hh[HID + j0 + c];
    const float bh2 = b_hh[2 * HID + j0 + c];

    unsigned short* hx0 = hbf;
    unsigned short* hx1 = hbf + BB * HID;

    float hA, hB;
    if (t0 == 0) {
        hA = hB = 0.f;
        if (!(tid & 1)) {   // zero my patches in ping buffer (u32 = 2 bf16)
            __hip_atomic_store((unsigned*)&hx0[(size_t)(b0A + r) * HID + j0 + c], 0u,
                               __ATOMIC_RELAXED, __HIP_MEMORY_SCOPE_SYSTEM);
            __hip_atomic_store((unsigned*)&hx0[(size_t)(b0B + r) * HID + j0 + c], 0u,
                               __ATOMIC_RELAXED, __HIP_MEMORY_SCOPE_SYSTEM);
        }
        barrier();
    } else {
        hA = h32[(size_t)(b0A + r) * HID + j0 + c];
        hB = h32[(size_t)(b0B + r) * HID + j0 + c];
    }

    // xg prefetch for first step
    const float* xrA = xg + ((size_t)(b0A + r) * Tc) * G3 + j0 + c;
    const float* xrB = xg + ((size_t)(b0B + r) * Tc) * G3 + j0 + c;
    float xA0 = xrA[0], xA1 = xrA[HID], xA2 = xrA[2 * HID];
    float xB0 = xrB[0], xB1 = xrB[HID], xB2 = xrB[2 * HID];

    for (int t = t0; t < t0 + Tc; ++t) {
        const unsigned short* hprev = (t & 1) ? hx1 : hx0;
        unsigned short*       hnext = (t & 1) ? hx0 : hx1;

        // stage both h blocks (bf16, 8 B per load; 16 loads in flight per thread)
        {
            const unsigned long long* srcA =
                (const unsigned long long*)(hprev + (size_t)b0A * HID);
            const unsigned long long* srcB =
                (const unsigned long long*)(hprev + (size_t)b0B * HID);
#pragma unroll
            for (int k = 0; k < 8; ++k) {
                const int i = k * 256 + tid;       // 0..2047
                const int row = i >> 7;            // 0..15
                const int q   = i & 127;           // u64 index in row (4 bf16)
                unsigned long long vA = __hip_atomic_load(srcA + row * 128 + q,
                        __ATOMIC_RELAXED, __HIP_MEMORY_SCOPE_SYSTEM);
                unsigned long long vB = __hip_atomic_load(srcB + row * 128 + q,
                        __ATOMIC_RELAXED, __HIP_MEMORY_SCOPE_SYSTEM);
                *(unsigned long long*)&hldsA[row * WPAD + q * 4] = vA;
                *(unsigned long long*)&hldsB[row * WPAD + q * 4] = vB;
            }
        }
        __syncthreads();

        // 6 gate-chains (2 streams x r/z/n) on 4 waves: w -> chain w; w<2 -> 4+w
        {
            const int frow = ln & 15;
            const int koff = (ln >> 4) * 8;
            auto chain = [&](int cid) {
                const int half = (cid >= 3) ? 1 : 0;
                const int g    = cid - half * 3;
                const unsigned short* hrow =
                    (half ? hldsB : hldsA) + frow * WPAD + koff;
                const unsigned short* wrow = wlds + (g * 16 + frow) * WPAD + koff;
                f32x4 acc = {0.f, 0.f, 0.f, 0.f};
#pragma unroll
                for (int ks = 0; ks < 16; ++ks)
                    acc = __builtin_amdgcn_mfma_f32_16x16x32_bf16(
                        *(const bf16x8*)(hrow + ks * 32),
                        *(const bf16x8*)(wrow + ks * 32), acc, 0, 0, 0);
#pragma unroll
                for (int i = 0; i < 4; ++i)   // D: col=lane&15, row=(lane>>4)*4+i
                    gpatch[half][g][(ln >> 4) * 4 + i][ln & 15] = acc[i];
            };
            chain(wv);
            if (wv < 2) chain(4 + wv);
        }
        __syncthreads();

        // gate math in fp32, both streams
        {
            const float rr = sigm(xA0 + gpatch[0][0][r][c] + bh0);
            const float zz = sigm(xA1 + gpatch[0][1][r][c] + bh1);
            const float nn = tanhf(xA2 + rr * (gpatch[0][2][r][c] + bh2));
            hA = (1.f - zz) * nn + zz * hA;
        }
        {
            const float rr = sigm(xB0 + gpatch[1][0][r][c] + bh0);
            const float zz = sigm(xB1 + gpatch[1][1][r][c] + bh1);
            const float nn = tanhf(xB2 + rr * (gpatch[1][2][r][c] + bh2));
            hB = (1.f - zz) * nn + zz * hB;
        }

        // pack bf16 pairs via shfl, even lanes store u32 system-scope
        const float oA = __shfl_xor(hA, 1);
        const float oB = __shfl_xor(hB, 1);
        if (!(tid & 1)) {
            const unsigned pA = (unsigned)f2bf(hA) | ((unsigned)f2bf(oA) << 16);
            const unsigned pB = (unsigned)f2bf(hB) | ((unsigned)f2bf(oB) << 16);
            __hip_atomic_store((unsigned*)&hnext[(size_t)(b0A + r) * HID + j0 + c], pA,
                               __ATOMIC_RELAXED, __HIP_MEMORY_SCOPE_SYSTEM);
            __hip_atomic_store((unsigned*)&hnext[(size_t)(b0B + r) * HID + j0 + c], pB,
                               __ATOMIC_RELAXED, __HIP_MEMORY_SCOPE_SYSTEM);
        }
        if (y) {
            y[((size_t)(b0A + r) * TT + t) * HID + j0 + c] = hA;
            y[((size_t)(b0B + r) * TT + t) * HID + j0 + c] = hB;
        }

        // arrive; prefetch next step's xg in the shadow of the poll; wait
        __syncthreads();               // drain data stores
        ++phase;
        if (tid == 0)
            __hip_atomic_store(flagA, phase, __ATOMIC_RELAXED, __HIP_MEMORY_SCOPE_SYSTEM);
        else if (tid == 64)
            __hip_atomic_store(flagB, phase, __ATOMIC_RELAXED, __HIP_MEMORY_SCOPE_SYSTEM);

        if (t + 1 < t0 + Tc) {         // xg prefetch overlaps the poll below
            const float* nA = xg + ((size_t)(b0A + r) * Tc + (t + 1 - t0)) * G3 + j0 + c;
            const float* nB = xg + ((size_t)(b0B + r) * Tc + (t + 1 - t0)) * G3 + j0 + c;
            xA0 = nA[0]; xA1 = nA[HID]; xA2 = nA[2 * HID];
            xB0 = nB[0]; xB1 = nB[HID]; xB2 = nB[2 * HID];
        }

        if (tid < 64) {
            while (true) {
                unsigned v = __hip_atomic_load(pollp, __ATOMIC_RELAXED,
                                               __HIP_MEMORY_SCOPE_SYSTEM);
                if (__all(v >= phase)) break;
                __builtin_amdgcn_s_sleep(1);
            }
        }
        __syncthreads();
    }

    h32[(size_t)(b0A + r) * HID + j0 + c] = hA;   // carry to next chunk / tail
    h32[(size_t)(b0B + r) * HID + j0 + c] = hB;
}

// ---------------- tail (unchanged) ----------------
__global__ __launch_bounds__(256) void tail_kernel(
    const float* __restrict__ hfin,
    const float* __restrict__ bn_w, const float* __restrict__ bn_b,
    const float* __restrict__ bn_mean, const float* __restrict__ bn_var,
    const float* __restrict__ fc1_w, const float* __restrict__ fc1_b,
    const float* __restrict__ ln_w, const float* __restrict__ ln_b,
    const float* __restrict__ fc2_w, const float* __restrict__ fc2_b,
    float* __restrict__ out)
{
    const int b = blockIdx.x;
    const int tid = threadIdx.x;
    __shared__ float pn[512];
    __shared__ float o1[256];
    __shared__ float red[2][4];

    for (int jj = tid; jj < 512; jj += 256) {
        float v = hfin[(size_t)b * 512 + jj];
        v = (v - bn_mean[jj]) * rsqrtf(bn_var[jj] + EPSV) * bn_w[jj] + bn_b[jj];
        pn[jj] = v;
    }
    __syncthreads();

    const float4* w1 = (const float4*)(fc1_w + (size_t)tid * 512);
    float acc = fc1_b[tid];
#pragma unroll 4
    for (int kq = 0; kq < 128; ++kq) {
        float4 w4 = w1[kq];
        float4 h4 = *(const float4*)&pn[kq * 4];
        acc = fmaf(w4.x, h4.x, acc); acc = fmaf(w4.y, h4.y, acc);
        acc = fmaf(w4.z, h4.z, acc); acc = fmaf(w4.w, h4.w, acc);
    }
    const float val = fmaxf(acc, 0.f);

    float s = val, sq = val * val;
#pragma unroll
    for (int off = 32; off >= 1; off >>= 1) {
        s  += __shfl_xor(s, off);
        sq += __shfl_xor(sq, off);
    }
    const int wv = tid >> 6, ln = tid & 63;
    if (ln == 0) { red[0][wv] = s; red[1][wv] = sq; }
    __syncthreads();
    const float S  = red[0][0] + red[0][1] + red[0][2] + red[0][3];
    const float SQ = red[1][0] + red[1][1] + red[1][2] + red[1][3];
    const float mu  = S * (1.f / 256.f);
    const float var = SQ * (1.f / 256.f) - mu * mu;
    const float nv = (val - mu) * rsqrtf(var + EPSV) * ln_w[tid] + ln_b[tid];
    o1[tid] = nv;
    __syncthreads();

    if (wv < 3) {
        const float* w2 = fc2_w + wv * 256;
        float p = w2[ln] * o1[ln] + w2[ln + 64] * o1[ln + 64]
                + w2[ln + 128] * o1[ln + 128] + w2[ln + 192] * o1[ln + 192];
#pragma unroll
        for (int off = 32; off >= 1; off >>= 1) p += __shfl_xor(p, off);
        if (ln == 0) out[b * 3 + wv] = p + fc2_b[wv];
    }
}

extern "C" void kernel_launch(void* const* d_in, const int* in_sizes, int n_in,
                              void* d_out, int out_size, void* d_ws, size_t ws_size,
                              hipStream_t stream) {
    const float* x       = (const float*)d_in[0];
    const float* w_ih0   = (const float*)d_in[1];
    const float* w_hh0   = (const float*)d_in[2];
    const float* b_ih0   = (const float*)d_in[3];
    const float* b_hh0   = (const float*)d_in[4];
    const float* w_ih1   = (const float*)d_in[5];
    const float* w_hh1   = (const float*)d_in[6];
    const float* b_ih1   = (const float*)d_in[7];
    const float* b_hh1   = (const float*)d_in[8];
    const float* bn_w    = (const float*)d_in[9];
    const float* bn_b    = (const float*)d_in[10];
    const float* bn_mean = (const float*)d_in[11];
    const float* bn_var  = (const float*)d_in[12];
    const float* fc1_w   = (const float*)d_in[13];
    const float* fc1_b   = (const float*)d_in[14];
    const float* ln_w    = (const float*)d_in[15];
    const float* ln_b    = (const float*)d_in[16];
    const float* fc2_w   = (const float*)d_in[17];
    const float* fc2_b   = (const float*)d_in[18];
    float* out = (float*)d_out;

    // ws layout (float slots): y0 | h32 | hbf(2x B*H bf16) | flags | xg chunk
    float* ws = (float*)d_ws;
    const size_t y0F  = (size_t)BB * TT * HID;        // 16,777,216
    const size_t h32F = (size_t)BB * HID;             //     65,536
    const size_t hbfF = (size_t)BB * HID;             // 2*B*H ushort = 65,536 slots
    const size_t barF = 256;                          // 8 bgs x 32 jg flags
    float*          y0  = ws;
    float*          h32 = y0 + y0F;
    unsigned short* hbf = (unsigned short*)(h32 + h32F);
    unsigned int*   bar = (unsigned int*)(h32 + h32F + hbfF);
    float*          xgc = h32 + h32F + hbfF + barF;

    const size_t fixedF = y0F + h32F + hbfF + barF;
    const size_t availF = ws_size / sizeof(float);
    int Tc = TT;
    while (Tc > 8 && fixedF + (size_t)BB * (size_t)Tc * G3 > availF) Tc >>= 1;

    for (int layer = 0; layer < 2; ++layer) {
        const float* Ain  = layer ? y0 : x;
        const int    K    = layer ? HID : IN0;
        const float* wih  = layer ? w_ih1 : w_ih0;
        const float* bih  = layer ? b_ih1 : b_ih0;
        const float* whh  = layer ? w_hh1 : w_hh0;
        const float* bhh  = layer ? b_hh1 : b_hh0;
        float*       yout = layer ? nullptr : y0;

        for (int c = 0; c < TT; c += Tc) {
            gemm_nt_bias<<<dim3(12, (BB * Tc) / 128), dim3(256), 0, stream>>>(
                Ain, wih, bih, xgc, K, c, Tc);
            hipMemsetAsync(bar, 0, barF * sizeof(float), stream);
            int t0 = c, tc = Tc;
            void* args[] = { (void*)&xgc, (void*)&whh, (void*)&bhh, (void*)&yout,
                             (void*)&h32, (void*)&hbf, (void*)&bar,
                             (void*)&t0, (void*)&tc };
            hipLaunchCooperativeKernel((void*)gru_pers, dim3(NWG), dim3(256),
                                       args, 0, stream);
        }
    }

    tail_kernel<<<dim3(128), dim3(256), 0, stream>>>(
        h32, bn_w, bn_b, bn_mean, bn_var,
        fc1_w, fc1_b, ln_w, ln_b, fc2_w, fc2_b, out);
}

// Round 9
// 2880.166 us; speedup vs baseline: 13.0977x; 1.2398x over previous
//
#include <hip/hip_runtime.h>
#include <math.h>

#define BB   128
#define TT   256
#define IN0  300
#define HID  512
#define G3   1536
#define EPSV 1e-5f
#define NWG  128          // recurrence wgs: 4 bg-pairs x 32 j-groups
#define WPAD 520          // bf16 elems per LDS row (512 + 8 pad)

typedef __attribute__((ext_vector_type(8))) short bf16x8;
typedef __attribute__((ext_vector_type(4))) float f32x4;

__device__ __forceinline__ float sigm(float x) { return 1.0f / (1.0f + expf(-x)); }

__device__ __forceinline__ unsigned short f2bf(float f) {
    union { float f; unsigned u; } v; v.f = f;
    unsigned r = v.u + 0x7fffu + ((v.u >> 16) & 1u);   // RNE
    return (unsigned short)(r >> 16);
}

// ---------------- bf16-MFMA xg GEMM ----------------
// C[m,n] = A_rows @ B[N,K]^T + bias, chunk-local rows; C is (B*Tc, 1536) fp32.
// 128x128 tile, 4 waves x 64x64 quadrant, K-step 32 (one 16x16x32 MFMA per
// sub-tile per step). Fragment mapping identical to the proven gru_pers MFMAs.
__global__ __launch_bounds__(256) void gemm_mfma_bias(
    const float* __restrict__ A, const float* __restrict__ Bm,
    const float* __restrict__ bias, float* __restrict__ C,
    int K, int c, int Tc)
{
    __shared__ unsigned short Abf[128][40];   // 40 ushorts = 80 B row (16B-aligned)
    __shared__ unsigned short Bbf[128][40];

    const int n0  = blockIdx.x * 128;
    const int m0  = blockIdx.y * 128;
    const int tid = threadIdx.x;
    const int wvi = tid >> 6;
    const int ln  = tid & 63;
    const int qr  = (wvi >> 1) * 64;   // quadrant row base
    const int qc  = (wvi & 1) * 64;    // quadrant col base
    const int frow = ln & 15;
    const int koff = (ln >> 4) * 8;

    f32x4 acc[4][4];
#pragma unroll
    for (int i = 0; i < 4; ++i)
#pragma unroll
        for (int j = 0; j < 4; ++j) acc[i][j] = (f32x4){0.f, 0.f, 0.f, 0.f};

    // staging assignment: thread -> (row, 16-col half)
    const int lr = tid >> 1;
    const int lc = (tid & 1) * 16;

    const int gr   = m0 + lr;
    const int brow = gr / Tc;
    const int tl   = gr - brow * Tc;
    const float* Arow = A + ((size_t)brow * TT + (size_t)(c + tl)) * K;
    const float* Brow = Bm + (size_t)(n0 + lr) * K;

    const int nk = (K + 31) >> 5;
    for (int kt = 0; kt < nk; ++kt) {
        const int k0 = kt * 32;
        float a[16], b[16];
        if (k0 + 32 <= K) {
            float4 v;
#pragma unroll
            for (int j = 0; j < 4; ++j) {
                v = *(const float4*)(Arow + k0 + lc + j * 4);
                a[j*4+0] = v.x; a[j*4+1] = v.y; a[j*4+2] = v.z; a[j*4+3] = v.w;
                v = *(const float4*)(Brow + k0 + lc + j * 4);
                b[j*4+0] = v.x; b[j*4+1] = v.y; b[j*4+2] = v.z; b[j*4+3] = v.w;
            }
        } else {
#pragma unroll
            for (int j = 0; j < 16; ++j) {
                const int gk = k0 + lc + j;
                a[j] = (gk < K) ? Arow[gk] : 0.f;
                b[j] = (gk < K) ? Brow[gk] : 0.f;
            }
        }
        bf16x8 pa0, pa1, pb0, pb1;
#pragma unroll
        for (int j = 0; j < 8; ++j) {
            pa0[j] = (short)f2bf(a[j]);     pa1[j] = (short)f2bf(a[8 + j]);
            pb0[j] = (short)f2bf(b[j]);     pb1[j] = (short)f2bf(b[8 + j]);
        }
        *(bf16x8*)&Abf[lr][lc]     = pa0;
        *(bf16x8*)&Abf[lr][lc + 8] = pa1;
        *(bf16x8*)&Bbf[lr][lc]     = pb0;
        *(bf16x8*)&Bbf[lr][lc + 8] = pb1;
        __syncthreads();

        bf16x8 af[4], bfv[4];
#pragma unroll
        for (int rt = 0; rt < 4; ++rt)
            af[rt] = *(const bf16x8*)&Abf[qr + rt * 16 + frow][koff];
#pragma unroll
        for (int ct = 0; ct < 4; ++ct)
            bfv[ct] = *(const bf16x8*)&Bbf[qc + ct * 16 + frow][koff];
#pragma unroll
        for (int rt = 0; rt < 4; ++rt)
#pragma unroll
            for (int ct = 0; ct < 4; ++ct)
                acc[rt][ct] = __builtin_amdgcn_mfma_f32_16x16x32_bf16(
                    af[rt], bfv[ct], acc[rt][ct], 0, 0, 0);
        __syncthreads();
    }

    // epilogue: D row=(ln>>4)*4+i, col=ln&15 (m89-verified mapping)
#pragma unroll
    for (int ct = 0; ct < 4; ++ct) {
        const int colg = n0 + qc + ct * 16 + (ln & 15);
        const float bv = bias[colg];
#pragma unroll
        for (int rt = 0; rt < 4; ++rt) {
#pragma unroll
            for (int i = 0; i < 4; ++i) {
                const int rowg = m0 + qr + rt * 16 + (ln >> 4) * 4 + i;
                C[(size_t)rowg * G3 + colg] = acc[rt][ct][i] + bv;
            }
        }
    }
}

// ---------------- persistent MFMA recurrence (ROUND-6 PROVEN, verbatim) ----------------
// 128 wgs = 4 bg-pairs (bgA=pr, bgB=pr+4) x 32 j-groups. w slice shared by both.
// h exchanged as packed bf16 via SYSTEM-scope stores/loads (LLC-coherent).
// Barrier = per-wg flag STORE (no RMW) + wave-0 vector poll of all 64 flags.
__global__ __launch_bounds__(256) void gru_pers(
    const float* __restrict__ xg,     // (B, Tc, 1536) chunk-local, b_ih folded
    const float* __restrict__ w_hh,   // (1536, 512) fp32
    const float* __restrict__ b_hh,   // (1536)
    float* __restrict__ y,            // (B,T,512) fp32 or nullptr
    float* __restrict__ h32,          // (B,512) fp32 master (chunk carry + tail)
    unsigned short* __restrict__ hbf, // 2 * B*512 bf16 ping-pong (system-scope)
    unsigned int* __restrict__ flags, // 8 bgs x 32 jg flags (zeroed per launch)
    int t0, int Tc)
{
    __shared__ unsigned short wlds[48 * WPAD];    // 49,920 B
    __shared__ unsigned short hldsA[16 * WPAD];   // 16,640 B
    __shared__ unsigned short hldsB[16 * WPAD];   // 16,640 B
    __shared__ float gpatch[2][3][16][17];        //  6,528 B

    const int wg  = blockIdx.x;       // 0..127
    const int pr  = wg >> 5;          // 0..3
    const int jg  = wg & 31;
    const int b0A = pr * 16;
    const int b0B = (pr + 4) * 16;
    const int j0  = jg * 16;
    const int tid = threadIdx.x;
    const int wv  = tid >> 6;
    const int ln  = tid & 63;
    const int r   = tid >> 4;         // patch row (batch)
    const int c   = tid & 15;         // patch col (hidden)

    unsigned int phase = 0;

    unsigned int* flagA = &flags[pr * 32 + jg];
    unsigned int* flagB = &flags[(pr + 4) * 32 + jg];
    unsigned int* pollp = (tid < 32) ? &flags[pr * 32 + tid]
                                     : &flags[(pr + 4) * 32 + (tid - 32)];

    auto barrier = [&]() {
        __syncthreads();
        ++phase;
        if (tid == 0)
            __hip_atomic_store(flagA, phase, __ATOMIC_RELAXED, __HIP_MEMORY_SCOPE_SYSTEM);
        else if (tid == 64)
            __hip_atomic_store(flagB, phase, __ATOMIC_RELAXED, __HIP_MEMORY_SCOPE_SYSTEM);
        __syncthreads();
        if (tid < 64) {
            while (true) {
                unsigned v = __hip_atomic_load(pollp, __ATOMIC_RELAXED,
                                               __HIP_MEMORY_SCOPE_SYSTEM);
                if (__all(v >= phase)) break;
                __builtin_amdgcn_s_sleep(1);
            }
        }
        __syncthreads();
    };

    // load + convert my w_hh slice to LDS bf16 (once per launch)
    for (int i = tid; i < 48 * 512; i += 256) {
        const int row = i >> 9, col = i & 511;
        const int grow = (row >> 4) * HID + j0 + (row & 15);   // gate*512 + j
        wlds[row * WPAD + col] = f2bf(w_hh[(size_t)grow * HID + col]);
    }

    const float bh0 = b_hh[j0 + c];
    const float bh1 = b_hh[HID + j0 + c];
    const float bh2 = b_hh[2 * HID + j0 + c];

    unsigned short* hx0 = hbf;
    unsigned short* hx1 = hbf + BB * HID;

    float hA, hB;
    if (t0 == 0) {
        hA = hB = 0.f;
        if (!(tid & 1)) {
            __hip_atomic_store((unsigned*)&hx0[(size_t)(b0A + r) * HID + j0 + c], 0u,
                               __ATOMIC_RELAXED, __HIP_MEMORY_SCOPE_SYSTEM);
            __hip_atomic_store((unsigned*)&hx0[(size_t)(b0B + r) * HID + j0 + c], 0u,
                               __ATOMIC_RELAXED, __HIP_MEMORY_SCOPE_SYSTEM);
        }
        barrier();
    } else {
        hA = h32[(size_t)(b0A + r) * HID + j0 + c];
        hB = h32[(size_t)(b0B + r) * HID + j0 + c];
    }

    // xg prefetch for first step
    const float* xrA = xg + ((size_t)(b0A + r) * Tc) * G3 + j0 + c;
    const float* xrB = xg + ((size_t)(b0B + r) * Tc) * G3 + j0 + c;
    float xA0 = xrA[0], xA1 = xrA[HID], xA2 = xrA[2 * HID];
    float xB0 = xrB[0], xB1 = xrB[HID], xB2 = xrB[2 * HID];

    for (int t = t0; t < t0 + Tc; ++t) {
        const unsigned short* hprev = (t & 1) ? hx1 : hx0;
        unsigned short*       hnext = (t & 1) ? hx0 : hx1;

        // stage both h blocks (bf16, 8 B per load; 16 loads in flight per thread)
        {
            const unsigned long long* srcA =
                (const unsigned long long*)(hprev + (size_t)b0A * HID);
            const unsigned long long* srcB =
                (const unsigned long long*)(hprev + (size_t)b0B * HID);
#pragma unroll
            for (int k = 0; k < 8; ++k) {
                const int i = k * 256 + tid;       // 0..2047
                const int row = i >> 7;            // 0..15
                const int q   = i & 127;           // u64 index in row (4 bf16)
                unsigned long long vA = __hip_atomic_load(srcA + row * 128 + q,
                        __ATOMIC_RELAXED, __HIP_MEMORY_SCOPE_SYSTEM);
                unsigned long long vB = __hip_atomic_load(srcB + row * 128 + q,
                        __ATOMIC_RELAXED, __HIP_MEMORY_SCOPE_SYSTEM);
                *(unsigned long long*)&hldsA[row * WPAD + q * 4] = vA;
                *(unsigned long long*)&hldsB[row * WPAD + q * 4] = vB;
            }
        }
        __syncthreads();

        // 6 gate-chains (2 streams x r/z/n) on 4 waves: w -> chain w; w<2 -> 4+w
        {
            const int frow = ln & 15;
            const int koff = (ln >> 4) * 8;
            auto chain = [&](int cid) {
                const int half = (cid >= 3) ? 1 : 0;
                const int g    = cid - half * 3;
                const unsigned short* hrow =
                    (half ? hldsB : hldsA) + frow * WPAD + koff;
                const unsigned short* wrow = wlds + (g * 16 + frow) * WPAD + koff;
                f32x4 acc = {0.f, 0.f, 0.f, 0.f};
#pragma unroll
                for (int ks = 0; ks < 16; ++ks)
                    acc = __builtin_amdgcn_mfma_f32_16x16x32_bf16(
                        *(const bf16x8*)(hrow + ks * 32),
                        *(const bf16x8*)(wrow + ks * 32), acc, 0, 0, 0);
#pragma unroll
                for (int i = 0; i < 4; ++i)   // D: col=lane&15, row=(lane>>4)*4+i
                    gpatch[half][g][(ln >> 4) * 4 + i][ln & 15] = acc[i];
            };
            chain(wv);
            if (wv < 2) chain(4 + wv);
        }
        __syncthreads();

        // gate math in fp32, both streams
        {
            const float rr = sigm(xA0 + gpatch[0][0][r][c] + bh0);
            const float zz = sigm(xA1 + gpatch[0][1][r][c] + bh1);
            const float nn = tanhf(xA2 + rr * (gpatch[0][2][r][c] + bh2));
            hA = (1.f - zz) * nn + zz * hA;
        }
        {
            const float rr = sigm(xB0 + gpatch[1][0][r][c] + bh0);
            const float zz = sigm(xB1 + gpatch[1][1][r][c] + bh1);
            const float nn = tanhf(xB2 + rr * (gpatch[1][2][r][c] + bh2));
            hB = (1.f - zz) * nn + zz * hB;
        }

        // pack bf16 pairs via shfl, even lanes store u32 system-scope
        const float oA = __shfl_xor(hA, 1);
        const float oB = __shfl_xor(hB, 1);
        if (!(tid & 1)) {
            const unsigned pA = (unsigned)f2bf(hA) | ((unsigned)f2bf(oA) << 16);
            const unsigned pB = (unsigned)f2bf(hB) | ((unsigned)f2bf(oB) << 16);
            __hip_atomic_store((unsigned*)&hnext[(size_t)(b0A + r) * HID + j0 + c], pA,
                               __ATOMIC_RELAXED, __HIP_MEMORY_SCOPE_SYSTEM);
            __hip_atomic_store((unsigned*)&hnext[(size_t)(b0B + r) * HID + j0 + c], pB,
                               __ATOMIC_RELAXED, __HIP_MEMORY_SCOPE_SYSTEM);
        }
        if (y) {
            y[((size_t)(b0A + r) * TT + t) * HID + j0 + c] = hA;
            y[((size_t)(b0B + r) * TT + t) * HID + j0 + c] = hB;
        }

        // arrive; prefetch next step's xg in the shadow of the poll; wait
        __syncthreads();               // drain data stores
        ++phase;
        if (tid == 0)
            __hip_atomic_store(flagA, phase, __ATOMIC_RELAXED, __HIP_MEMORY_SCOPE_SYSTEM);
        else if (tid == 64)
            __hip_atomic_store(flagB, phase, __ATOMIC_RELAXED, __HIP_MEMORY_SCOPE_SYSTEM);

        if (t + 1 < t0 + Tc) {         // xg prefetch overlaps the poll below
            const float* nA = xg + ((size_t)(b0A + r) * Tc + (t + 1 - t0)) * G3 + j0 + c;
            const float* nB = xg + ((size_t)(b0B + r) * Tc + (t + 1 - t0)) * G3 + j0 + c;
            xA0 = nA[0]; xA1 = nA[HID]; xA2 = nA[2 * HID];
            xB0 = nB[0]; xB1 = nB[HID]; xB2 = nB[2 * HID];
        }

        if (tid < 64) {
            while (true) {
                unsigned v = __hip_atomic_load(pollp, __ATOMIC_RELAXED,
                                               __HIP_MEMORY_SCOPE_SYSTEM);
                if (__all(v >= phase)) break;
                __builtin_amdgcn_s_sleep(1);
            }
        }
        __syncthreads();
    }

    h32[(size_t)(b0A + r) * HID + j0 + c] = hA;   // carry to next chunk / tail
    h32[(size_t)(b0B + r) * HID + j0 + c] = hB;
}

// ---------------- tail (unchanged) ----------------
__global__ __launch_bounds__(256) void tail_kernel(
    const float* __restrict__ hfin,
    const float* __restrict__ bn_w, const float* __restrict__ bn_b,
    const float* __restrict__ bn_mean, const float* __restrict__ bn_var,
    const float* __restrict__ fc1_w, const float* __restrict__ fc1_b,
    const float* __restrict__ ln_w, const float* __restrict__ ln_b,
    const float* __restrict__ fc2_w, const float* __restrict__ fc2_b,
    float* __restrict__ out)
{
    const int b = blockIdx.x;
    const int tid = threadIdx.x;
    __shared__ float pn[512];
    __shared__ float o1[256];
    __shared__ float red[2][4];

    for (int jj = tid; jj < 512; jj += 256) {
        float v = hfin[(size_t)b * 512 + jj];
        v = (v - bn_mean[jj]) * rsqrtf(bn_var[jj] + EPSV) * bn_w[jj] + bn_b[jj];
        pn[jj] = v;
    }
    __syncthreads();

    const float4* w1 = (const float4*)(fc1_w + (size_t)tid * 512);
    float acc = fc1_b[tid];
#pragma unroll 4
    for (int kq = 0; kq < 128; ++kq) {
        float4 w4 = w1[kq];
        float4 h4 = *(const float4*)&pn[kq * 4];
        acc = fmaf(w4.x, h4.x, acc); acc = fmaf(w4.y, h4.y, acc);
        acc = fmaf(w4.z, h4.z, acc); acc = fmaf(w4.w, h4.w, acc);
    }
    const float val = fmaxf(acc, 0.f);

    float s = val, sq = val * val;
#pragma unroll
    for (int off = 32; off >= 1; off >>= 1) {
        s  += __shfl_xor(s, off);
        sq += __shfl_xor(sq, off);
    }
    const int wv = tid >> 6, ln = tid & 63;
    if (ln == 0) { red[0][wv] = s; red[1][wv] = sq; }
    __syncthreads();
    const float S  = red[0][0] + red[0][1] + red[0][2] + red[0][3];
    const float SQ = red[1][0] + red[1][1] + red[1][2] + red[1][3];
    const float mu  = S * (1.f / 256.f);
    const float var = SQ * (1.f / 256.f) - mu * mu;
    const float nv = (val - mu) * rsqrtf(var + EPSV) * ln_w[tid] + ln_b[tid];
    o1[tid] = nv;
    __syncthreads();

    if (wv < 3) {
        const float* w2 = fc2_w + wv * 256;
        float p = w2[ln] * o1[ln] + w2[ln + 64] * o1[ln + 64]
                + w2[ln + 128] * o1[ln + 128] + w2[ln + 192] * o1[ln + 192];
#pragma unroll
        for (int off = 32; off >= 1; off >>= 1) p += __shfl_xor(p, off);
        if (ln == 0) out[b * 3 + wv] = p + fc2_b[wv];
    }
}

extern "C" void kernel_launch(void* const* d_in, const int* in_sizes, int n_in,
                              void* d_out, int out_size, void* d_ws, size_t ws_size,
                              hipStream_t stream) {
    const float* x       = (const float*)d_in[0];
    const float* w_ih0   = (const float*)d_in[1];
    const float* w_hh0   = (const float*)d_in[2];
    const float* b_ih0   = (const float*)d_in[3];
    const float* b_hh0   = (const float*)d_in[4];
    const float* w_ih1   = (const float*)d_in[5];
    const float* w_hh1   = (const float*)d_in[6];
    const float* b_ih1   = (const float*)d_in[7];
    const float* b_hh1   = (const float*)d_in[8];
    const float* bn_w    = (const float*)d_in[9];
    const float* bn_b    = (const float*)d_in[10];
    const float* bn_mean = (const float*)d_in[11];
    const float* bn_var  = (const float*)d_in[12];
    const float* fc1_w   = (const float*)d_in[13];
    const float* fc1_b   = (const float*)d_in[14];
    const float* ln_w    = (const float*)d_in[15];
    const float* ln_b    = (const float*)d_in[16];
    const float* fc2_w   = (const float*)d_in[17];
    const float* fc2_b   = (const float*)d_in[18];
    float* out = (float*)d_out;

    // ws layout (float slots): y0 | h32 | hbf(2x B*H bf16) | flags | xg chunk
    float* ws = (float*)d_ws;
    const size_t y0F  = (size_t)BB * TT * HID;        // 16,777,216
    const size_t h32F = (size_t)BB * HID;             //     65,536
    const size_t hbfF = (size_t)BB * HID;             // 2*B*H ushort = 65,536 slots
    const size_t barF = 256;                          // 8 bgs x 32 jg flags
    float*          y0  = ws;
    float*          h32 = y0 + y0F;
    unsigned short* hbf = (unsigned short*)(h32 + h32F);
    unsigned int*   bar = (unsigned int*)(h32 + h32F + hbfF);
    float*          xgc = h32 + h32F + hbfF + barF;

    const size_t fixedF = y0F + h32F + hbfF + barF;
    const size_t availF = ws_size / sizeof(float);
    int Tc = TT;
    while (Tc > 8 && fixedF + (size_t)BB * (size_t)Tc * G3 > availF) Tc >>= 1;

    for (int layer = 0; layer < 2; ++layer) {
        const float* Ain  = layer ? y0 : x;
        const int    K    = layer ? HID : IN0;
        const float* wih  = layer ? w_ih1 : w_ih0;
        const float* bih  = layer ? b_ih1 : b_ih0;
        const float* whh  = layer ? w_hh1 : w_hh0;
        const float* bhh  = layer ? b_hh1 : b_hh0;
        float*       yout = layer ? nullptr : y0;

        for (int c = 0; c < TT; c += Tc) {
            gemm_mfma_bias<<<dim3(12, (BB * Tc) / 128), dim3(256), 0, stream>>>(
                Ain, wih, bih, xgc, K, c, Tc);
            hipMemsetAsync(bar, 0, barF * sizeof(float), stream);
            int t0 = c, tc = Tc;
            void* args[] = { (void*)&xgc, (void*)&whh, (void*)&bhh, (void*)&yout,
                             (void*)&h32, (void*)&hbf, (void*)&bar,
                             (void*)&t0, (void*)&tc };
            hipLaunchCooperativeKernel((void*)gru_pers, dim3(NWG), dim3(256),
                                       args, 0, stream);
        }
    }

    tail_kernel<<<dim3(128), dim3(256), 0, stream>>>(
        h32, bn_w, bn_b, bn_mean, bn_var,
        fc1_w, fc1_b, ln_w, ln_b, fc2_w, fc2_b, out);
}

// Round 10
// 2257.181 us; speedup vs baseline: 16.7127x; 1.2760x over previous
//
#include <hip/hip_runtime.h>
#include <math.h>

#define BB   128
#define TT   256
#define IN0  300
#define HID  512
#define G3   1536
#define EPSV 1e-5f
#define WPAD 520          // bf16 elems per LDS row (512 + 8 pad)

typedef __attribute__((ext_vector_type(8))) short bf16x8;
typedef __attribute__((ext_vector_type(4))) float f32x4;

__device__ __forceinline__ float sigm(float x) { return 1.0f / (1.0f + expf(-x)); }

__device__ __forceinline__ unsigned short f2bf(float f) {
    union { float f; unsigned u; } v; v.f = f;
    unsigned r = v.u + 0x7fffu + ((v.u >> 16) & 1u);   // RNE
    return (unsigned short)(r >> 16);
}

// ---------------- bf16-MFMA xg GEMM (round-9 proven; layer 0 only now) ----------------
__global__ __launch_bounds__(256) void gemm_mfma_bias(
    const float* __restrict__ A, const float* __restrict__ Bm,
    const float* __restrict__ bias, float* __restrict__ C,
    int K, int c, int Tc)
{
    __shared__ unsigned short Abf[128][40];
    __shared__ unsigned short Bbf[128][40];

    const int n0  = blockIdx.x * 128;
    const int m0  = blockIdx.y * 128;
    const int tid = threadIdx.x;
    const int wvi = tid >> 6;
    const int ln  = tid & 63;
    const int qr  = (wvi >> 1) * 64;
    const int qc  = (wvi & 1) * 64;
    const int frow = ln & 15;
    const int koff = (ln >> 4) * 8;

    f32x4 acc[4][4];
#pragma unroll
    for (int i = 0; i < 4; ++i)
#pragma unroll
        for (int j = 0; j < 4; ++j) acc[i][j] = (f32x4){0.f, 0.f, 0.f, 0.f};

    const int lr = tid >> 1;
    const int lc = (tid & 1) * 16;

    const int gr   = m0 + lr;
    const int brow = gr / Tc;
    const int tl   = gr - brow * Tc;
    const float* Arow = A + ((size_t)brow * TT + (size_t)(c + tl)) * K;
    const float* Brow = Bm + (size_t)(n0 + lr) * K;

    const int nk = (K + 31) >> 5;
    for (int kt = 0; kt < nk; ++kt) {
        const int k0 = kt * 32;
        float a[16], b[16];
        if (k0 + 32 <= K) {
            float4 v;
#pragma unroll
            for (int j = 0; j < 4; ++j) {
                v = *(const float4*)(Arow + k0 + lc + j * 4);
                a[j*4+0] = v.x; a[j*4+1] = v.y; a[j*4+2] = v.z; a[j*4+3] = v.w;
                v = *(const float4*)(Brow + k0 + lc + j * 4);
                b[j*4+0] = v.x; b[j*4+1] = v.y; b[j*4+2] = v.z; b[j*4+3] = v.w;
            }
        } else {
#pragma unroll
            for (int j = 0; j < 16; ++j) {
                const int gk = k0 + lc + j;
                a[j] = (gk < K) ? Arow[gk] : 0.f;
                b[j] = (gk < K) ? Brow[gk] : 0.f;
            }
        }
        bf16x8 pa0, pa1, pb0, pb1;
#pragma unroll
        for (int j = 0; j < 8; ++j) {
            pa0[j] = (short)f2bf(a[j]);     pa1[j] = (short)f2bf(a[8 + j]);
            pb0[j] = (short)f2bf(b[j]);     pb1[j] = (short)f2bf(b[8 + j]);
        }
        *(bf16x8*)&Abf[lr][lc]     = pa0;
        *(bf16x8*)&Abf[lr][lc + 8] = pa1;
        *(bf16x8*)&Bbf[lr][lc]     = pb0;
        *(bf16x8*)&Bbf[lr][lc + 8] = pb1;
        __syncthreads();

        bf16x8 af[4], bfv[4];
#pragma unroll
        for (int rt = 0; rt < 4; ++rt)
            af[rt] = *(const bf16x8*)&Abf[qr + rt * 16 + frow][koff];
#pragma unroll
        for (int ct = 0; ct < 4; ++ct)
            bfv[ct] = *(const bf16x8*)&Bbf[qc + ct * 16 + frow][koff];
#pragma unroll
        for (int rt = 0; rt < 4; ++rt)
#pragma unroll
            for (int ct = 0; ct < 4; ++ct)
                acc[rt][ct] = __builtin_amdgcn_mfma_f32_16x16x32_bf16(
                    af[rt], bfv[ct], acc[rt][ct], 0, 0, 0);
        __syncthreads();
    }

#pragma unroll
    for (int ct = 0; ct < 4; ++ct) {
        const int colg = n0 + qc + ct * 16 + (ln & 15);
        const float bv = bias[colg];
#pragma unroll
        for (int rt = 0; rt < 4; ++rt) {
#pragma unroll
            for (int i = 0; i < 4; ++i) {
                const int rowg = m0 + qr + rt * 16 + (ln >> 4) * 4 + i;
                C[(size_t)rowg * G3 + colg] = acc[rt][ct][i] + bv;
            }
        }
    }
}

// ---------------- fused two-layer persistent recurrence ----------------
// 256 wgs: blockIdx 0..127 = layer-0 (round-6 proven structure, y0 stored as
// packed bf16); 128..255 = layer-1 (x-gates computed inline from y0 via
// LDS-resident w_ih1; consumes y0 by polling layer-0's per-step flags).
// All h exchange: packed bf16 system-scope (LLC-coherent), flag-array barriers.
__global__ __launch_bounds__(256) void fused_rec(
    const float* __restrict__ xg,      // (B, Tc, 1536) layer-0 x-gates chunk
    const float* __restrict__ w_hh0, const float* __restrict__ b_hh0,
    const float* __restrict__ w_hh1, const float* __restrict__ b_hh1,
    const float* __restrict__ w_ih1, const float* __restrict__ b_ih1,
    unsigned short* __restrict__ y0bf, // (B, T, H) bf16 layer-0 output
    float* __restrict__ h32_0, float* __restrict__ h32_1,
    unsigned short* __restrict__ hbf0, unsigned short* __restrict__ hbf1,
    unsigned int* __restrict__ flags0, unsigned int* __restrict__ flags1,
    int t0, int Tc)
{
    __shared__ unsigned short wldsA[48 * WPAD];   // w_hh slice (both roles)
    __shared__ unsigned short wldsB[48 * WPAD];   // w_ih1 slice (layer-1 only)
    __shared__ unsigned short bufA[16 * WPAD];    // staging
    __shared__ unsigned short bufB[16 * WPAD];    // staging
    __shared__ float gpatch[6][16][17];

    const int tid = threadIdx.x;
    const int wv  = tid >> 6;
    const int ln  = tid & 63;
    const int r   = tid >> 4;         // patch row (batch), threads 0..255
    const int c   = tid & 15;         // patch col (hidden)
    const int frow = ln & 15;
    const int koff = (ln >> 4) * 8;

    if (blockIdx.x < 128) {
        // ================= layer 0 (round-6 proven, verbatim data path) =================
        const int wg  = blockIdx.x;
        const int pr  = wg >> 5;
        const int jg  = wg & 31;
        const int b0A = pr * 16;
        const int b0B = (pr + 4) * 16;
        const int j0  = jg * 16;

        unsigned int phase = 0;
        unsigned int* flagA = &flags0[pr * 32 + jg];
        unsigned int* flagB = &flags0[(pr + 4) * 32 + jg];
        unsigned int* pollp = (tid < 32) ? &flags0[pr * 32 + tid]
                                         : &flags0[(pr + 4) * 32 + (tid - 32)];

        auto barrier = [&]() {
            __syncthreads();
            ++phase;
            if (tid == 0)
                __hip_atomic_store(flagA, phase, __ATOMIC_RELAXED, __HIP_MEMORY_SCOPE_SYSTEM);
            else if (tid == 64)
                __hip_atomic_store(flagB, phase, __ATOMIC_RELAXED, __HIP_MEMORY_SCOPE_SYSTEM);
            __syncthreads();
            if (tid < 64) {
                while (true) {
                    unsigned v = __hip_atomic_load(pollp, __ATOMIC_RELAXED,
                                                   __HIP_MEMORY_SCOPE_SYSTEM);
                    if (__all(v >= phase)) break;
                    __builtin_amdgcn_s_sleep(1);
                }
            }
            __syncthreads();
        };

        for (int i = tid; i < 48 * 512; i += 256) {
            const int row = i >> 9, col = i & 511;
            const int grow = (row >> 4) * HID + j0 + (row & 15);
            wldsA[row * WPAD + col] = f2bf(w_hh0[(size_t)grow * HID + col]);
        }

        const float bh0 = b_hh0[j0 + c];
        const float bh1 = b_hh0[HID + j0 + c];
        const float bh2 = b_hh0[2 * HID + j0 + c];

        unsigned short* hx0 = hbf0;
        unsigned short* hx1 = hbf0 + BB * HID;

        float hA, hB;
        if (t0 == 0) {
            hA = hB = 0.f;
            if (!(tid & 1)) {
                __hip_atomic_store((unsigned*)&hx0[(size_t)(b0A + r) * HID + j0 + c], 0u,
                                   __ATOMIC_RELAXED, __HIP_MEMORY_SCOPE_SYSTEM);
                __hip_atomic_store((unsigned*)&hx0[(size_t)(b0B + r) * HID + j0 + c], 0u,
                                   __ATOMIC_RELAXED, __HIP_MEMORY_SCOPE_SYSTEM);
            }
        } else {
            hA = h32_0[(size_t)(b0A + r) * HID + j0 + c];
            hB = h32_0[(size_t)(b0B + r) * HID + j0 + c];
        }
        barrier();   // always: uniform phase (after step s, flag = s + 2)

        const float* xrA = xg + ((size_t)(b0A + r) * Tc) * G3 + j0 + c;
        const float* xrB = xg + ((size_t)(b0B + r) * Tc) * G3 + j0 + c;
        float xA0 = xrA[0], xA1 = xrA[HID], xA2 = xrA[2 * HID];
        float xB0 = xrB[0], xB1 = xrB[HID], xB2 = xrB[2 * HID];

        for (int s = 0; s < Tc; ++s) {
            const int t = t0 + s;
            const unsigned short* hprev = (t & 1) ? hx1 : hx0;
            unsigned short*       hnext = (t & 1) ? hx0 : hx1;

            {
                const unsigned long long* srcA =
                    (const unsigned long long*)(hprev + (size_t)b0A * HID);
                const unsigned long long* srcB =
                    (const unsigned long long*)(hprev + (size_t)b0B * HID);
#pragma unroll
                for (int k = 0; k < 8; ++k) {
                    const int i = k * 256 + tid;
                    const int row = i >> 7;
                    const int q   = i & 127;
                    unsigned long long vA = __hip_atomic_load(srcA + row * 128 + q,
                            __ATOMIC_RELAXED, __HIP_MEMORY_SCOPE_SYSTEM);
                    unsigned long long vB = __hip_atomic_load(srcB + row * 128 + q,
                            __ATOMIC_RELAXED, __HIP_MEMORY_SCOPE_SYSTEM);
                    *(unsigned long long*)&bufA[row * WPAD + q * 4] = vA;
                    *(unsigned long long*)&bufB[row * WPAD + q * 4] = vB;
                }
            }
            __syncthreads();

            {
                auto chain = [&](int cid) {
                    const int half = (cid >= 3) ? 1 : 0;
                    const int g    = cid - half * 3;
                    const unsigned short* arow =
                        (half ? bufB : bufA) + frow * WPAD + koff;
                    const unsigned short* brow = wldsA + (g * 16 + frow) * WPAD + koff;
                    f32x4 acc = {0.f, 0.f, 0.f, 0.f};
#pragma unroll
                    for (int ks = 0; ks < 16; ++ks)
                        acc = __builtin_amdgcn_mfma_f32_16x16x32_bf16(
                            *(const bf16x8*)(arow + ks * 32),
                            *(const bf16x8*)(brow + ks * 32), acc, 0, 0, 0);
#pragma unroll
                    for (int i = 0; i < 4; ++i)
                        gpatch[cid][(ln >> 4) * 4 + i][ln & 15] = acc[i];
                };
                chain(wv);
                if (wv < 2) chain(4 + wv);
            }
            __syncthreads();

            {
                const float rr = sigm(xA0 + gpatch[0][r][c] + bh0);
                const float zz = sigm(xA1 + gpatch[1][r][c] + bh1);
                const float nn = tanhf(xA2 + rr * (gpatch[2][r][c] + bh2));
                hA = (1.f - zz) * nn + zz * hA;
            }
            {
                const float rr = sigm(xB0 + gpatch[3][r][c] + bh0);
                const float zz = sigm(xB1 + gpatch[4][r][c] + bh1);
                const float nn = tanhf(xB2 + rr * (gpatch[5][r][c] + bh2));
                hB = (1.f - zz) * nn + zz * hB;
            }

            const float oA = __shfl_xor(hA, 1);
            const float oB = __shfl_xor(hB, 1);
            if (!(tid & 1)) {
                const unsigned pA = (unsigned)f2bf(hA) | ((unsigned)f2bf(oA) << 16);
                const unsigned pB = (unsigned)f2bf(hB) | ((unsigned)f2bf(oB) << 16);
                __hip_atomic_store((unsigned*)&hnext[(size_t)(b0A + r) * HID + j0 + c], pA,
                                   __ATOMIC_RELAXED, __HIP_MEMORY_SCOPE_SYSTEM);
                __hip_atomic_store((unsigned*)&hnext[(size_t)(b0B + r) * HID + j0 + c], pB,
                                   __ATOMIC_RELAXED, __HIP_MEMORY_SCOPE_SYSTEM);
                // y0 as packed bf16 (same values) for layer-1 consumption
                __hip_atomic_store((unsigned*)&y0bf[((size_t)(b0A + r) * TT + t) * HID + j0 + c],
                                   pA, __ATOMIC_RELAXED, __HIP_MEMORY_SCOPE_SYSTEM);
                __hip_atomic_store((unsigned*)&y0bf[((size_t)(b0B + r) * TT + t) * HID + j0 + c],
                                   pB, __ATOMIC_RELAXED, __HIP_MEMORY_SCOPE_SYSTEM);
            }

            __syncthreads();           // drain data stores
            ++phase;
            if (tid == 0)
                __hip_atomic_store(flagA, phase, __ATOMIC_RELAXED, __HIP_MEMORY_SCOPE_SYSTEM);
            else if (tid == 64)
                __hip_atomic_store(flagB, phase, __ATOMIC_RELAXED, __HIP_MEMORY_SCOPE_SYSTEM);

            if (s + 1 < Tc) {
                const float* nA = xg + ((size_t)(b0A + r) * Tc + (s + 1)) * G3 + j0 + c;
                const float* nB = xg + ((size_t)(b0B + r) * Tc + (s + 1)) * G3 + j0 + c;
                xA0 = nA[0]; xA1 = nA[HID]; xA2 = nA[2 * HID];
                xB0 = nB[0]; xB1 = nB[HID]; xB2 = nB[2 * HID];
            }

            if (tid < 64) {
                while (true) {
                    unsigned v = __hip_atomic_load(pollp, __ATOMIC_RELAXED,
                                                   __HIP_MEMORY_SCOPE_SYSTEM);
                    if (__all(v >= phase)) break;
                    __builtin_amdgcn_s_sleep(1);
                }
            }
            __syncthreads();
        }

        h32_0[(size_t)(b0A + r) * HID + j0 + c] = hA;
        h32_0[(size_t)(b0B + r) * HID + j0 + c] = hB;

    } else {
        // ================= layer 1 (inline x-gates from y0) =================
        const int wg  = blockIdx.x - 128;
        const int pr  = wg >> 5;
        const int jg  = wg & 31;
        const int b0A = pr * 16;
        const int b0B = (pr + 4) * 16;
        const int j0  = jg * 16;

        unsigned int phase = 0;
        unsigned int* flagA = &flags1[pr * 32 + jg];
        unsigned int* flagB = &flags1[(pr + 4) * 32 + jg];
        // wave 0 polls own flags1 (dual-domain); wave 1 polls producer flags0
        unsigned int* poll1 = (ln < 32) ? &flags1[pr * 32 + ln]
                                        : &flags1[(pr + 4) * 32 + (ln - 32)];
        unsigned int* poll0 = (ln < 32) ? &flags0[pr * 32 + ln]
                                        : &flags0[(pr + 4) * 32 + (ln - 32)];

        // weight slices -> LDS bf16 (once)
        for (int i = tid; i < 48 * 512; i += 256) {
            const int row = i >> 9, col = i & 511;
            const int grow = (row >> 4) * HID + j0 + (row & 15);
            wldsA[row * WPAD + col] = f2bf(w_hh1[(size_t)grow * HID + col]);
            wldsB[row * WPAD + col] = f2bf(w_ih1[(size_t)grow * HID + col]);
        }

        const float bh0 = b_hh1[j0 + c];
        const float bh1 = b_hh1[HID + j0 + c];
        const float bh2 = b_hh1[2 * HID + j0 + c];
        const float bi0 = b_ih1[j0 + c];
        const float bi1 = b_ih1[HID + j0 + c];
        const float bi2 = b_ih1[2 * HID + j0 + c];

        unsigned short* hx0 = hbf1;
        unsigned short* hx1 = hbf1 + BB * HID;

        float hA, hB;
        if (t0 == 0) {
            hA = hB = 0.f;
            if (!(tid & 1)) {
                __hip_atomic_store((unsigned*)&hx0[(size_t)(b0A + r) * HID + j0 + c], 0u,
                                   __ATOMIC_RELAXED, __HIP_MEMORY_SCOPE_SYSTEM);
                __hip_atomic_store((unsigned*)&hx0[(size_t)(b0B + r) * HID + j0 + c], 0u,
                                   __ATOMIC_RELAXED, __HIP_MEMORY_SCOPE_SYSTEM);
            }
        } else {
            hA = h32_1[(size_t)(b0A + r) * HID + j0 + c];
            hB = h32_1[(size_t)(b0B + r) * HID + j0 + c];
        }
        // init barrier + wait for y0[t0] (flags0 >= 2)
        __syncthreads();
        ++phase;   // = 1
        if (tid == 0)
            __hip_atomic_store(flagA, phase, __ATOMIC_RELAXED, __HIP_MEMORY_SCOPE_SYSTEM);
        else if (tid == 64)
            __hip_atomic_store(flagB, phase, __ATOMIC_RELAXED, __HIP_MEMORY_SCOPE_SYSTEM);
        __syncthreads();
        if (wv == 0) {
            while (true) {
                unsigned v = __hip_atomic_load(poll1, __ATOMIC_RELAXED, __HIP_MEMORY_SCOPE_SYSTEM);
                if (__all(v >= phase)) break;
                __builtin_amdgcn_s_sleep(1);
            }
        } else if (wv == 1) {
            while (true) {
                unsigned v = __hip_atomic_load(poll0, __ATOMIC_RELAXED, __HIP_MEMORY_SCOPE_SYSTEM);
                if (__all(v >= 2u)) break;
                __builtin_amdgcn_s_sleep(1);
            }
        }
        __syncthreads();

        auto stage = [&](int b0, int t, const unsigned short* hprev) {
            const unsigned long long* hsrc =
                (const unsigned long long*)(hprev + (size_t)b0 * HID);
#pragma unroll
            for (int k = 0; k < 8; ++k) {
                const int i = k * 256 + tid;
                const int row = i >> 7;
                const int q   = i & 127;
                unsigned long long hv = __hip_atomic_load(hsrc + row * 128 + q,
                        __ATOMIC_RELAXED, __HIP_MEMORY_SCOPE_SYSTEM);
                const unsigned long long* ysrc = (const unsigned long long*)
                    (y0bf + ((size_t)(b0 + row) * TT + t) * HID);
                unsigned long long yv = __hip_atomic_load(ysrc + q,
                        __ATOMIC_RELAXED, __HIP_MEMORY_SCOPE_SYSTEM);
                *(unsigned long long*)&bufA[row * WPAD + q * 4] = hv;   // h1
                *(unsigned long long*)&bufB[row * WPAD + q * 4] = yv;   // y0
            }
        };

        auto chains = [&]() {
            auto chain = [&](int cid) {
                const int xsel = (cid >= 3) ? 1 : 0;
                const int g    = cid - xsel * 3;
                const unsigned short* arow = (xsel ? bufB : bufA) + frow * WPAD + koff;
                const unsigned short* brow =
                    (xsel ? wldsB : wldsA) + (g * 16 + frow) * WPAD + koff;
                f32x4 acc = {0.f, 0.f, 0.f, 0.f};
#pragma unroll
                for (int ks = 0; ks < 16; ++ks)
                    acc = __builtin_amdgcn_mfma_f32_16x16x32_bf16(
                        *(const bf16x8*)(arow + ks * 32),
                        *(const bf16x8*)(brow + ks * 32), acc, 0, 0, 0);
#pragma unroll
                for (int i = 0; i < 4; ++i)
                    gpatch[cid][(ln >> 4) * 4 + i][ln & 15] = acc[i];
            };
            chain(wv);
            if (wv < 2) chain(4 + wv);
        };

        auto gate = [&](float h) {
            const float rr = sigm(gpatch[3][r][c] + bi0 + gpatch[0][r][c] + bh0);
            const float zz = sigm(gpatch[4][r][c] + bi1 + gpatch[1][r][c] + bh1);
            const float nn = tanhf(gpatch[5][r][c] + bi2 + rr * (gpatch[2][r][c] + bh2));
            return (1.f - zz) * nn + zz * h;
        };

        for (int s = 0; s < Tc; ++s) {
            const int t = t0 + s;
            const unsigned short* hprev = (t & 1) ? hx1 : hx0;
            unsigned short*       hnext = (t & 1) ? hx0 : hx1;

            stage(b0A, t, hprev);
            __syncthreads();
            chains();                      // stream A
            __syncthreads();
            stage(b0B, t, hprev);          // overwrite staging for stream B
            hA = gate(hA);                 // stream A gate math (reads gpatch)
            {
                const float oA = __shfl_xor(hA, 1);
                if (!(tid & 1)) {
                    const unsigned pA = (unsigned)f2bf(hA) | ((unsigned)f2bf(oA) << 16);
                    __hip_atomic_store((unsigned*)&hnext[(size_t)(b0A + r) * HID + j0 + c],
                                       pA, __ATOMIC_RELAXED, __HIP_MEMORY_SCOPE_SYSTEM);
                }
            }
            __syncthreads();
            chains();                      // stream B
            __syncthreads();
            hB = gate(hB);
            {
                const float oB = __shfl_xor(hB, 1);
                if (!(tid & 1)) {
                    const unsigned pB = (unsigned)f2bf(hB) | ((unsigned)f2bf(oB) << 16);
                    __hip_atomic_store((unsigned*)&hnext[(size_t)(b0B + r) * HID + j0 + c],
                                       pB, __ATOMIC_RELAXED, __HIP_MEMORY_SCOPE_SYSTEM);
                }
            }

            __syncthreads();               // drain h1 stores
            ++phase;                       // after step s: phase = s + 2
            if (tid == 0)
                __hip_atomic_store(flagA, phase, __ATOMIC_RELAXED, __HIP_MEMORY_SCOPE_SYSTEM);
            else if (tid == 64)
                __hip_atomic_store(flagB, phase, __ATOMIC_RELAXED, __HIP_MEMORY_SCOPE_SYSTEM);
            __syncthreads();
            if (wv == 0) {                 // own h1 exchange ready
                while (true) {
                    unsigned v = __hip_atomic_load(poll1, __ATOMIC_RELAXED,
                                                   __HIP_MEMORY_SCOPE_SYSTEM);
                    if (__all(v >= phase)) break;
                    __builtin_amdgcn_s_sleep(1);
                }
            } else if (wv == 1 && s + 1 < Tc) {   // y0[t+1] ready (flags0 >= s+3)
                const unsigned tgt = (unsigned)(s + 3);
                while (true) {
                    unsigned v = __hip_atomic_load(poll0, __ATOMIC_RELAXED,
                                                   __HIP_MEMORY_SCOPE_SYSTEM);
                    if (__all(v >= tgt)) break;
                    __builtin_amdgcn_s_sleep(1);
                }
            }
            __syncthreads();
        }

        h32_1[(size_t)(b0A + r) * HID + j0 + c] = hA;
        h32_1[(size_t)(b0B + r) * HID + j0 + c] = hB;
    }
}

// ---------------- tail (unchanged) ----------------
__global__ __launch_bounds__(256) void tail_kernel(
    const float* __restrict__ hfin,
    const float* __restrict__ bn_w, const float* __restrict__ bn_b,
    const float* __restrict__ bn_mean, const float* __restrict__ bn_var,
    const float* __restrict__ fc1_w, const float* __restrict__ fc1_b,
    const float* __restrict__ ln_w, const float* __restrict__ ln_b,
    const float* __restrict__ fc2_w, const float* __restrict__ fc2_b,
    float* __restrict__ out)
{
    const int b = blockIdx.x;
    const int tid = threadIdx.x;
    __shared__ float pn[512];
    __shared__ float o1[256];
    __shared__ float red[2][4];

    for (int jj = tid; jj < 512; jj += 256) {
        float v = hfin[(size_t)b * 512 + jj];
        v = (v - bn_mean[jj]) * rsqrtf(bn_var[jj] + EPSV) * bn_w[jj] + bn_b[jj];
        pn[jj] = v;
    }
    __syncthreads();

    const float4* w1 = (const float4*)(fc1_w + (size_t)tid * 512);
    float acc = fc1_b[tid];
#pragma unroll 4
    for (int kq = 0; kq < 128; ++kq) {
        float4 w4 = w1[kq];
        float4 h4 = *(const float4*)&pn[kq * 4];
        acc = fmaf(w4.x, h4.x, acc); acc = fmaf(w4.y, h4.y, acc);
        acc = fmaf(w4.z, h4.z, acc); acc = fmaf(w4.w, h4.w, acc);
    }
    const float val = fmaxf(acc, 0.f);

    float s = val, sq = val * val;
#pragma unroll
    for (int off = 32; off >= 1; off >>= 1) {
        s  += __shfl_xor(s, off);
        sq += __shfl_xor(sq, off);
    }
    const int wv = tid >> 6, ln = tid & 63;
    if (ln == 0) { red[0][wv] = s; red[1][wv] = sq; }
    __syncthreads();
    const float S  = red[0][0] + red[0][1] + red[0][2] + red[0][3];
    const float SQ = red[1][0] + red[1][1] + red[1][2] + red[1][3];
    const float mu  = S * (1.f / 256.f);
    const float var = SQ * (1.f / 256.f) - mu * mu;
    const float nv = (val - mu) * rsqrtf(var + EPSV) * ln_w[tid] + ln_b[tid];
    o1[tid] = nv;
    __syncthreads();

    if (wv < 3) {
        const float* w2 = fc2_w + wv * 256;
        float p = w2[ln] * o1[ln] + w2[ln + 64] * o1[ln + 64]
                + w2[ln + 128] * o1[ln + 128] + w2[ln + 192] * o1[ln + 192];
#pragma unroll
        for (int off = 32; off >= 1; off >>= 1) p += __shfl_xor(p, off);
        if (ln == 0) out[b * 3 + wv] = p + fc2_b[wv];
    }
}

extern "C" void kernel_launch(void* const* d_in, const int* in_sizes, int n_in,
                              void* d_out, int out_size, void* d_ws, size_t ws_size,
                              hipStream_t stream) {
    const float* x       = (const float*)d_in[0];
    const float* w_ih0   = (const float*)d_in[1];
    const float* w_hh0   = (const float*)d_in[2];
    const float* b_ih0   = (const float*)d_in[3];
    const float* b_hh0   = (const float*)d_in[4];
    const float* w_ih1   = (const float*)d_in[5];
    const float* w_hh1   = (const float*)d_in[6];
    const float* b_ih1   = (const float*)d_in[7];
    const float* b_hh1   = (const float*)d_in[8];
    const float* bn_w    = (const float*)d_in[9];
    const float* bn_b    = (const float*)d_in[10];
    const float* bn_mean = (const float*)d_in[11];
    const float* bn_var  = (const float*)d_in[12];
    const float* fc1_w   = (const float*)d_in[13];
    const float* fc1_b   = (const float*)d_in[14];
    const float* ln_w    = (const float*)d_in[15];
    const float* ln_b    = (const float*)d_in[16];
    const float* fc2_w   = (const float*)d_in[17];
    const float* fc2_b   = (const float*)d_in[18];
    float* out = (float*)d_out;

    // ws layout (float slots):
    // h32_0 | h32_1 | hbf0(2xB*H bf16) | hbf1 | y0bf(B*T*H bf16) | flags | xg chunk
    float* ws = (float*)d_ws;
    const size_t h32F  = (size_t)BB * HID;            //     65,536
    const size_t hbfF  = (size_t)BB * HID;            // 2*B*H ushort = 65,536 slots
    const size_t y0bfF = (size_t)BB * TT * HID / 2;   // B*T*H ushort = 8,388,608 slots
    const size_t flgF  = 512;                         // flags0(256) + flags1(256)
    float*          h32_0 = ws;
    float*          h32_1 = h32_0 + h32F;
    unsigned short* hbf0  = (unsigned short*)(h32_1 + h32F);
    unsigned short* hbf1  = (unsigned short*)(h32_1 + h32F + hbfF);
    unsigned short* y0bf  = (unsigned short*)(h32_1 + h32F + 2 * hbfF);
    unsigned int*   flags = (unsigned int*)(h32_1 + h32F + 2 * hbfF + y0bfF);
    float*          xgc   = h32_1 + h32F + 2 * hbfF + y0bfF + flgF;
    unsigned int*   flags0 = flags;
    unsigned int*   flags1 = flags + 256;

    const size_t fixedF = 2 * h32F + 2 * hbfF + y0bfF + flgF;
    const size_t availF = ws_size / sizeof(float);
    int Tc = TT;
    while (Tc > 8 && fixedF + (size_t)BB * (size_t)Tc * G3 > availF) Tc >>= 1;

    for (int c = 0; c < TT; c += Tc) {
        gemm_mfma_bias<<<dim3(12, (BB * Tc) / 128), dim3(256), 0, stream>>>(
            x, w_ih0, b_ih0, xgc, IN0, c, Tc);
        hipMemsetAsync(flags, 0, flgF * sizeof(float), stream);
        int t0 = c, tc = Tc;
        void* args[] = { (void*)&xgc,
                         (void*)&w_hh0, (void*)&b_hh0,
                         (void*)&w_hh1, (void*)&b_hh1,
                         (void*)&w_ih1, (void*)&b_ih1,
                         (void*)&y0bf,
                         (void*)&h32_0, (void*)&h32_1,
                         (void*)&hbf0, (void*)&hbf1,
                         (void*)&flags0, (void*)&flags1,
                         (void*)&t0, (void*)&tc };
        hipLaunchCooperativeKernel((void*)fused_rec, dim3(256), dim3(256),
                                   args, 0, stream);
    }

    tail_kernel<<<dim3(128), dim3(256), 0, stream>>>(
        h32_1, bn_w, bn_b, bn_mean, bn_var,
        fc1_w, fc1_b, ln_w, ln_b, fc2_w, fc2_b, out);
}

// Round 11
// 1493.404 us; speedup vs baseline: 25.2602x; 1.5114x over previous
//
#include <hip/hip_runtime.h>
#include <math.h>

#define BB   128
#define TT   256
#define IN0  300
#define HID  512
#define G3   1536
#define EPSV 1e-5f
#define WPAD 520          // bf16 elems per LDS row (512 + 8 pad)

typedef __attribute__((ext_vector_type(8))) short bf16x8;
typedef __attribute__((ext_vector_type(4))) float f32x4;

__device__ __forceinline__ float sigm(float x) { return 1.0f / (1.0f + expf(-x)); }

__device__ __forceinline__ unsigned short f2bf(float f) {
    union { float f; unsigned u; } v; v.f = f;
    unsigned r = v.u + 0x7fffu + ((v.u >> 16) & 1u);   // RNE
    return (unsigned short)(r >> 16);
}

// ---------------- bf16-MFMA xg GEMM (round-9 proven; layer 0 only) ----------------
__global__ __launch_bounds__(256) void gemm_mfma_bias(
    const float* __restrict__ A, const float* __restrict__ Bm,
    const float* __restrict__ bias, float* __restrict__ C,
    int K, int c, int Tc)
{
    __shared__ unsigned short Abf[128][40];
    __shared__ unsigned short Bbf[128][40];

    const int n0  = blockIdx.x * 128;
    const int m0  = blockIdx.y * 128;
    const int tid = threadIdx.x;
    const int wvi = tid >> 6;
    const int ln  = tid & 63;
    const int qr  = (wvi >> 1) * 64;
    const int qc  = (wvi & 1) * 64;
    const int frow = ln & 15;
    const int koff = (ln >> 4) * 8;

    f32x4 acc[4][4];
#pragma unroll
    for (int i = 0; i < 4; ++i)
#pragma unroll
        for (int j = 0; j < 4; ++j) acc[i][j] = (f32x4){0.f, 0.f, 0.f, 0.f};

    const int lr = tid >> 1;
    const int lc = (tid & 1) * 16;

    const int gr   = m0 + lr;
    const int brow = gr / Tc;
    const int tl   = gr - brow * Tc;
    const float* Arow = A + ((size_t)brow * TT + (size_t)(c + tl)) * K;
    const float* Brow = Bm + (size_t)(n0 + lr) * K;

    const int nk = (K + 31) >> 5;
    for (int kt = 0; kt < nk; ++kt) {
        const int k0 = kt * 32;
        float a[16], b[16];
        if (k0 + 32 <= K) {
            float4 v;
#pragma unroll
            for (int j = 0; j < 4; ++j) {
                v = *(const float4*)(Arow + k0 + lc + j * 4);
                a[j*4+0] = v.x; a[j*4+1] = v.y; a[j*4+2] = v.z; a[j*4+3] = v.w;
                v = *(const float4*)(Brow + k0 + lc + j * 4);
                b[j*4+0] = v.x; b[j*4+1] = v.y; b[j*4+2] = v.z; b[j*4+3] = v.w;
            }
        } else {
#pragma unroll
            for (int j = 0; j < 16; ++j) {
                const int gk = k0 + lc + j;
                a[j] = (gk < K) ? Arow[gk] : 0.f;
                b[j] = (gk < K) ? Brow[gk] : 0.f;
            }
        }
        bf16x8 pa0, pa1, pb0, pb1;
#pragma unroll
        for (int j = 0; j < 8; ++j) {
            pa0[j] = (short)f2bf(a[j]);     pa1[j] = (short)f2bf(a[8 + j]);
            pb0[j] = (short)f2bf(b[j]);     pb1[j] = (short)f2bf(b[8 + j]);
        }
        *(bf16x8*)&Abf[lr][lc]     = pa0;
        *(bf16x8*)&Abf[lr][lc + 8] = pa1;
        *(bf16x8*)&Bbf[lr][lc]     = pb0;
        *(bf16x8*)&Bbf[lr][lc + 8] = pb1;
        __syncthreads();

        bf16x8 af[4], bfv[4];
#pragma unroll
        for (int rt = 0; rt < 4; ++rt)
            af[rt] = *(const bf16x8*)&Abf[qr + rt * 16 + frow][koff];
#pragma unroll
        for (int ct = 0; ct < 4; ++ct)
            bfv[ct] = *(const bf16x8*)&Bbf[qc + ct * 16 + frow][koff];
#pragma unroll
        for (int rt = 0; rt < 4; ++rt)
#pragma unroll
            for (int ct = 0; ct < 4; ++ct)
                acc[rt][ct] = __builtin_amdgcn_mfma_f32_16x16x32_bf16(
                    af[rt], bfv[ct], acc[rt][ct], 0, 0, 0);
        __syncthreads();
    }

#pragma unroll
    for (int ct = 0; ct < 4; ++ct) {
        const int colg = n0 + qc + ct * 16 + (ln & 15);
        const float bv = bias[colg];
#pragma unroll
        for (int rt = 0; rt < 4; ++rt) {
#pragma unroll
            for (int i = 0; i < 4; ++i) {
                const int rowg = m0 + qr + rt * 16 + (ln >> 4) * 4 + i;
                C[(size_t)rowg * G3 + colg] = acc[rt][ct][i] + bv;
            }
        }
    }
}

// ---------------- fused two-layer persistent recurrence ----------------
// 256 wgs: blockIdx 0..127 = layer-0 (round-6 proven, verbatim); 128..255 =
// layer-1 with SINGLE LLC staging exposure per step (all 32 u64 loads issued
// up-front, A-first; B loads complete under chains-A).
__global__ __launch_bounds__(256) void fused_rec(
    const float* __restrict__ xg,      // (B, Tc, 1536) layer-0 x-gates chunk
    const float* __restrict__ w_hh0, const float* __restrict__ b_hh0,
    const float* __restrict__ w_hh1, const float* __restrict__ b_hh1,
    const float* __restrict__ w_ih1, const float* __restrict__ b_ih1,
    unsigned short* __restrict__ y0bf, // (B, T, H) bf16 layer-0 output
    float* __restrict__ h32_0, float* __restrict__ h32_1,
    unsigned short* __restrict__ hbf0, unsigned short* __restrict__ hbf1,
    unsigned int* __restrict__ flags0, unsigned int* __restrict__ flags1,
    int t0, int Tc)
{
    __shared__ unsigned short wldsA[48 * WPAD];   // w_hh slice (both roles)
    __shared__ unsigned short wldsB[48 * WPAD];   // w_ih1 slice (layer-1 only)
    __shared__ unsigned short bufA[16 * WPAD];    // staging
    __shared__ unsigned short bufB[16 * WPAD];    // staging
    __shared__ float gpatch[6][16][17];

    const int tid = threadIdx.x;
    const int wv  = tid >> 6;
    const int ln  = tid & 63;
    const int r   = tid >> 4;         // patch row (batch)
    const int c   = tid & 15;         // patch col (hidden)
    const int frow = ln & 15;
    const int koff = (ln >> 4) * 8;

    if (blockIdx.x < 128) {
        // ================= layer 0 (round-6 proven, verbatim data path) =================
        const int wg  = blockIdx.x;
        const int pr  = wg >> 5;
        const int jg  = wg & 31;
        const int b0A = pr * 16;
        const int b0B = (pr + 4) * 16;
        const int j0  = jg * 16;

        unsigned int phase = 0;
        unsigned int* flagA = &flags0[pr * 32 + jg];
        unsigned int* flagB = &flags0[(pr + 4) * 32 + jg];
        unsigned int* pollp = (tid < 32) ? &flags0[pr * 32 + tid]
                                         : &flags0[(pr + 4) * 32 + (tid - 32)];

        auto barrier = [&]() {
            __syncthreads();
            ++phase;
            if (tid == 0)
                __hip_atomic_store(flagA, phase, __ATOMIC_RELAXED, __HIP_MEMORY_SCOPE_SYSTEM);
            else if (tid == 64)
                __hip_atomic_store(flagB, phase, __ATOMIC_RELAXED, __HIP_MEMORY_SCOPE_SYSTEM);
            __syncthreads();
            if (tid < 64) {
                while (true) {
                    unsigned v = __hip_atomic_load(pollp, __ATOMIC_RELAXED,
                                                   __HIP_MEMORY_SCOPE_SYSTEM);
                    if (__all(v >= phase)) break;
                    __builtin_amdgcn_s_sleep(1);
                }
            }
            __syncthreads();
        };

        for (int i = tid; i < 48 * 512; i += 256) {
            const int row = i >> 9, col = i & 511;
            const int grow = (row >> 4) * HID + j0 + (row & 15);
            wldsA[row * WPAD + col] = f2bf(w_hh0[(size_t)grow * HID + col]);
        }

        const float bh0 = b_hh0[j0 + c];
        const float bh1 = b_hh0[HID + j0 + c];
        const float bh2 = b_hh0[2 * HID + j0 + c];

        unsigned short* hx0 = hbf0;
        unsigned short* hx1 = hbf0 + BB * HID;

        float hA, hB;
        if (t0 == 0) {
            hA = hB = 0.f;
            if (!(tid & 1)) {
                __hip_atomic_store((unsigned*)&hx0[(size_t)(b0A + r) * HID + j0 + c], 0u,
                                   __ATOMIC_RELAXED, __HIP_MEMORY_SCOPE_SYSTEM);
                __hip_atomic_store((unsigned*)&hx0[(size_t)(b0B + r) * HID + j0 + c], 0u,
                                   __ATOMIC_RELAXED, __HIP_MEMORY_SCOPE_SYSTEM);
            }
        } else {
            hA = h32_0[(size_t)(b0A + r) * HID + j0 + c];
            hB = h32_0[(size_t)(b0B + r) * HID + j0 + c];
        }
        barrier();   // uniform phase (after step s, flag = s + 2)

        const float* xrA = xg + ((size_t)(b0A + r) * Tc) * G3 + j0 + c;
        const float* xrB = xg + ((size_t)(b0B + r) * Tc) * G3 + j0 + c;
        float xA0 = xrA[0], xA1 = xrA[HID], xA2 = xrA[2 * HID];
        float xB0 = xrB[0], xB1 = xrB[HID], xB2 = xrB[2 * HID];

        for (int s = 0; s < Tc; ++s) {
            const int t = t0 + s;
            const unsigned short* hprev = (t & 1) ? hx1 : hx0;
            unsigned short*       hnext = (t & 1) ? hx0 : hx1;

            {
                const unsigned long long* srcA =
                    (const unsigned long long*)(hprev + (size_t)b0A * HID);
                const unsigned long long* srcB =
                    (const unsigned long long*)(hprev + (size_t)b0B * HID);
#pragma unroll
                for (int k = 0; k < 8; ++k) {
                    const int i = k * 256 + tid;
                    const int row = i >> 7;
                    const int q   = i & 127;
                    unsigned long long vA = __hip_atomic_load(srcA + row * 128 + q,
                            __ATOMIC_RELAXED, __HIP_MEMORY_SCOPE_SYSTEM);
                    unsigned long long vB = __hip_atomic_load(srcB + row * 128 + q,
                            __ATOMIC_RELAXED, __HIP_MEMORY_SCOPE_SYSTEM);
                    *(unsigned long long*)&bufA[row * WPAD + q * 4] = vA;
                    *(unsigned long long*)&bufB[row * WPAD + q * 4] = vB;
                }
            }
            __syncthreads();

            {
                auto chain = [&](int cid) {
                    const int half = (cid >= 3) ? 1 : 0;
                    const int g    = cid - half * 3;
                    const unsigned short* arow =
                        (half ? bufB : bufA) + frow * WPAD + koff;
                    const unsigned short* brow = wldsA + (g * 16 + frow) * WPAD + koff;
                    f32x4 acc = {0.f, 0.f, 0.f, 0.f};
#pragma unroll
                    for (int ks = 0; ks < 16; ++ks)
                        acc = __builtin_amdgcn_mfma_f32_16x16x32_bf16(
                            *(const bf16x8*)(arow + ks * 32),
                            *(const bf16x8*)(brow + ks * 32), acc, 0, 0, 0);
#pragma unroll
                    for (int i = 0; i < 4; ++i)
                        gpatch[cid][(ln >> 4) * 4 + i][ln & 15] = acc[i];
                };
                chain(wv);
                if (wv < 2) chain(4 + wv);
            }
            __syncthreads();

            {
                const float rr = sigm(xA0 + gpatch[0][r][c] + bh0);
                const float zz = sigm(xA1 + gpatch[1][r][c] + bh1);
                const float nn = tanhf(xA2 + rr * (gpatch[2][r][c] + bh2));
                hA = (1.f - zz) * nn + zz * hA;
            }
            {
                const float rr = sigm(xB0 + gpatch[3][r][c] + bh0);
                const float zz = sigm(xB1 + gpatch[4][r][c] + bh1);
                const float nn = tanhf(xB2 + rr * (gpatch[5][r][c] + bh2));
                hB = (1.f - zz) * nn + zz * hB;
            }

            const float oA = __shfl_xor(hA, 1);
            const float oB = __shfl_xor(hB, 1);
            if (!(tid & 1)) {
                const unsigned pA = (unsigned)f2bf(hA) | ((unsigned)f2bf(oA) << 16);
                const unsigned pB = (unsigned)f2bf(hB) | ((unsigned)f2bf(oB) << 16);
                __hip_atomic_store((unsigned*)&hnext[(size_t)(b0A + r) * HID + j0 + c], pA,
                                   __ATOMIC_RELAXED, __HIP_MEMORY_SCOPE_SYSTEM);
                __hip_atomic_store((unsigned*)&hnext[(size_t)(b0B + r) * HID + j0 + c], pB,
                                   __ATOMIC_RELAXED, __HIP_MEMORY_SCOPE_SYSTEM);
                __hip_atomic_store((unsigned*)&y0bf[((size_t)(b0A + r) * TT + t) * HID + j0 + c],
                                   pA, __ATOMIC_RELAXED, __HIP_MEMORY_SCOPE_SYSTEM);
                __hip_atomic_store((unsigned*)&y0bf[((size_t)(b0B + r) * TT + t) * HID + j0 + c],
                                   pB, __ATOMIC_RELAXED, __HIP_MEMORY_SCOPE_SYSTEM);
            }

            __syncthreads();           // drain data stores
            ++phase;
            if (tid == 0)
                __hip_atomic_store(flagA, phase, __ATOMIC_RELAXED, __HIP_MEMORY_SCOPE_SYSTEM);
            else if (tid == 64)
                __hip_atomic_store(flagB, phase, __ATOMIC_RELAXED, __HIP_MEMORY_SCOPE_SYSTEM);

            if (s + 1 < Tc) {
                const float* nA = xg + ((size_t)(b0A + r) * Tc + (s + 1)) * G3 + j0 + c;
                const float* nB = xg + ((size_t)(b0B + r) * Tc + (s + 1)) * G3 + j0 + c;
                xA0 = nA[0]; xA1 = nA[HID]; xA2 = nA[2 * HID];
                xB0 = nB[0]; xB1 = nB[HID]; xB2 = nB[2 * HID];
            }

            if (tid < 64) {
                while (true) {
                    unsigned v = __hip_atomic_load(pollp, __ATOMIC_RELAXED,
                                                   __HIP_MEMORY_SCOPE_SYSTEM);
                    if (__all(v >= phase)) break;
                    __builtin_amdgcn_s_sleep(1);
                }
            }
            __syncthreads();
        }

        h32_0[(size_t)(b0A + r) * HID + j0 + c] = hA;
        h32_0[(size_t)(b0B + r) * HID + j0 + c] = hB;

    } else {
        // ================= layer 1 (inline x-gates from y0; 1 LLC exposure) =================
        const int wg  = blockIdx.x - 128;
        const int pr  = wg >> 5;
        const int jg  = wg & 31;
        const int b0A = pr * 16;
        const int b0B = (pr + 4) * 16;
        const int j0  = jg * 16;

        unsigned int phase = 0;
        unsigned int* flagA = &flags1[pr * 32 + jg];
        unsigned int* flagB = &flags1[(pr + 4) * 32 + jg];
        unsigned int* poll1 = (ln < 32) ? &flags1[pr * 32 + ln]
                                        : &flags1[(pr + 4) * 32 + (ln - 32)];
        unsigned int* poll0 = (ln < 32) ? &flags0[pr * 32 + ln]
                                        : &flags0[(pr + 4) * 32 + (ln - 32)];

        for (int i = tid; i < 48 * 512; i += 256) {
            const int row = i >> 9, col = i & 511;
            const int grow = (row >> 4) * HID + j0 + (row & 15);
            wldsA[row * WPAD + col] = f2bf(w_hh1[(size_t)grow * HID + col]);
            wldsB[row * WPAD + col] = f2bf(w_ih1[(size_t)grow * HID + col]);
        }

        const float bh0 = b_hh1[j0 + c];
        const float bh1 = b_hh1[HID + j0 + c];
        const float bh2 = b_hh1[2 * HID + j0 + c];
        const float bi0 = b_ih1[j0 + c];
        const float bi1 = b_ih1[HID + j0 + c];
        const float bi2 = b_ih1[2 * HID + j0 + c];

        unsigned short* hx0 = hbf1;
        unsigned short* hx1 = hbf1 + BB * HID;

        float hA, hB;
        if (t0 == 0) {
            hA = hB = 0.f;
            if (!(tid & 1)) {
                __hip_atomic_store((unsigned*)&hx0[(size_t)(b0A + r) * HID + j0 + c], 0u,
                                   __ATOMIC_RELAXED, __HIP_MEMORY_SCOPE_SYSTEM);
                __hip_atomic_store((unsigned*)&hx0[(size_t)(b0B + r) * HID + j0 + c], 0u,
                                   __ATOMIC_RELAXED, __HIP_MEMORY_SCOPE_SYSTEM);
            }
        } else {
            hA = h32_1[(size_t)(b0A + r) * HID + j0 + c];
            hB = h32_1[(size_t)(b0B + r) * HID + j0 + c];
        }
        // init barrier + wait for y0[t0] (flags0 >= 2)
        __syncthreads();
        ++phase;   // = 1
        if (tid == 0)
            __hip_atomic_store(flagA, phase, __ATOMIC_RELAXED, __HIP_MEMORY_SCOPE_SYSTEM);
        else if (tid == 64)
            __hip_atomic_store(flagB, phase, __ATOMIC_RELAXED, __HIP_MEMORY_SCOPE_SYSTEM);
        if (wv == 0) {
            while (true) {
                unsigned v = __hip_atomic_load(poll1, __ATOMIC_RELAXED, __HIP_MEMORY_SCOPE_SYSTEM);
                if (__all(v >= phase)) break;
                __builtin_amdgcn_s_sleep(1);
            }
        } else if (wv == 1) {
            while (true) {
                unsigned v = __hip_atomic_load(poll0, __ATOMIC_RELAXED, __HIP_MEMORY_SCOPE_SYSTEM);
                if (__all(v >= 2u)) break;
                __builtin_amdgcn_s_sleep(1);
            }
        }
        __syncthreads();

        auto chains = [&]() {
            auto chain = [&](int cid) {
                const int xsel = (cid >= 3) ? 1 : 0;
                const int g    = cid - xsel * 3;
                const unsigned short* arow = (xsel ? bufB : bufA) + frow * WPAD + koff;
                const unsigned short* brow =
                    (xsel ? wldsB : wldsA) + (g * 16 + frow) * WPAD + koff;
                f32x4 acc = {0.f, 0.f, 0.f, 0.f};
#pragma unroll
                for (int ks = 0; ks < 16; ++ks)
                    acc = __builtin_amdgcn_mfma_f32_16x16x32_bf16(
                        *(const bf16x8*)(arow + ks * 32),
                        *(const bf16x8*)(brow + ks * 32), acc, 0, 0, 0);
#pragma unroll
                for (int i = 0; i < 4; ++i)
                    gpatch[cid][(ln >> 4) * 4 + i][ln & 15] = acc[i];
            };
            chain(wv);
            if (wv < 2) chain(4 + wv);
        };

        auto gate = [&](float h) {
            const float rr = sigm(gpatch[3][r][c] + bi0 + gpatch[0][r][c] + bh0);
            const float zz = sigm(gpatch[4][r][c] + bi1 + gpatch[1][r][c] + bh1);
            const float nn = tanhf(gpatch[5][r][c] + bi2 + rr * (gpatch[2][r][c] + bh2));
            return (1.f - zz) * nn + zz * h;
        };

        for (int s = 0; s < Tc; ++s) {
            const int t = t0 + s;
            const unsigned short* hprev = (t & 1) ? hx1 : hx0;
            unsigned short*       hnext = (t & 1) ? hx0 : hx1;

            // ---- single LLC exposure: issue A loads, then B loads (A-first order) ----
            unsigned long long rah[8], ray[8], rbh[8], rby[8];
            {
                const unsigned long long* hA8 =
                    (const unsigned long long*)(hprev + (size_t)b0A * HID);
#pragma unroll
                for (int k = 0; k < 8; ++k) {
                    const int i = k * 256 + tid;
                    const int row = i >> 7;
                    const int q   = i & 127;
                    rah[k] = __hip_atomic_load(hA8 + row * 128 + q,
                            __ATOMIC_RELAXED, __HIP_MEMORY_SCOPE_SYSTEM);
                    const unsigned long long* yA8 = (const unsigned long long*)
                        (y0bf + ((size_t)(b0A + row) * TT + t) * HID);
                    ray[k] = __hip_atomic_load(yA8 + q,
                            __ATOMIC_RELAXED, __HIP_MEMORY_SCOPE_SYSTEM);
                }
                const unsigned long long* hB8 =
                    (const unsigned long long*)(hprev + (size_t)b0B * HID);
#pragma unroll
                for (int k = 0; k < 8; ++k) {
                    const int i = k * 256 + tid;
                    const int row = i >> 7;
                    const int q   = i & 127;
                    rbh[k] = __hip_atomic_load(hB8 + row * 128 + q,
                            __ATOMIC_RELAXED, __HIP_MEMORY_SCOPE_SYSTEM);
                    const unsigned long long* yB8 = (const unsigned long long*)
                        (y0bf + ((size_t)(b0B + row) * TT + t) * HID);
                    rby[k] = __hip_atomic_load(yB8 + q,
                            __ATOMIC_RELAXED, __HIP_MEMORY_SCOPE_SYSTEM);
                }
            }
            // write stream A staging (waits only on A loads; B loads stay in flight)
#pragma unroll
            for (int k = 0; k < 8; ++k) {
                const int i = k * 256 + tid;
                const int row = i >> 7;
                const int q   = i & 127;
                *(unsigned long long*)&bufA[row * WPAD + q * 4] = rah[k];
                *(unsigned long long*)&bufB[row * WPAD + q * 4] = ray[k];
            }
            __syncthreads();
            chains();                      // stream A (B loads complete underneath)
            __syncthreads();
            // write stream B staging (pure reg->LDS) + gate A
#pragma unroll
            for (int k = 0; k < 8; ++k) {
                const int i = k * 256 + tid;
                const int row = i >> 7;
                const int q   = i & 127;
                *(unsigned long long*)&bufA[row * WPAD + q * 4] = rbh[k];
                *(unsigned long long*)&bufB[row * WPAD + q * 4] = rby[k];
            }
            hA = gate(hA);
            {
                const float oA = __shfl_xor(hA, 1);
                if (!(tid & 1)) {
                    const unsigned pA = (unsigned)f2bf(hA) | ((unsigned)f2bf(oA) << 16);
                    __hip_atomic_store((unsigned*)&hnext[(size_t)(b0A + r) * HID + j0 + c],
                                       pA, __ATOMIC_RELAXED, __HIP_MEMORY_SCOPE_SYSTEM);
                }
            }
            __syncthreads();
            chains();                      // stream B
            __syncthreads();
            hB = gate(hB);
            {
                const float oB = __shfl_xor(hB, 1);
                if (!(tid & 1)) {
                    const unsigned pB = (unsigned)f2bf(hB) | ((unsigned)f2bf(oB) << 16);
                    __hip_atomic_store((unsigned*)&hnext[(size_t)(b0B + r) * HID + j0 + c],
                                       pB, __ATOMIC_RELAXED, __HIP_MEMORY_SCOPE_SYSTEM);
                }
            }

            __syncthreads();               // drain h1 stores
            ++phase;                       // after step s: phase = s + 2
            if (tid == 0)
                __hip_atomic_store(flagA, phase, __ATOMIC_RELAXED, __HIP_MEMORY_SCOPE_SYSTEM);
            else if (tid == 64)
                __hip_atomic_store(flagB, phase, __ATOMIC_RELAXED, __HIP_MEMORY_SCOPE_SYSTEM);
            if (wv == 0) {                 // own h1 exchange ready
                while (true) {
                    unsigned v = __hip_atomic_load(poll1, __ATOMIC_RELAXED,
                                                   __HIP_MEMORY_SCOPE_SYSTEM);
                    if (__all(v >= phase)) break;
                    __builtin_amdgcn_s_sleep(1);
                }
            } else if (wv == 1 && s + 1 < Tc) {   // y0[t+1] ready (flags0 >= s+3)
                const unsigned tgt = (unsigned)(s + 3);
                while (true) {
                    unsigned v = __hip_atomic_load(poll0, __ATOMIC_RELAXED,
                                                   __HIP_MEMORY_SCOPE_SYSTEM);
                    if (__all(v >= tgt)) break;
                    __builtin_amdgcn_s_sleep(1);
                }
            }
            __syncthreads();
        }

        h32_1[(size_t)(b0A + r) * HID + j0 + c] = hA;
        h32_1[(size_t)(b0B + r) * HID + j0 + c] = hB;
    }
}

// ---------------- tail (unchanged) ----------------
__global__ __launch_bounds__(256) void tail_kernel(
    const float* __restrict__ hfin,
    const float* __restrict__ bn_w, const float* __restrict__ bn_b,
    const float* __restrict__ bn_mean, const float* __restrict__ bn_var,
    const float* __restrict__ fc1_w, const float* __restrict__ fc1_b,
    const float* __restrict__ ln_w, const float* __restrict__ ln_b,
    const float* __restrict__ fc2_w, const float* __restrict__ fc2_b,
    float* __restrict__ out)
{
    const int b = blockIdx.x;
    const int tid = threadIdx.x;
    __shared__ float pn[512];
    __shared__ float o1[256];
    __shared__ float red[2][4];

    for (int jj = tid; jj < 512; jj += 256) {
        float v = hfin[(size_t)b * 512 + jj];
        v = (v - bn_mean[jj]) * rsqrtf(bn_var[jj] + EPSV) * bn_w[jj] + bn_b[jj];
        pn[jj] = v;
    }
    __syncthreads();

    const float4* w1 = (const float4*)(fc1_w + (size_t)tid * 512);
    float acc = fc1_b[tid];
#pragma unroll 4
    for (int kq = 0; kq < 128; ++kq) {
        float4 w4 = w1[kq];
        float4 h4 = *(const float4*)&pn[kq * 4];
        acc = fmaf(w4.x, h4.x, acc); acc = fmaf(w4.y, h4.y, acc);
        acc = fmaf(w4.z, h4.z, acc); acc = fmaf(w4.w, h4.w, acc);
    }
    const float val = fmaxf(acc, 0.f);

    float s = val, sq = val * val;
#pragma unroll
    for (int off = 32; off >= 1; off >>= 1) {
        s  += __shfl_xor(s, off);
        sq += __shfl_xor(sq, off);
    }
    const int wv = tid >> 6, ln = tid & 63;
    if (ln == 0) { red[0][wv] = s; red[1][wv] = sq; }
    __syncthreads();
    const float S  = red[0][0] + red[0][1] + red[0][2] + red[0][3];
    const float SQ = red[1][0] + red[1][1] + red[1][2] + red[1][3];
    const float mu  = S * (1.f / 256.f);
    const float var = SQ * (1.f / 256.f) - mu * mu;
    const float nv = (val - mu) * rsqrtf(var + EPSV) * ln_w[tid] + ln_b[tid];
    o1[tid] = nv;
    __syncthreads();

    if (wv < 3) {
        const float* w2 = fc2_w + wv * 256;
        float p = w2[ln] * o1[ln] + w2[ln + 64] * o1[ln + 64]
                + w2[ln + 128] * o1[ln + 128] + w2[ln + 192] * o1[ln + 192];
#pragma unroll
        for (int off = 32; off >= 1; off >>= 1) p += __shfl_xor(p, off);
        if (ln == 0) out[b * 3 + wv] = p + fc2_b[wv];
    }
}

extern "C" void kernel_launch(void* const* d_in, const int* in_sizes, int n_in,
                              void* d_out, int out_size, void* d_ws, size_t ws_size,
                              hipStream_t stream) {
    const float* x       = (const float*)d_in[0];
    const float* w_ih0   = (const float*)d_in[1];
    const float* w_hh0   = (const float*)d_in[2];
    const float* b_ih0   = (const float*)d_in[3];
    const float* b_hh0   = (const float*)d_in[4];
    const float* w_ih1   = (const float*)d_in[5];
    const float* w_hh1   = (const float*)d_in[6];
    const float* b_ih1   = (const float*)d_in[7];
    const float* b_hh1   = (const float*)d_in[8];
    const float* bn_w    = (const float*)d_in[9];
    const float* bn_b    = (const float*)d_in[10];
    const float* bn_mean = (const float*)d_in[11];
    const float* bn_var  = (const float*)d_in[12];
    const float* fc1_w   = (const float*)d_in[13];
    const float* fc1_b   = (const float*)d_in[14];
    const float* ln_w    = (const float*)d_in[15];
    const float* ln_b    = (const float*)d_in[16];
    const float* fc2_w   = (const float*)d_in[17];
    const float* fc2_b   = (const float*)d_in[18];
    float* out = (float*)d_out;

    // ws layout (float slots):
    // h32_0 | h32_1 | hbf0(2xB*H bf16) | hbf1 | y0bf(B*T*H bf16) | flags | xg chunk
    float* ws = (float*)d_ws;
    const size_t h32F  = (size_t)BB * HID;            //     65,536
    const size_t hbfF  = (size_t)BB * HID;            // 2*B*H ushort = 65,536 slots
    const size_t y0bfF = (size_t)BB * TT * HID / 2;   // B*T*H ushort = 8,388,608 slots
    const size_t flgF  = 512;                         // flags0(256) + flags1(256)
    float*          h32_0 = ws;
    float*          h32_1 = h32_0 + h32F;
    unsigned short* hbf0  = (unsigned short*)(h32_1 + h32F);
    unsigned short* hbf1  = (unsigned short*)(h32_1 + h32F + hbfF);
    unsigned short* y0bf  = (unsigned short*)(h32_1 + h32F + 2 * hbfF);
    unsigned int*   flags = (unsigned int*)(h32_1 + h32F + 2 * hbfF + y0bfF);
    float*          xgc   = h32_1 + h32F + 2 * hbfF + y0bfF + flgF;
    unsigned int*   flags0 = flags;
    unsigned int*   flags1 = flags + 256;

    const size_t fixedF = 2 * h32F + 2 * hbfF + y0bfF + flgF;
    const size_t availF = ws_size / sizeof(float);
    int Tc = TT;
    while (Tc > 8 && fixedF + (size_t)BB * (size_t)Tc * G3 > availF) Tc >>= 1;

    for (int c = 0; c < TT; c += Tc) {
        gemm_mfma_bias<<<dim3(12, (BB * Tc) / 128), dim3(256), 0, stream>>>(
            x, w_ih0, b_ih0, xgc, IN0, c, Tc);
        hipMemsetAsync(flags, 0, flgF * sizeof(float), stream);
        int t0 = c, tc = Tc;
        void* args[] = { (void*)&xgc,
                         (void*)&w_hh0, (void*)&b_hh0,
                         (void*)&w_hh1, (void*)&b_hh1,
                         (void*)&w_ih1, (void*)&b_ih1,
                         (void*)&y0bf,
                         (void*)&h32_0, (void*)&h32_1,
                         (void*)&hbf0, (void*)&hbf1,
                         (void*)&flags0, (void*)&flags1,
                         (void*)&t0, (void*)&tc };
        hipLaunchCooperativeKernel((void*)fused_rec, dim3(256), dim3(256),
                                   args, 0, stream);
    }

    tail_kernel<<<dim3(128), dim3(256), 0, stream>>>(
        h32_1, bn_w, bn_b, bn_mean, bn_var,
        fc1_w, fc1_b, ln_w, ln_b, fc2_w, fc2_b, out);
}

// Round 12
// 1451.240 us; speedup vs baseline: 25.9941x; 1.0291x over previous
//
#include <hip/hip_runtime.h>
#include <math.h>

#define BB   128
#define TT   256
#define IN0  300
#define HID  512
#define G3   1536
#define EPSV 1e-5f
#define WPAD 520          // bf16 elems per LDS row (512 + 8 pad)

typedef __attribute__((ext_vector_type(8))) short bf16x8;
typedef __attribute__((ext_vector_type(4))) float f32x4;

__device__ __forceinline__ float sigm(float x) { return 1.0f / (1.0f + expf(-x)); }

__device__ __forceinline__ unsigned short f2bf(float f) {
    union { float f; unsigned u; } v; v.f = f;
    unsigned r = v.u + 0x7fffu + ((v.u >> 16) & 1u);   // RNE
    return (unsigned short)(r >> 16);
}

// ---------------- bf16-MFMA xg GEMM (round-9 proven; layer 0 only) ----------------
__global__ __launch_bounds__(256) void gemm_mfma_bias(
    const float* __restrict__ A, const float* __restrict__ Bm,
    const float* __restrict__ bias, float* __restrict__ C,
    int K, int c, int Tc)
{
    __shared__ unsigned short Abf[128][40];
    __shared__ unsigned short Bbf[128][40];

    const int n0  = blockIdx.x * 128;
    const int m0  = blockIdx.y * 128;
    const int tid = threadIdx.x;
    const int wvi = tid >> 6;
    const int ln  = tid & 63;
    const int qr  = (wvi >> 1) * 64;
    const int qc  = (wvi & 1) * 64;
    const int frow = ln & 15;
    const int koff = (ln >> 4) * 8;

    f32x4 acc[4][4];
#pragma unroll
    for (int i = 0; i < 4; ++i)
#pragma unroll
        for (int j = 0; j < 4; ++j) acc[i][j] = (f32x4){0.f, 0.f, 0.f, 0.f};

    const int lr = tid >> 1;
    const int lc = (tid & 1) * 16;

    const int gr   = m0 + lr;
    const int brow = gr / Tc;
    const int tl   = gr - brow * Tc;
    const float* Arow = A + ((size_t)brow * TT + (size_t)(c + tl)) * K;
    const float* Brow = Bm + (size_t)(n0 + lr) * K;

    const int nk = (K + 31) >> 5;
    for (int kt = 0; kt < nk; ++kt) {
        const int k0 = kt * 32;
        float a[16], b[16];
        if (k0 + 32 <= K) {
            float4 v;
#pragma unroll
            for (int j = 0; j < 4; ++j) {
                v = *(const float4*)(Arow + k0 + lc + j * 4);
                a[j*4+0] = v.x; a[j*4+1] = v.y; a[j*4+2] = v.z; a[j*4+3] = v.w;
                v = *(const float4*)(Brow + k0 + lc + j * 4);
                b[j*4+0] = v.x; b[j*4+1] = v.y; b[j*4+2] = v.z; b[j*4+3] = v.w;
            }
        } else {
#pragma unroll
            for (int j = 0; j < 16; ++j) {
                const int gk = k0 + lc + j;
                a[j] = (gk < K) ? Arow[gk] : 0.f;
                b[j] = (gk < K) ? Brow[gk] : 0.f;
            }
        }
        bf16x8 pa0, pa1, pb0, pb1;
#pragma unroll
        for (int j = 0; j < 8; ++j) {
            pa0[j] = (short)f2bf(a[j]);     pa1[j] = (short)f2bf(a[8 + j]);
            pb0[j] = (short)f2bf(b[j]);     pb1[j] = (short)f2bf(b[8 + j]);
        }
        *(bf16x8*)&Abf[lr][lc]     = pa0;
        *(bf16x8*)&Abf[lr][lc + 8] = pa1;
        *(bf16x8*)&Bbf[lr][lc]     = pb0;
        *(bf16x8*)&Bbf[lr][lc + 8] = pb1;
        __syncthreads();

        bf16x8 af[4], bfv[4];
#pragma unroll
        for (int rt = 0; rt < 4; ++rt)
            af[rt] = *(const bf16x8*)&Abf[qr + rt * 16 + frow][koff];
#pragma unroll
        for (int ct = 0; ct < 4; ++ct)
            bfv[ct] = *(const bf16x8*)&Bbf[qc + ct * 16 + frow][koff];
#pragma unroll
        for (int rt = 0; rt < 4; ++rt)
#pragma unroll
            for (int ct = 0; ct < 4; ++ct)
                acc[rt][ct] = __builtin_amdgcn_mfma_f32_16x16x32_bf16(
                    af[rt], bfv[ct], acc[rt][ct], 0, 0, 0);
        __syncthreads();
    }

#pragma unroll
    for (int ct = 0; ct < 4; ++ct) {
        const int colg = n0 + qc + ct * 16 + (ln & 15);
        const float bv = bias[colg];
#pragma unroll
        for (int rt = 0; rt < 4; ++rt) {
#pragma unroll
            for (int i = 0; i < 4; ++i) {
                const int rowg = m0 + qr + rt * 16 + (ln >> 4) * 4 + i;
                C[(size_t)rowg * G3 + colg] = acc[rt][ct][i] + bv;
            }
        }
    }
}

// ---------------- fused two-layer persistent recurrence ----------------
// 256 wgs: blockIdx 0..127 = layer-0; 128..255 = layer-1 (inline x-gates).
// NEW vs round 11: single 32-row batch-group per wg (streams = its two
// 16-row halves) -> ONE flag domain (32 wgs) per step instead of two;
// layer-0 polls with ALL waves (no post-poll __syncthreads).
__global__ __launch_bounds__(256) void fused_rec(
    const float* __restrict__ xg,      // (B, Tc, 1536) layer-0 x-gates chunk
    const float* __restrict__ w_hh0, const float* __restrict__ b_hh0,
    const float* __restrict__ w_hh1, const float* __restrict__ b_hh1,
    const float* __restrict__ w_ih1, const float* __restrict__ b_ih1,
    unsigned short* __restrict__ y0bf, // (B, T, H) bf16 layer-0 output
    float* __restrict__ h32_0, float* __restrict__ h32_1,
    unsigned short* __restrict__ hbf0, unsigned short* __restrict__ hbf1,
    unsigned int* __restrict__ flags0, unsigned int* __restrict__ flags1,
    int t0, int Tc)
{
    __shared__ unsigned short wldsA[48 * WPAD];   // w_hh slice (both roles)
    __shared__ unsigned short wldsB[48 * WPAD];   // w_ih1 slice (layer-1 only)
    __shared__ unsigned short bufA[16 * WPAD];    // staging
    __shared__ unsigned short bufB[16 * WPAD];    // staging
    __shared__ float gpatch[6][16][17];

    const int tid = threadIdx.x;
    const int wv  = tid >> 6;
    const int ln  = tid & 63;
    const int r   = tid >> 4;         // patch row (batch)
    const int c   = tid & 15;         // patch col (hidden)
    const int frow = ln & 15;
    const int koff = (ln >> 4) * 8;

    if (blockIdx.x < 128) {
        // ================= layer 0 =================
        const int wg  = blockIdx.x;
        const int bg  = wg >> 5;          // 0..3 (32-row batch-group)
        const int jg  = wg & 31;
        const int b0A = bg * 32;
        const int b0B = bg * 32 + 16;
        const int j0  = jg * 16;

        unsigned int phase = 0;
        unsigned int* flagp = &flags0[bg * 32 + jg];
        unsigned int* pollp = &flags0[bg * 32 + (ln & 31)];   // all waves poll

        for (int i = tid; i < 48 * 512; i += 256) {
            const int row = i >> 9, col = i & 511;
            const int grow = (row >> 4) * HID + j0 + (row & 15);
            wldsA[row * WPAD + col] = f2bf(w_hh0[(size_t)grow * HID + col]);
        }

        const float bh0 = b_hh0[j0 + c];
        const float bh1 = b_hh0[HID + j0 + c];
        const float bh2 = b_hh0[2 * HID + j0 + c];

        unsigned short* hx0 = hbf0;
        unsigned short* hx1 = hbf0 + BB * HID;

        float hA, hB;
        if (t0 == 0) {
            hA = hB = 0.f;
            if (!(tid & 1)) {
                __hip_atomic_store((unsigned*)&hx0[(size_t)(b0A + r) * HID + j0 + c], 0u,
                                   __ATOMIC_RELAXED, __HIP_MEMORY_SCOPE_SYSTEM);
                __hip_atomic_store((unsigned*)&hx0[(size_t)(b0B + r) * HID + j0 + c], 0u,
                                   __ATOMIC_RELAXED, __HIP_MEMORY_SCOPE_SYSTEM);
            }
        } else {
            hA = h32_0[(size_t)(b0A + r) * HID + j0 + c];
            hB = h32_0[(size_t)(b0B + r) * HID + j0 + c];
        }
        // init barrier (all-wave poll)
        __syncthreads();
        ++phase;
        if (tid == 0)
            __hip_atomic_store(flagp, phase, __ATOMIC_RELAXED, __HIP_MEMORY_SCOPE_SYSTEM);
        while (true) {
            unsigned v = __hip_atomic_load(pollp, __ATOMIC_RELAXED, __HIP_MEMORY_SCOPE_SYSTEM);
            if (__all(v >= phase)) break;
            __builtin_amdgcn_s_sleep(2);
        }
        __syncthreads();

        const float* xrA = xg + ((size_t)(b0A + r) * Tc) * G3 + j0 + c;
        const float* xrB = xg + ((size_t)(b0B + r) * Tc) * G3 + j0 + c;
        float xA0 = xrA[0], xA1 = xrA[HID], xA2 = xrA[2 * HID];
        float xB0 = xrB[0], xB1 = xrB[HID], xB2 = xrB[2 * HID];

        for (int s = 0; s < Tc; ++s) {
            const int t = t0 + s;
            const unsigned short* hprev = (t & 1) ? hx1 : hx0;
            unsigned short*       hnext = (t & 1) ? hx0 : hx1;

            {
                const unsigned long long* srcA =
                    (const unsigned long long*)(hprev + (size_t)b0A * HID);
                const unsigned long long* srcB =
                    (const unsigned long long*)(hprev + (size_t)b0B * HID);
#pragma unroll
                for (int k = 0; k < 8; ++k) {
                    const int i = k * 256 + tid;
                    const int row = i >> 7;
                    const int q   = i & 127;
                    unsigned long long vA = __hip_atomic_load(srcA + row * 128 + q,
                            __ATOMIC_RELAXED, __HIP_MEMORY_SCOPE_SYSTEM);
                    unsigned long long vB = __hip_atomic_load(srcB + row * 128 + q,
                            __ATOMIC_RELAXED, __HIP_MEMORY_SCOPE_SYSTEM);
                    *(unsigned long long*)&bufA[row * WPAD + q * 4] = vA;
                    *(unsigned long long*)&bufB[row * WPAD + q * 4] = vB;
                }
            }
            __syncthreads();

            {
                auto chain = [&](int cid) {
                    const int half = (cid >= 3) ? 1 : 0;
                    const int g    = cid - half * 3;
                    const unsigned short* arow =
                        (half ? bufB : bufA) + frow * WPAD + koff;
                    const unsigned short* brow = wldsA + (g * 16 + frow) * WPAD + koff;
                    f32x4 acc = {0.f, 0.f, 0.f, 0.f};
#pragma unroll
                    for (int ks = 0; ks < 16; ++ks)
                        acc = __builtin_amdgcn_mfma_f32_16x16x32_bf16(
                            *(const bf16x8*)(arow + ks * 32),
                            *(const bf16x8*)(brow + ks * 32), acc, 0, 0, 0);
#pragma unroll
                    for (int i = 0; i < 4; ++i)
                        gpatch[cid][(ln >> 4) * 4 + i][ln & 15] = acc[i];
                };
                chain(wv);
                if (wv < 2) chain(4 + wv);
            }
            __syncthreads();

            {
                const float rr = sigm(xA0 + gpatch[0][r][c] + bh0);
                const float zz = sigm(xA1 + gpatch[1][r][c] + bh1);
                const float nn = tanhf(xA2 + rr * (gpatch[2][r][c] + bh2));
                hA = (1.f - zz) * nn + zz * hA;
            }
            {
                const float rr = sigm(xB0 + gpatch[3][r][c] + bh0);
                const float zz = sigm(xB1 + gpatch[4][r][c] + bh1);
                const float nn = tanhf(xB2 + rr * (gpatch[5][r][c] + bh2));
                hB = (1.f - zz) * nn + zz * hB;
            }

            const float oA = __shfl_xor(hA, 1);
            const float oB = __shfl_xor(hB, 1);
            if (!(tid & 1)) {
                const unsigned pA = (unsigned)f2bf(hA) | ((unsigned)f2bf(oA) << 16);
                const unsigned pB = (unsigned)f2bf(hB) | ((unsigned)f2bf(oB) << 16);
                __hip_atomic_store((unsigned*)&hnext[(size_t)(b0A + r) * HID + j0 + c], pA,
                                   __ATOMIC_RELAXED, __HIP_MEMORY_SCOPE_SYSTEM);
                __hip_atomic_store((unsigned*)&hnext[(size_t)(b0B + r) * HID + j0 + c], pB,
                                   __ATOMIC_RELAXED, __HIP_MEMORY_SCOPE_SYSTEM);
                __hip_atomic_store((unsigned*)&y0bf[((size_t)(b0A + r) * TT + t) * HID + j0 + c],
                                   pA, __ATOMIC_RELAXED, __HIP_MEMORY_SCOPE_SYSTEM);
                __hip_atomic_store((unsigned*)&y0bf[((size_t)(b0B + r) * TT + t) * HID + j0 + c],
                                   pB, __ATOMIC_RELAXED, __HIP_MEMORY_SCOPE_SYSTEM);
            }

            __syncthreads();           // drain data stores
            ++phase;
            if (tid == 0)
                __hip_atomic_store(flagp, phase, __ATOMIC_RELAXED, __HIP_MEMORY_SCOPE_SYSTEM);

            if (s + 1 < Tc) {          // xg prefetch overlaps the poll below
                const float* nA = xg + ((size_t)(b0A + r) * Tc + (s + 1)) * G3 + j0 + c;
                const float* nB = xg + ((size_t)(b0B + r) * Tc + (s + 1)) * G3 + j0 + c;
                xA0 = nA[0]; xA1 = nA[HID]; xA2 = nA[2 * HID];
                xB0 = nB[0]; xB1 = nB[HID]; xB2 = nB[2 * HID];
            }

            // all-wave poll; no trailing __syncthreads (staging is hazard-free)
            while (true) {
                unsigned v = __hip_atomic_load(pollp, __ATOMIC_RELAXED,
                                               __HIP_MEMORY_SCOPE_SYSTEM);
                if (__all(v >= phase)) break;
                __builtin_amdgcn_s_sleep(2);
            }
        }

        h32_0[(size_t)(b0A + r) * HID + j0 + c] = hA;
        h32_0[(size_t)(b0B + r) * HID + j0 + c] = hB;

    } else {
        // ================= layer 1 (inline x-gates from y0; 1 LLC exposure) =================
        const int wg  = blockIdx.x - 128;
        const int bg  = wg >> 5;          // 0..3 (matches layer-0 rows)
        const int jg  = wg & 31;
        const int b0A = bg * 32;
        const int b0B = bg * 32 + 16;
        const int j0  = jg * 16;

        unsigned int phase = 0;
        unsigned int* flagp = &flags1[bg * 32 + jg];
        unsigned int* poll1 = &flags1[bg * 32 + (ln & 31)];
        unsigned int* poll0 = &flags0[bg * 32 + (ln & 31)];

        for (int i = tid; i < 48 * 512; i += 256) {
            const int row = i >> 9, col = i & 511;
            const int grow = (row >> 4) * HID + j0 + (row & 15);
            wldsA[row * WPAD + col] = f2bf(w_hh1[(size_t)grow * HID + col]);
            wldsB[row * WPAD + col] = f2bf(w_ih1[(size_t)grow * HID + col]);
        }

        const float bh0 = b_hh1[j0 + c];
        const float bh1 = b_hh1[HID + j0 + c];
        const float bh2 = b_hh1[2 * HID + j0 + c];
        const float bi0 = b_ih1[j0 + c];
        const float bi1 = b_ih1[HID + j0 + c];
        const float bi2 = b_ih1[2 * HID + j0 + c];

        unsigned short* hx0 = hbf1;
        unsigned short* hx1 = hbf1 + BB * HID;

        float hA, hB;
        if (t0 == 0) {
            hA = hB = 0.f;
            if (!(tid & 1)) {
                __hip_atomic_store((unsigned*)&hx0[(size_t)(b0A + r) * HID + j0 + c], 0u,
                                   __ATOMIC_RELAXED, __HIP_MEMORY_SCOPE_SYSTEM);
                __hip_atomic_store((unsigned*)&hx0[(size_t)(b0B + r) * HID + j0 + c], 0u,
                                   __ATOMIC_RELAXED, __HIP_MEMORY_SCOPE_SYSTEM);
            }
        } else {
            hA = h32_1[(size_t)(b0A + r) * HID + j0 + c];
            hB = h32_1[(size_t)(b0B + r) * HID + j0 + c];
        }
        // init barrier + wait for y0[t0] (flags0 >= 2)
        __syncthreads();
        ++phase;   // = 1
        if (tid == 0)
            __hip_atomic_store(flagp, phase, __ATOMIC_RELAXED, __HIP_MEMORY_SCOPE_SYSTEM);
        if (wv == 0) {
            while (true) {
                unsigned v = __hip_atomic_load(poll1, __ATOMIC_RELAXED, __HIP_MEMORY_SCOPE_SYSTEM);
                if (__all(v >= phase)) break;
                __builtin_amdgcn_s_sleep(2);
            }
        } else if (wv == 1) {
            while (true) {
                unsigned v = __hip_atomic_load(poll0, __ATOMIC_RELAXED, __HIP_MEMORY_SCOPE_SYSTEM);
                if (__all(v >= 2u)) break;
                __builtin_amdgcn_s_sleep(2);
            }
        }
        __syncthreads();

        auto chains = [&]() {
            auto chain = [&](int cid) {
                const int xsel = (cid >= 3) ? 1 : 0;
                const int g    = cid - xsel * 3;
                const unsigned short* arow = (xsel ? bufB : bufA) + frow * WPAD + koff;
                const unsigned short* brow =
                    (xsel ? wldsB : wldsA) + (g * 16 + frow) * WPAD + koff;
                f32x4 acc = {0.f, 0.f, 0.f, 0.f};
#pragma unroll
                for (int ks = 0; ks < 16; ++ks)
                    acc = __builtin_amdgcn_mfma_f32_16x16x32_bf16(
                        *(const bf16x8*)(arow + ks * 32),
                        *(const bf16x8*)(brow + ks * 32), acc, 0, 0, 0);
#pragma unroll
                for (int i = 0; i < 4; ++i)
                    gpatch[cid][(ln >> 4) * 4 + i][ln & 15] = acc[i];
            };
            chain(wv);
            if (wv < 2) chain(4 + wv);
        };

        auto gate = [&](float h) {
            const float rr = sigm(gpatch[3][r][c] + bi0 + gpatch[0][r][c] + bh0);
            const float zz = sigm(gpatch[4][r][c] + bi1 + gpatch[1][r][c] + bh1);
            const float nn = tanhf(gpatch[5][r][c] + bi2 + rr * (gpatch[2][r][c] + bh2));
            return (1.f - zz) * nn + zz * h;
        };

        for (int s = 0; s < Tc; ++s) {
            const int t = t0 + s;
            const unsigned short* hprev = (t & 1) ? hx1 : hx0;
            unsigned short*       hnext = (t & 1) ? hx0 : hx1;

            // single LLC exposure: issue A loads, then B loads (A-first order)
            unsigned long long rah[8], ray[8], rbh[8], rby[8];
            {
                const unsigned long long* hA8 =
                    (const unsigned long long*)(hprev + (size_t)b0A * HID);
#pragma unroll
                for (int k = 0; k < 8; ++k) {
                    const int i = k * 256 + tid;
                    const int row = i >> 7;
                    const int q   = i & 127;
                    rah[k] = __hip_atomic_load(hA8 + row * 128 + q,
                            __ATOMIC_RELAXED, __HIP_MEMORY_SCOPE_SYSTEM);
                    const unsigned long long* yA8 = (const unsigned long long*)
                        (y0bf + ((size_t)(b0A + row) * TT + t) * HID);
                    ray[k] = __hip_atomic_load(yA8 + q,
                            __ATOMIC_RELAXED, __HIP_MEMORY_SCOPE_SYSTEM);
                }
                const unsigned long long* hB8 =
                    (const unsigned long long*)(hprev + (size_t)b0B * HID);
#pragma unroll
                for (int k = 0; k < 8; ++k) {
                    const int i = k * 256 + tid;
                    const int row = i >> 7;
                    const int q   = i & 127;
                    rbh[k] = __hip_atomic_load(hB8 + row * 128 + q,
                            __ATOMIC_RELAXED, __HIP_MEMORY_SCOPE_SYSTEM);
                    const unsigned long long* yB8 = (const unsigned long long*)
                        (y0bf + ((size_t)(b0B + row) * TT + t) * HID);
                    rby[k] = __hip_atomic_load(yB8 + q,
                            __ATOMIC_RELAXED, __HIP_MEMORY_SCOPE_SYSTEM);
                }
            }
#pragma unroll
            for (int k = 0; k < 8; ++k) {
                const int i = k * 256 + tid;
                const int row = i >> 7;
                const int q   = i & 127;
                *(unsigned long long*)&bufA[row * WPAD + q * 4] = rah[k];
                *(unsigned long long*)&bufB[row * WPAD + q * 4] = ray[k];
            }
            __syncthreads();
            chains();                      // stream A (B loads complete underneath)
            __syncthreads();
#pragma unroll
            for (int k = 0; k < 8; ++k) {
                const int i = k * 256 + tid;
                const int row = i >> 7;
                const int q   = i & 127;
                *(unsigned long long*)&bufA[row * WPAD + q * 4] = rbh[k];
                *(unsigned long long*)&bufB[row * WPAD + q * 4] = rby[k];
            }
            hA = gate(hA);
            {
                const float oA = __shfl_xor(hA, 1);
                if (!(tid & 1)) {
                    const unsigned pA = (unsigned)f2bf(hA) | ((unsigned)f2bf(oA) << 16);
                    __hip_atomic_store((unsigned*)&hnext[(size_t)(b0A + r) * HID + j0 + c],
                                       pA, __ATOMIC_RELAXED, __HIP_MEMORY_SCOPE_SYSTEM);
                }
            }
            __syncthreads();
            chains();                      // stream B
            __syncthreads();
            hB = gate(hB);
            {
                const float oB = __shfl_xor(hB, 1);
                if (!(tid & 1)) {
                    const unsigned pB = (unsigned)f2bf(hB) | ((unsigned)f2bf(oB) << 16);
                    __hip_atomic_store((unsigned*)&hnext[(size_t)(b0B + r) * HID + j0 + c],
                                       pB, __ATOMIC_RELAXED, __HIP_MEMORY_SCOPE_SYSTEM);
                }
            }

            __syncthreads();               // drain h1 stores
            ++phase;                       // after step s: phase = s + 2
            if (tid == 0)
                __hip_atomic_store(flagp, phase, __ATOMIC_RELAXED, __HIP_MEMORY_SCOPE_SYSTEM);
            if (wv == 0) {                 // own h1 exchange ready
                while (true) {
                    unsigned v = __hip_atomic_load(poll1, __ATOMIC_RELAXED,
                                                   __HIP_MEMORY_SCOPE_SYSTEM);
                    if (__all(v >= phase)) break;
                    __builtin_amdgcn_s_sleep(2);
                }
            } else if (wv == 1 && s + 1 < Tc) {   // y0[t+1] ready (flags0 >= s+3)
                const unsigned tgt = (unsigned)(s + 3);
                while (true) {
                    unsigned v = __hip_atomic_load(poll0, __ATOMIC_RELAXED,
                                                   __HIP_MEMORY_SCOPE_SYSTEM);
                    if (__all(v >= tgt)) break;
                    __builtin_amdgcn_s_sleep(2);
                }
            }
            __syncthreads();
        }

        h32_1[(size_t)(b0A + r) * HID + j0 + c] = hA;
        h32_1[(size_t)(b0B + r) * HID + j0 + c] = hB;
    }
}

// ---------------- tail (unchanged) ----------------
__global__ __launch_bounds__(256) void tail_kernel(
    const float* __restrict__ hfin,
    const float* __restrict__ bn_w, const float* __restrict__ bn_b,
    const float* __restrict__ bn_mean, const float* __restrict__ bn_var,
    const float* __restrict__ fc1_w, const float* __restrict__ fc1_b,
    const float* __restrict__ ln_w, const float* __restrict__ ln_b,
    const float* __restrict__ fc2_w, const float* __restrict__ fc2_b,
    float* __restrict__ out)
{
    const int b = blockIdx.x;
    const int tid = threadIdx.x;
    __shared__ float pn[512];
    __shared__ float o1[256];
    __shared__ float red[2][4];

    for (int jj = tid; jj < 512; jj += 256) {
        float v = hfin[(size_t)b * 512 + jj];
        v = (v - bn_mean[jj]) * rsqrtf(bn_var[jj] + EPSV) * bn_w[jj] + bn_b[jj];
        pn[jj] = v;
    }
    __syncthreads();

    const float4* w1 = (const float4*)(fc1_w + (size_t)tid * 512);
    float acc = fc1_b[tid];
#pragma unroll 4
    for (int kq = 0; kq < 128; ++kq) {
        float4 w4 = w1[kq];
        float4 h4 = *(const float4*)&pn[kq * 4];
        acc = fmaf(w4.x, h4.x, acc); acc = fmaf(w4.y, h4.y, acc);
        acc = fmaf(w4.z, h4.z, acc); acc = fmaf(w4.w, h4.w, acc);
    }
    const float val = fmaxf(acc, 0.f);

    float s = val, sq = val * val;
#pragma unroll
    for (int off = 32; off >= 1; off >>= 1) {
        s  += __shfl_xor(s, off);
        sq += __shfl_xor(sq, off);
    }
    const int wv = tid >> 6, ln = tid & 63;
    if (ln == 0) { red[0][wv] = s; red[1][wv] = sq; }
    __syncthreads();
    const float S  = red[0][0] + red[0][1] + red[0][2] + red[0][3];
    const float SQ = red[1][0] + red[1][1] + red[1][2] + red[1][3];
    const float mu  = S * (1.f / 256.f);
    const float var = SQ * (1.f / 256.f) - mu * mu;
    const float nv = (val - mu) * rsqrtf(var + EPSV) * ln_w[tid] + ln_b[tid];
    o1[tid] = nv;
    __syncthreads();

    if (wv < 3) {
        const float* w2 = fc2_w + wv * 256;
        float p = w2[ln] * o1[ln] + w2[ln + 64] * o1[ln + 64]
                + w2[ln + 128] * o1[ln + 128] + w2[ln + 192] * o1[ln + 192];
#pragma unroll
        for (int off = 32; off >= 1; off >>= 1) p += __shfl_xor(p, off);
        if (ln == 0) out[b * 3 + wv] = p + fc2_b[wv];
    }
}

extern "C" void kernel_launch(void* const* d_in, const int* in_sizes, int n_in,
                              void* d_out, int out_size, void* d_ws, size_t ws_size,
                              hipStream_t stream) {
    const float* x       = (const float*)d_in[0];
    const float* w_ih0   = (const float*)d_in[1];
    const float* w_hh0   = (const float*)d_in[2];
    const float* b_ih0   = (const float*)d_in[3];
    const float* b_hh0   = (const float*)d_in[4];
    const float* w_ih1   = (const float*)d_in[5];
    const float* w_hh1   = (const float*)d_in[6];
    const float* b_ih1   = (const float*)d_in[7];
    const float* b_hh1   = (const float*)d_in[8];
    const float* bn_w    = (const float*)d_in[9];
    const float* bn_b    = (const float*)d_in[10];
    const float* bn_mean = (const float*)d_in[11];
    const float* bn_var  = (const float*)d_in[12];
    const float* fc1_w   = (const float*)d_in[13];
    const float* fc1_b   = (const float*)d_in[14];
    const float* ln_w    = (const float*)d_in[15];
    const float* ln_b    = (const float*)d_in[16];
    const float* fc2_w   = (const float*)d_in[17];
    const float* fc2_b   = (const float*)d_in[18];
    float* out = (float*)d_out;

    // ws layout (float slots):
    // h32_0 | h32_1 | hbf0(2xB*H bf16) | hbf1 | y0bf(B*T*H bf16) | flags | xg chunk
    float* ws = (float*)d_ws;
    const size_t h32F  = (size_t)BB * HID;            //     65,536
    const size_t hbfF  = (size_t)BB * HID;            // 2*B*H ushort = 65,536 slots
    const size_t y0bfF = (size_t)BB * TT * HID / 2;   // B*T*H ushort = 8,388,608 slots
    const size_t flgF  = 512;                         // flags0(256) + flags1(256)
    float*          h32_0 = ws;
    float*          h32_1 = h32_0 + h32F;
    unsigned short* hbf0  = (unsigned short*)(h32_1 + h32F);
    unsigned short* hbf1  = (unsigned short*)(h32_1 + h32F + hbfF);
    unsigned short* y0bf  = (unsigned short*)(h32_1 + h32F + 2 * hbfF);
    unsigned int*   flags = (unsigned int*)(h32_1 + h32F + 2 * hbfF + y0bfF);
    float*          xgc   = h32_1 + h32F + 2 * hbfF + y0bfF + flgF;
    unsigned int*   flags0 = flags;
    unsigned int*   flags1 = flags + 256;

    const size_t fixedF = 2 * h32F + 2 * hbfF + y0bfF + flgF;
    const size_t availF = ws_size / sizeof(float);
    int Tc = TT;
    while (Tc > 8 && fixedF + (size_t)BB * (size_t)Tc * G3 > availF) Tc >>= 1;

    for (int c = 0; c < TT; c += Tc) {
        gemm_mfma_bias<<<dim3(12, (BB * Tc) / 128), dim3(256), 0, stream>>>(
            x, w_ih0, b_ih0, xgc, IN0, c, Tc);
        hipMemsetAsync(flags, 0, flgF * sizeof(float), stream);
        int t0 = c, tc = Tc;
        void* args[] = { (void*)&xgc,
                         (void*)&w_hh0, (void*)&b_hh0,
                         (void*)&w_hh1, (void*)&b_hh1,
                         (void*)&w_ih1, (void*)&b_ih1,
                         (void*)&y0bf,
                         (void*)&h32_0, (void*)&h32_1,
                         (void*)&hbf0, (void*)&hbf1,
                         (void*)&flags0, (void*)&flags1,
                         (void*)&t0, (void*)&tc };
        hipLaunchCooperativeKernel((void*)fused_rec, dim3(256), dim3(256),
                                   args, 0, stream);
    }

    tail_kernel<<<dim3(128), dim3(256), 0, stream>>>(
        h32_1, bn_w, bn_b, bn_mean, bn_var,
        fc1_w, fc1_b, ln_w, ln_b, fc2_w, fc2_b, out);
}